// Round 8
// baseline (732.873 us; speedup 1.0000x reference)
//
#include <hip/hip_runtime.h>
#include <hip/hip_bf16.h>

// RtNet25DDualRENet forward. Round 13 (resubmit — R7 bench was an infra failure,
// "container failed twice"; kernel unverified, re-audited, unchanged):
//  - k_gemm64 v2: register-prefetch + double-buffered LDS, ONE barrier/chunk
//    (was 2). R12 counters: VALUBusy 15%, occupancy 15.6%, HBM 12% => pure
//    latency/barrier bound (compute floor ~6us, BW floor ~5us, measured 55us).
//    Prefetch of chunk c+1 issues right after the barrier and hides under the
//    48x16-FMA compute (~1550cy >> 900cy HBM latency). LDS 26->52KB (3 blk/CU).
//  - everything else unchanged from Round 12.

#define BNINV 0.9999950000374997f  // 1/sqrt(1+1e-5)

typedef __attribute__((ext_vector_type(8))) short bf16x8;
typedef __attribute__((ext_vector_type(4))) float f32x4;

__device__ inline unsigned short f2bf(float f) {
  union { float f; unsigned u; } x; x.f = f;
  unsigned r = x.u + 0x7fffu + ((x.u >> 16) & 1u);  // RNE
  return (unsigned short)(r >> 16);
}

// ---------------- workspace layout (float offsets) ----------------
#define OFF_XN      0u          // PART (64 x 8 x 49 partial sums)
#define OFF_Y1BF    3010560u    // bf16 [3136 pairs][2432]
#define OFF_KMT     6823936u    // bf16 [896 n][2432 k]
#define OFF_W2BF    7913472u    // bf16 [96][896]
#define OFF_Y2BF    7956480u    // bf16 [3136][896]
#define OFF_T       9361408u    // (b,49,96)
#define OFF_XPN     9662464u    // 2 x (b,49,960)
#define OFF_SQ      15683584u   // 2 x (b,49,96)
#define OFF_S0P     16285696u   // (b,16,49,49)
#define OFF_S1Y1    18744320u
#define OFF_S1Y2    21202944u
#define OFF_ATT     23661568u
#define OFF_EPI     23667840u
#define OFF_H1      23913600u   // 2 x (64,1920)
#define OFF_EM3     24159360u   // 2 x (64,960)
#define OFF_H2      24297600u
#define OFF_WOUTT   24328320u
#define OFF_CCAT    24420480u
#define OFF_MCLST   24512640u
#define OFF_ECLST   26355840u
#define OFF_WBF     28199040u   // 46080 uints (96x960 bf16 pairs)

// ---------------- tiled transpose ----------------
__global__ __launch_bounds__(256) void k_transpose_t(const float* __restrict__ in,
                                                     float* __restrict__ out,
                                                     int R, int C) {
  __shared__ float tl[32][33];
  int c0 = blockIdx.x * 32, r0 = blockIdx.y * 32;
  int tx = threadIdx.x & 31, ty = threadIdx.x >> 5;
#pragma unroll
  for (int i = 0; i < 4; ++i)
    tl[ty + i * 8][tx] = in[(r0 + ty + i * 8) * C + c0 + tx];
  __syncthreads();
#pragma unroll
  for (int i = 0; i < 4; ++i)
    out[(c0 + ty + i * 8) * R + r0 + tx] = tl[tx][ty + i * 8];
}

// ---- prep: scr_w_in -> packed bf16 pairs ----
__global__ void k_prepwbf(const float* __restrict__ w_in, unsigned* __restrict__ WbfU) {
  int i = blockIdx.x * 256 + threadIdx.x;
  if (i >= 46080) return;
  float a = w_in[2 * i], b = w_in[2 * i + 1];
  WbfU[i] = (unsigned)f2bf(a) | ((unsigned)f2bf(b) << 16);
}

// ---- prep: conv1 kernel matrix Kmat_t[n=(o,d)][k=(ic,pos)] bf16 [896][2432] ----
__global__ void k_kmat(const float* __restrict__ w1, unsigned* __restrict__ kmtu) {
  int i = blockIdx.x * 256 + threadIdx.x;
  if (i >= 896 * 1216) return;
  int n = i / 1216, ku = i % 1216;
  unsigned out = 0;
#pragma unroll
  for (int h = 0; h < 2; ++h) {
    int k = ku * 2 + h;
    float v = 0.f;
    if (n < 864 && k < 2400) {
      int o = n / 9, d = n % 9, i2 = d / 3, j2 = d % 3;
      int ic = k / 25, pos = k % 25, u = pos / 5, vv = pos % 5;
      int di = u - i2, dj = vv - j2;
      if ((unsigned)di < 3u && (unsigned)dj < 3u)
        v = w1[(o * 96 + ic) * 9 + di * 3 + dj];
    }
    out |= ((unsigned)f2bf(v)) << (16 * h);
  }
  kmtu[i] = out;
}

// ---- prep: w2 -> bf16 [96][896] ----
__global__ void k_w2bf(const float* __restrict__ w2, unsigned short* __restrict__ w2b) {
  int i = blockIdx.x * 256 + threadIdx.x;
  if (i >= 86016) return;
  int o2 = i / 896, k = i % 896;
  w2b[i] = (k < 864) ? f2bf(w2[o2 * 864 + k]) : (unsigned short)0;
}

// ---------------- K1: partial sum-of-squares of relu(x) per (b,p) ----------------
__global__ __launch_bounds__(256) void k_l2npart(const float* __restrict__ x,
                                                 float* __restrict__ part) {
  int b = blockIdx.x, sl = blockIdx.y, t = threadIdx.x;
  __shared__ float red[256];
  const float* xb = x + b * 47040 + sl * 5880;
  int p = t & 63, s2 = t >> 6;
  float s = 0.f;
  if (p < 49) {
#pragma unroll 6
    for (int c = 0; c < 30; ++c) {
      float v = xb[(s2 * 30 + c) * 49 + p];
      if (v > 0.f) s += v * v;
    }
  }
  red[t] = s;
  __syncthreads();
  if (t < 49)
    part[(b * 8 + sl) * 49 + t] = red[t] + red[t + 64] + red[t + 128] + red[t + 192];
}

// ------- K2: fused l2norm + self-corr x scr_w_in einsum + BN + relu (bf16 MFMA) -------
// grid (64 b, 7 h). float4 staging stores (conflict-free), b128 P-build reads.
__global__ __launch_bounds__(512) void k_scr_in(
    const float* __restrict__ x, const float* __restrict__ part,
    const unsigned* __restrict__ WbfU,
    const float* __restrict__ bn, unsigned short* __restrict__ y1bf) {
  const int b = blockIdx.x, h = blockIdx.y, t = threadIdx.x;
  const int wave = t >> 6, lane = t & 63, quad = lane >> 4, lr = lane & 15;
  const int mh = wave >> 2, ng = wave & 3;
  __shared__ __align__(16) short Pl[2][192 * 40];
  __shared__ __align__(16) short Wl[2][96 * 40];
  __shared__ __align__(16) float xc[2][2160];   // [j][k] stride 36
  __shared__ float invL[60];
  // zero-pad y1bf[pair][2400..2432)
  if (t < 112) {
    int pairL = t >> 4, ku = t & 15;
    ((unsigned*)y1bf)[(unsigned)(b * 49 + h * 7 + pairL) * 1216u + 1200u + ku] = 0u;
  }
  // per-padded-pixel inverse norms
  if (t < 60) {
    int r = t / 12, wc = t - r * 12;
    int row = h + r - 2, w = wc - 2;
    float iv = 0.f;
    if ((unsigned)row < 7u && (unsigned)w < 7u) {
      int p = row * 7 + w;
      float s = 0.f;
#pragma unroll
      for (int sl = 0; sl < 8; ++sl) s += part[(b * 8 + sl) * 49 + p];
      iv = 1.f / fmaxf(sqrtf(s), 1e-12f);
    }
    invL[t] = iv;
  }
  f32x4 acc[3][3];
#pragma unroll
  for (int m = 0; m < 3; ++m)
#pragma unroll
    for (int n = 0; n < 3; ++n) acc[m][n] = (f32x4){0.f, 0.f, 0.f, 0.f};
  const float* xb = x + b * 47040;
  // staging geometry: thread u<480 owns pixel j = u%60, k-group k4 = u/60 (4 k's)
  const int sj = t % 60, sk4 = t / 60;
  const bool sOk = (t < 480);
  int pixOff = 0;
  bool pixIn = false;
  if (sOk) {
    int r = sj / 12, wc = sj - r * 12;
    int row = h + r - 2, w = wc - 2;
    pixIn = ((unsigned)row < 7u && (unsigned)w < 7u);
    pixOff = row * 7 + w;
  }
  const int colB = t >> 1, halfB = t & 1;
  int i1 = 0, i2 = 0;
  if (t < 384) {
    int cc = colB < 175 ? colB : 174;
    int wp = cc / 25, uv = cc - wp * 25, du = uv / 5, dv = uv - du * 5;
    i1 = (26 + wp) * 36;
    i2 = (du * 12 + wp + dv) * 36;
  }
  float xr0[4] = {0.f, 0.f, 0.f, 0.f};
  unsigned wr0[3];
  // prefetch chunk 0
  {
    if (sOk && pixIn) {
      const float* src = &xb[(sk4 * 4) * 49 + pixOff];
#pragma unroll
      for (int q = 0; q < 4; ++q) xr0[q] = src[q * 49];
    }
#pragma unroll
    for (int it = 0; it < 3; ++it) {
      int i = t + it * 512;
      wr0[it] = WbfU[(i >> 4) * 480 + (i & 15)];
    }
  }
  __syncthreads();   // invL ready before first LDS store
  int p = 0;
  for (int c = 0; c < 30; ++c, p ^= 1) {
    // store prefetched regs into LDS buffer p (normalized); one float4/thread
    float* xcb = xc[p];
    if (sOk) {
      float iv = invL[sj];
      float4 v;
      v.x = fmaxf(xr0[0], 0.f) * iv;
      v.y = fmaxf(xr0[1], 0.f) * iv;
      v.z = fmaxf(xr0[2], 0.f) * iv;
      v.w = fmaxf(xr0[3], 0.f) * iv;
      *(float4*)&xcb[sj * 36 + sk4 * 4] = v;
    }
    unsigned* Wlu = (unsigned*)Wl[p];
#pragma unroll
    for (int it = 0; it < 3; ++it) {
      int i = t + it * 512;
      Wlu[(i >> 4) * 20 + (i & 15)] = wr0[it];
    }
    __syncthreads();
    // build P[p]: b128 reads (center ~broadcast, window ~4-way residual)
    if (t < 384) {
      const float* r1 = &xcb[i1 + halfB * 16];
      const float* r2 = &xcb[i2 + halfB * 16];
      float a[16], cc[16];
#pragma unroll
      for (int q = 0; q < 4; ++q) {
        *(float4*)&a[q * 4] = *(const float4*)&r1[q * 4];
        *(float4*)&cc[q * 4] = *(const float4*)&r2[q * 4];
      }
      unsigned pk[8];
#pragma unroll
      for (int q = 0; q < 8; ++q) {
        float v0 = a[q * 2] * cc[q * 2];
        float v1 = a[q * 2 + 1] * cc[q * 2 + 1];
        pk[q] = (unsigned)f2bf(v0) | ((unsigned)f2bf(v1) << 16);
      }
      unsigned* dst = (unsigned*)Pl[p] + colB * 20 + halfB * 8;
      *(uint4*)dst = *(uint4*)&pk[0];
      *(uint4*)(dst + 4) = *(uint4*)&pk[4];
    }
    __syncthreads();
    // prefetch chunk c+1 (rides across the MFMA phase)
    if (c < 29) {
      const int k0 = (c + 1) * 32;
      if (sOk) {
        if (pixIn) {
          const float* src = &xb[(k0 + sk4 * 4) * 49 + pixOff];
#pragma unroll
          for (int q = 0; q < 4; ++q) xr0[q] = src[q * 49];
        }
      }
      int base = k0 >> 1;
#pragma unroll
      for (int it = 0; it < 3; ++it) {
        int i = t + it * 512;
        wr0[it] = WbfU[(i >> 4) * 480 + base + (i & 15)];
      }
    }
    // MFMA on buffer p
    const int ko = quad * 8;
    bf16x8 af[3], bfr[3];
#pragma unroll
    for (int m = 0; m < 3; ++m)
      af[m] = *(const bf16x8*)&Wl[p][((mh * 3 + m) * 16 + lr) * 40 + ko];
#pragma unroll
    for (int n = 0; n < 3; ++n)
      bfr[n] = *(const bf16x8*)&Pl[p][((ng * 3 + n) * 16 + lr) * 40 + ko];
#pragma unroll
    for (int m = 0; m < 3; ++m)
#pragma unroll
      for (int n = 0; n < 3; ++n)
        acc[m][n] = __builtin_amdgcn_mfma_f32_16x16x32_bf16(
            af[m], bfr[n], acc[m][n], 0, 0, 0);
  }
  // epilogue: C/D col=lane&15, row=quad*4+reg
#pragma unroll
  for (int n = 0; n < 3; ++n) {
    int col = (ng * 3 + n) * 16 + lr;
    if (col >= 175) continue;
    int wp = col / 25, uv = col - wp * 25;
    unsigned pairIdx = (unsigned)(b * 49 + h * 7 + wp);
#pragma unroll
    for (int m = 0; m < 3; ++m) {
#pragma unroll
      for (int r = 0; r < 4; ++r) {
        int o = (mh * 3 + m) * 16 + quad * 4 + r;
        float g = BNINV * bn[o], bt = bn[96 + o];
        float v = fmaxf(acc[m][n][r] * g + bt, 0.f);
        y1bf[pairIdx * 2432u + (unsigned)(o * 25 + uv)] = f2bf(v);
      }
    }
  }
}

// ------- K3: conv1 MFMA GEMM. grid (64 m-slots [49 used], 7 n) -------
__global__ __launch_bounds__(256) void k_conv1g(
    const unsigned* __restrict__ y1u, const unsigned* __restrict__ kmtu,
    const float* __restrict__ bn1, unsigned short* __restrict__ y2bf) {
  if (blockIdx.x >= 49) return;
  const int t = threadIdx.x;
  const int wave = t >> 6, lane = t & 63, quad = lane >> 4, lr = lane & 15;
  const int mh = wave >> 1, nh = wave & 1;
  const int pairBase = blockIdx.x * 64, nBase = blockIdx.y * 128;
  __shared__ __align__(16) short Ash[64 * 72];
  __shared__ __align__(16) short Bsh[128 * 72];
  __shared__ float bnl[192];
  unsigned* Au = (unsigned*)Ash;
  unsigned* Bu = (unsigned*)Bsh;
  if (t < 192) bnl[t] = bn1[t];
  f32x4 acc[2][4];
#pragma unroll
  for (int m = 0; m < 2; ++m)
#pragma unroll
    for (int n = 0; n < 4; ++n) acc[m][n] = (f32x4){0.f, 0.f, 0.f, 0.f};
  const int prA = t >> 2, qA = t & 3;
  const int nB = t >> 1, qB = t & 1;
  for (int c = 0; c < 38; ++c) {
    int ku0 = c * 32;
    __syncthreads();
    {
      const unsigned* src = y1u + (unsigned)(pairBase + prA) * 1216u + ku0 + qA * 8;
      unsigned* dst = Au + prA * 36 + qA * 8;
      *(uint4*)dst = *(const uint4*)src;
      *(uint4*)(dst + 4) = *(const uint4*)(src + 4);
    }
    {
      const unsigned* src = kmtu + (unsigned)(nBase + nB) * 1216u + ku0 + qB * 16;
      unsigned* dst = Bu + nB * 36 + qB * 16;
#pragma unroll
      for (int q = 0; q < 4; ++q)
        *(uint4*)(dst + q * 4) = *(const uint4*)(src + q * 4);
    }
    __syncthreads();
#pragma unroll
    for (int s = 0; s < 2; ++s) {
      int ko = s * 32 + quad * 8;
      bf16x8 af[2], bf[4];
#pragma unroll
      for (int m = 0; m < 2; ++m)
        af[m] = *(const bf16x8*)&Ash[((mh * 2 + m) * 16 + lr) * 72 + ko];
#pragma unroll
      for (int n = 0; n < 4; ++n)
        bf[n] = *(const bf16x8*)&Bsh[((nh * 4 + n) * 16 + lr) * 72 + ko];
#pragma unroll
      for (int m = 0; m < 2; ++m)
#pragma unroll
        for (int n = 0; n < 4; ++n)
          acc[m][n] = __builtin_amdgcn_mfma_f32_16x16x32_bf16(
              af[m], bf[n], acc[m][n], 0, 0, 0);
    }
  }
#pragma unroll
  for (int m = 0; m < 2; ++m) {
#pragma unroll
    for (int r = 0; r < 4; ++r) {
      unsigned pair = (unsigned)(pairBase + (mh * 2 + m) * 16 + quad * 4 + r);
#pragma unroll
      for (int n = 0; n < 4; ++n) {
        int nn = nBase + (nh * 4 + n) * 16 + lr;
        unsigned short outv = 0;
        if (nn < 864) {
          int o = nn / 9;
          float v = fmaxf(acc[m][n][r] * (BNINV * bnl[o]) + bnl[96 + o], 0.f);
          outv = f2bf(v);
        }
        y2bf[pair * 896u + nn] = outv;
      }
    }
  }
}

// ------- K4: conv2 MFMA GEMM, 98 blocks of 32 pairs -------
__global__ __launch_bounds__(256) void k_conv2g(
    const unsigned* __restrict__ y2u, const unsigned* __restrict__ w2u,
    const float* __restrict__ bn2, float* __restrict__ tout) {
  const int t = threadIdx.x;
  const int wave = t >> 6, lane = t & 63, quad = lane >> 4, lr = lane & 15;
  const int mh = wave >> 1, nh = wave & 1;
  const int pairBase = blockIdx.x * 32;
  __shared__ __align__(16) short Ash[32 * 72];
  __shared__ __align__(16) short Bsh[96 * 72];
  __shared__ float bnl[192];
  unsigned* Au = (unsigned*)Ash;
  unsigned* Bu = (unsigned*)Bsh;
  if (t < 192) bnl[t] = bn2[t];
  f32x4 acc[3];
#pragma unroll
  for (int n = 0; n < 3; ++n) acc[n] = (f32x4){0.f, 0.f, 0.f, 0.f};
  const int prA = t >> 3, qA = (t & 7) * 4;
  const int nB = t >> 1, qB = (t & 1) * 16;
  for (int c = 0; c < 14; ++c) {
    int ku0 = c * 32;
    __syncthreads();
    {
      const unsigned* src = y2u + (unsigned)(pairBase + prA) * 448u + ku0 + qA;
      *(uint4*)(Au + prA * 36 + qA) = *(const uint4*)src;
    }
    if (t < 192) {
      const unsigned* src = w2u + (unsigned)nB * 448u + ku0 + qB;
      unsigned* dst = Bu + nB * 36 + qB;
#pragma unroll
      for (int q = 0; q < 4; ++q)
        *(uint4*)(dst + q * 4) = *(const uint4*)(src + q * 4);
    }
    __syncthreads();
#pragma unroll
    for (int s = 0; s < 2; ++s) {
      int ko = s * 32 + quad * 8;
      bf16x8 af;
      af = *(const bf16x8*)&Ash[(mh * 16 + lr) * 72 + ko];
#pragma unroll
      for (int n = 0; n < 3; ++n) {
        bf16x8 bf = *(const bf16x8*)&Bsh[((nh * 3 + n) * 16 + lr) * 72 + ko];
        acc[n] = __builtin_amdgcn_mfma_f32_16x16x32_bf16(af, bf, acc[n], 0, 0, 0);
      }
    }
  }
#pragma unroll
  for (int r = 0; r < 4; ++r) {
    unsigned pair = (unsigned)(pairBase + mh * 16 + quad * 4 + r);
#pragma unroll
    for (int n = 0; n < 3; ++n) {
      int o = (nh * 3 + n) * 16 + lr;
      float v = fmaxf(acc[n][r] * (BNINV * bnl[o]) + bnl[96 + o], 0.f);
      tout[pair * 96u + o] = v;
    }
  }
}

// ------- K5: fused w_out GEMM + BN + residual relu + mean-sub + cca1 + l2norm -------
__global__ __launch_bounds__(512) void k_out_cca(
    const float* __restrict__ tin, const float* __restrict__ wouT,
    const float* __restrict__ bno, const float* __restrict__ x,
    const float* __restrict__ ccaT, const float* __restrict__ bnc,
    float* __restrict__ xpn, float* __restrict__ sq) {
  int b = blockIdx.x, pr = blockIdx.y, t = threadIdx.x;
  __shared__ __align__(16) float tl2[96 * 8];     // 3.0 KB  [ic][pl]
  __shared__ __align__(16) float xrT[960 * 8];    // 30.0 KB [o][pl] : x then y
  __shared__ float red[8 * 520];                  // 16.3 KB pl-major scratch
  __shared__ float mean[7];
  __shared__ float sv[7 * 97];
  __shared__ float inv7[7];
  for (int i = t; i < 672; i += 512) {
    int pl = i / 96, ic = i - pl * 96;
    tl2[ic * 8 + pl] = tin[(b * 49 + pr * 7 + pl) * 96 + ic];
  }
  for (int i = t; i < 6720; i += 512) {
    int o = i / 7, pl = i - o * 7;
    xrT[o * 8 + pl] = x[(b * 960 + o) * 49 + pr * 7 + pl];
  }
  __syncthreads();
  float acc0[7] = {0.f, 0.f, 0.f, 0.f, 0.f, 0.f, 0.f};
  float acc1[7] = {0.f, 0.f, 0.f, 0.f, 0.f, 0.f, 0.f};
  const bool has1 = (t < 448);
  const int o1 = has1 ? t + 512 : t;
#pragma unroll 8
  for (int ic = 0; ic < 96; ++ic) {
    float tv[8];
    *(float4*)&tv[0] = *(const float4*)&tl2[ic * 8];
    *(float4*)&tv[4] = *(const float4*)&tl2[ic * 8 + 4];
    float w0 = wouT[ic * 960 + t];
    float w1 = wouT[ic * 960 + o1];
#pragma unroll
    for (int pl = 0; pl < 7; ++pl) {
      acc0[pl] += w0 * tv[pl];
      acc1[pl] += w1 * tv[pl];
    }
  }
  float part[7] = {0.f, 0.f, 0.f, 0.f, 0.f, 0.f, 0.f};
  {
    float xv[8];
    *(float4*)&xv[0] = *(const float4*)&xrT[t * 8];
    *(float4*)&xv[4] = *(const float4*)&xrT[t * 8 + 4];
    float g = BNINV * bno[t], bt = bno[960 + t];
#pragma unroll
    for (int pl = 0; pl < 7; ++pl) {
      float v = fmaxf(xv[pl] + acc0[pl] * g + bt, 0.f);
      acc0[pl] = v; part[pl] += v;
      xrT[t * 8 + pl] = v;
    }
  }
  if (has1) {
    float xv[8];
    *(float4*)&xv[0] = *(const float4*)&xrT[o1 * 8];
    *(float4*)&xv[4] = *(const float4*)&xrT[o1 * 8 + 4];
    float g = BNINV * bno[o1], bt = bno[960 + o1];
#pragma unroll
    for (int pl = 0; pl < 7; ++pl) {
      float v = fmaxf(xv[pl] + acc1[pl] * g + bt, 0.f);
      acc1[pl] = v; part[pl] += v;
      xrT[o1 * 8 + pl] = v;
    }
  }
#pragma unroll
  for (int pl = 0; pl < 7; ++pl) red[pl * 520 + t] = part[pl];
  __syncthreads();
  if (t < 64) {
#pragma unroll
    for (int pl = 0; pl < 7; ++pl) {
      float s = 0.f;
#pragma unroll
      for (int j = 0; j < 8; ++j) s += red[pl * 520 + t + j * 64];
      red[pl * 520 + t] = s;
    }
  }
  __syncthreads();
  if (t < 7) {
    float s = 0.f;
    for (int i = 0; i < 64; ++i) s += red[t * 520 + i];
    mean[t] = s * (1.f / 960.f);
  }
  __syncthreads();
#pragma unroll
  for (int pl = 0; pl < 7; ++pl)
    xpn[(b * 49 + pr * 7 + pl) * 960 + t] = acc0[pl] - mean[pl];
  if (has1) {
#pragma unroll
    for (int pl = 0; pl < 7; ++pl)
      xpn[(b * 49 + pr * 7 + pl) * 960 + o1] = acc1[pl] - mean[pl];
  }
  float acc2[7] = {0.f, 0.f, 0.f, 0.f, 0.f, 0.f, 0.f};
  float sw = 0.f;
  int o2 = t % 96, csl = t / 96;
  if (t < 480) {
    int c0 = csl * 192;
#pragma unroll 8
    for (int c = c0; c < c0 + 192; ++c) {
      float w = ccaT[c * 96 + o2];
      sw += w;
      float tv[8];
      *(float4*)&tv[0] = *(const float4*)&xrT[c * 8];
      *(float4*)&tv[4] = *(const float4*)&xrT[c * 8 + 4];
#pragma unroll
      for (int pl = 0; pl < 7; ++pl) acc2[pl] += w * tv[pl];
    }
#pragma unroll
    for (int pl = 0; pl < 7; ++pl) red[pl * 520 + t] = acc2[pl];
    red[7 * 520 + t] = sw;
  }
  __syncthreads();
  if (t < 96) {
    float g = BNINV * bnc[t], bt = bnc[96 + t];
    float swt = 0.f;
#pragma unroll
    for (int s5 = 0; s5 < 5; ++s5) swt += red[7 * 520 + s5 * 96 + t];
#pragma unroll
    for (int pl = 0; pl < 7; ++pl) {
      float a = 0.f;
#pragma unroll
      for (int s5 = 0; s5 < 5; ++s5) a += red[pl * 520 + s5 * 96 + t];
      a -= mean[pl] * swt;
      sv[pl * 97 + t] = fmaxf(a * g + bt, 0.f);
    }
  }
  __syncthreads();
  if (t < 112) {
    int pl = t >> 4, ln = t & 15;
    float s = 0.f;
    for (int o = ln; o < 96; o += 16) { float v = sv[pl * 97 + o]; s += v * v; }
    red[pl * 16 + ln] = s;
  }
  __syncthreads();
  if (t < 7) {
    float s = 0.f;
    for (int i = 0; i < 16; ++i) s += red[t * 16 + i];
    inv7[t] = 1.f / fmaxf(sqrtf(s), 1e-8f);
  }
  __syncthreads();
  for (int i = t; i < 672; i += 512) {
    int pl = i / 96, o = i - pl * 96;
    sq[(b * 49 + pr * 7 + pl) * 96 + o] = sv[pl * 97 + o] * inv7[pl];
  }
}

// ------- K7: fused corr + sep4d#0 (512 threads) -------
__global__ __launch_bounds__(512) void k_mid(
    const float* __restrict__ sq0, const float* __restrict__ sq1,
    const float* __restrict__ wuv, const float* __restrict__ bnuv,
    const float* __restrict__ wkl, const float* __restrict__ bnkl,
    const float* __restrict__ pw16, const float* __restrict__ pbn16,
    float* __restrict__ s0p) {
  int b = blockIdx.x, t = threadIdx.x;
  __shared__ float smem[12496];
  float* sL = smem;
  float* qL = smem + 5047;
  float* A = smem + 10094;
  for (int i = t; i < 4704; i += 512) {
    int p = i / 96, c = i % 96;
    sL[p * 103 + c] = sq0[b * 4704 + i];
    qL[p * 103 + c] = sq1[b * 4704 + i];
  }
  __syncthreads();
  for (int i = t; i < 2401; i += 512) {
    int ij = i / 49, kl = i % 49;
    float a = 0.f;
#pragma unroll 4
    for (int c = 0; c < 96; ++c) a += sL[ij * 103 + c] * qL[kl * 103 + c];
    A[i] = a;
  }
  __syncthreads();
  float* B = smem;
  {
    float w0[9];
#pragma unroll
    for (int d = 0; d < 9; ++d) w0[d] = wuv[d];
    float g = BNINV * bnuv[0], bt = bnuv[1];
    for (int i = t; i < 2401; i += 512) {
      int ij = i / 49, kl = i % 49;
      int u = ij / 7, v = ij % 7;
      float a = 0.f;
#pragma unroll
      for (int du = 0; du < 3; ++du) {
        int uu = u + du - 1;
        if ((unsigned)uu >= 7u) continue;
#pragma unroll
        for (int dv = 0; dv < 3; ++dv) {
          int vv = v + dv - 1;
          if ((unsigned)vv >= 7u) continue;
          a += w0[du * 3 + dv] * A[(uu * 7 + vv) * 49 + kl];
        }
      }
      B[i] = fmaxf(a * g + bt, 0.f);
    }
  }
  __syncthreads();
  float* Cc = smem + 4900;
  {
    float w1[9];
#pragma unroll
    for (int d = 0; d < 9; ++d) w1[d] = wkl[d];
    float g = BNINV * bnkl[0], bt = bnkl[1];
    for (int i = t; i < 2401; i += 512) {
      int ij = i / 49, kl = i % 49;
      int kk = kl / 7, ll = kl % 7;
      float a = 0.f;
#pragma unroll
      for (int dh = 0; dh < 3; ++dh) {
        int k2 = kk + dh - 1;
        if ((unsigned)k2 >= 7u) continue;
#pragma unroll
        for (int dw = 0; dw < 3; ++dw) {
          int l2 = ll + dw - 1;
          if ((unsigned)l2 >= 7u) continue;
          a += w1[dh * 3 + dw] * B[ij * 49 + k2 * 7 + l2];
        }
      }
      Cc[i] = a * g + bt;
    }
  }
  __syncthreads();
  for (int o = 0; o < 16; ++o) {
    float sc = pw16[o] * BNINV * pbn16[o], bt2 = pbn16[16 + o];
    for (int i = t; i < 2401; i += 512)
      s0p[(b * 16 + o) * 2401 + i] = fmaxf(Cc[i] * sc + bt2, 0.f);
  }
}

// ---------------- sep4d #1 conv a. grid (64 b, 7 kc), 512 thr ----------------
__global__ __launch_bounds__(512) void k_sep1a(
    const float* __restrict__ in, const float* __restrict__ w,
    const float* __restrict__ bnp, float* __restrict__ out) {
  int b = blockIdx.x, kc = blockIdx.y, t = threadIdx.x;
  __shared__ float inS[16 * 345];
  __shared__ __align__(16) float wP[3072];
  for (int i = t; i < 3072; i += 512) {
    int oc = i / 12, d = i % 12;
    wP[i] = (d < 9) ? w[oc * 9 + d] : 0.f;
  }
  for (int i = t; i < 5488; i += 512) {
    int ic = i / 343, r = i - ic * 343;
    int ij = r / 7, s = r - ij * 7;
    inS[ic * 345 + s * 49 + ij] = in[(b * 16 + ic) * 2401 + ij * 49 + kc * 7 + s];
  }
  __syncthreads();
  for (int rho = t; rho < 784; rho += 512) {
    int o = rho / 49, rem = rho - o * 49, u = rem / 7, s = rem - u * 7;
    float acc[7] = {0.f, 0.f, 0.f, 0.f, 0.f, 0.f, 0.f};
    for (int ic = 0; ic < 16; ++ic) {
      float wv[12];
      const float* wb = &wP[(o * 16 + ic) * 12];
      *(float4*)&wv[0] = *(const float4*)&wb[0];
      *(float4*)&wv[4] = *(const float4*)&wb[4];
      *(float4*)&wv[8] = *(const float4*)&wb[8];
      const float* rowb = &inS[ic * 345 + s * 49];
#pragma unroll
      for (int du = 0; du < 3; ++du) {
        int uu = u + du - 1;
        if ((unsigned)uu >= 7u) continue;
        const float* rr = rowb + uu * 7;
        float r7[7];
#pragma unroll
        for (int q = 0; q < 7; ++q) r7[q] = rr[q];
#pragma unroll
        for (int v = 0; v < 7; ++v) {
          float a = acc[v];
          if (v > 0) a += wv[du * 3 + 0] * r7[v - 1];
          a += wv[du * 3 + 1] * r7[v];
          if (v < 6) a += wv[du * 3 + 2] * r7[v + 1];
          acc[v] = a;
        }
      }
    }
    float g = BNINV * bnp[o], bt = bnp[16 + o];
    long ob = (long)(b * 16 + o) * 2401 + kc * 7 + s;
#pragma unroll
    for (int v = 0; v < 7; ++v)
      out[ob + (u * 7 + v) * 49] = fmaxf(acc[v] * g + bt, 0.f);
  }
}

// ---------------- sep4d #1 conv b. grid (64 b, 7 ir), 512 thr ----------------
__global__ __launch_bounds__(512) void k_sep1b(
    const float* __restrict__ in, const float* __restrict__ w,
    const float* __restrict__ bnp, float* __restrict__ out) {
  int b = blockIdx.x, ir = blockIdx.y, t = threadIdx.x;
  __shared__ float inS[16 * 345];
  __shared__ __align__(16) float wP[3072];
  for (int i = t; i < 3072; i += 512) {
    int oc = i / 12, d = i % 12;
    wP[i] = (d < 9) ? w[oc * 9 + d] : 0.f;
  }
  for (int i = t; i < 5488; i += 512) {
    int ic = i / 343, r = i - ic * 343;
    inS[ic * 345 + r] = in[(b * 16 + ic) * 2401 + ir * 343 + r];
  }
  __syncthreads();
  for (int rho = t; rho < 784; rho += 512) {
    int o = rho / 49, rem = rho - o * 49, jj = rem / 7, k = rem - jj * 7;
    float acc[7] = {0.f, 0.f, 0.f, 0.f, 0.f, 0.f, 0.f};
    for (int ic = 0; ic < 16; ++ic) {
      float wv[12];
      const float* wb = &wP[(o * 16 + ic) * 12];
      *(float4*)&wv[0] = *(const float4*)&wb[0];
      *(float4*)&wv[4] = *(const float4*)&wb[4];
      *(float4*)&wv[8] = *(const float4*)&wb[8];
      const float* rowb = &inS[ic * 345 + jj * 49];
#pragma unroll
      for (int dh = 0; dh < 3; ++dh) {
        int k2 = k + dh - 1;
        if ((unsigned)k2 >= 7u) continue;
        const float* rr = rowb + k2 * 7;
        float r7[7];
#pragma unroll
        for (int q = 0; q < 7; ++q) r7[q] = rr[q];
#pragma unroll
        for (int l = 0; l < 7; ++l) {
          float a = acc[l];
          if (l > 0) a += wv[dh * 3 + 0] * r7[l - 1];
          a += wv[dh * 3 + 1] * r7[l];
          if (l < 6) a += wv[dh * 3 + 2] * r7[l + 1];
          acc[l] = a;
        }
      }
    }
    float g = BNINV * bnp[o], bt = bnp[16 + o];
    long ob = (long)(b * 16 + o) * 2401 + ir * 343 + jj * 49 + k * 7;
#pragma unroll
    for (int l = 0; l < 7; ++l)
      out[ob + l] = acc[l] * g + bt;
  }
}

// ------- K10: fused sep1p + gauss-softmax attention (dual-phase concurrent) -------
__global__ __launch_bounds__(256) void k_c4attn(
    const float* __restrict__ in, const float* __restrict__ pw,
    const float* __restrict__ pbn, float* __restrict__ attn_s,
    float* __restrict__ attn_q) {
  int b = blockIdx.x, t = threadIdx.x;
  __shared__ float c[2401];
  __shared__ float nA[2401];
  __shared__ float nB[2401];
  __shared__ float plw[16];
  if (t < 16) plw[t] = pw[t];
  __syncthreads();
  float g0 = BNINV * pbn[0], bt0 = pbn[1];
  for (int i = t; i < 2401; i += 256) {
    float a = 0.f;
#pragma unroll
    for (int ic = 0; ic < 16; ++ic) a += plw[ic] * in[(b * 16 + ic) * 2401 + i];
    c[i] = a * g0 + bt0;
  }
  __syncthreads();
  if (t < 49) {
    float m = 0.f;
    for (int ij = 0; ij < 49; ++ij) m += c[ij * 49 + t];
    m *= (1.f / 49.f);
    float v = 0.f;
    for (int ij = 0; ij < 49; ++ij) { float d = c[ij * 49 + t] - m; v += d * d; }
    v *= (1.f / 48.f);
    float inv = 1.f / sqrtf(v + 1e-5f);
    float mx = -1e30f;
    for (int ij = 0; ij < 49; ++ij) mx = fmaxf(mx, (c[ij * 49 + t] - m) * inv);
    float s = 0.f;
    for (int ij = 0; ij < 49; ++ij) {
      float e = expf((c[ij * 49 + t] - m) * inv - mx);
      nA[ij * 49 + t] = e; s += e;
    }
    float r = 1.f / s;
    for (int ij = 0; ij < 49; ++ij) nA[ij * 49 + t] *= r;
  } else if (t >= 64 && t < 113) {
    int t2 = t - 64;
    float m = 0.f;
    for (int kl = 0; kl < 49; ++kl) m += c[t2 * 49 + kl];
    m *= (1.f / 49.f);
    float v = 0.f;
    for (int kl = 0; kl < 49; ++kl) { float d = c[t2 * 49 + kl] - m; v += d * d; }
    v *= (1.f / 48.f);
    float inv = 1.f / sqrtf(v + 1e-5f);
    float mx = -1e30f;
    for (int kl = 0; kl < 49; ++kl) mx = fmaxf(mx, (c[t2 * 49 + kl] - m) * inv);
    float s = 0.f;
    for (int kl = 0; kl < 49; ++kl) {
      float e = expf((c[t2 * 49 + kl] - m) * inv - mx);
      nB[t2 * 49 + kl] = e; s += e;
    }
    float r = 1.f / s;
    for (int kl = 0; kl < 49; ++kl) nB[t2 * 49 + kl] *= r;
  }
  __syncthreads();
  if (t < 49) {
    float s = 0.f;
    for (int kl = 0; kl < 49; ++kl) s += nA[t * 49 + kl];
    attn_s[b * 49 + t] = s;
  } else if (t >= 64 && t < 113) {
    int t2 = t - 64;
    float s = 0.f;
    for (int ij = 0; ij < 49; ++ij) s += nB[ij * 49 + t2];
    attn_q[b * 49 + t2] = s;
  }
}

// ------- K11: attention-weighted mean/max pooling -------
__global__ __launch_bounds__(256) void k_pool(const float* __restrict__ xpn,
                                              const float* __restrict__ attn,
                                              float* __restrict__ ep) {
  int b = blockIdx.x, br = blockIdx.y, t = threadIdx.x;
  const float* xb = xpn + br * 3010560 + b * 47040;
  const float* a = attn + br * 3136 + b * 49;
  __shared__ float al[49];
  if (t < 49) al[t] = a[t];
  __syncthreads();
  float* eb = ep + br * 122880 + b * 1920;
  for (int c = t; c < 960; c += 256) {
    float s = 0.f, mx = -1e30f;
#pragma unroll 7
    for (int hw = 0; hw < 49; ++hw) {
      float v = al[hw] * xb[hw * 960 + c];
      s += v; mx = fmaxf(mx, v);
    }
    eb[c] = s * (1.f / 49.f);
    eb[960 + c] = mx;
  }
}

// ------- M=64 GEMM, split-K with atomicAdd; z selects meta/ene -------
// v2: register prefetch + double-buffered LDS, one barrier per 48-k chunk.
__global__ __launch_bounds__(256) void k_gemm64(
    const float* __restrict__ A0, const float* __restrict__ A1, int asplit,
    int reluA, const float* __restrict__ Wm, const float* __restrict__ We,
    int K, int Kslice, float* __restrict__ Cm, float* __restrict__ Ce,
    int N, int zAoff) {
  int otile = blockIdx.x, ks = blockIdx.y, z = blockIdx.z;
  const float* W = z ? We : Wm;
  float* C = z ? Ce : Cm;
  int zo = z * zAoff;
  int t = threadIdx.x, bt = t >> 4, ot = t & 15;
  __shared__ __align__(16) float eT[2][48 * 68];
  __shared__ __align__(16) float wT[2][48 * 68];
  float acc[4][4];
#pragma unroll
  for (int i = 0; i < 4; ++i)
#pragma unroll
    for (int j = 0; j < 4; ++j) acc[i][j] = 0.f;
  const int kbeg = ks * Kslice;
  const int nch = Kslice / 48;  // 5 for Kslice=240
  // per-thread staging ids (3 rows of 768-element space)
  int sb[3], skg[3];
#pragma unroll
  for (int it = 0; it < 3; ++it) {
    int i = t + it * 256;
    sb[it] = i / 12;   // row (A) / out-col (W)
    skg[it] = i % 12;  // k-group of 4
  }
  float4 ra[3], rw[3];
  // prefetch chunk 0
#pragma unroll
  for (int it = 0; it < 3; ++it) {
    int k = kbeg + skg[it] * 4;
    float4 v;
    if (asplit) {
      v = (k < asplit) ? *(const float4*)&A0[sb[it] * 1920 + zo + k]
                       : *(const float4*)&A1[sb[it] * 1920 + zo + k - asplit];
    } else {
      v = *(const float4*)&A0[zo + sb[it] * K + k];
    }
    if (reluA) {
      v.x = fmaxf(v.x, 0.f); v.y = fmaxf(v.y, 0.f);
      v.z = fmaxf(v.z, 0.f); v.w = fmaxf(v.w, 0.f);
    }
    ra[it] = v;
    rw[it] = *(const float4*)&W[(otile * 64 + sb[it]) * K + kbeg + skg[it] * 4];
  }
  int p = 0;
  for (int c = 0; c < nch; ++c, p ^= 1) {
    // store prefetched chunk c into buffer p
#pragma unroll
    for (int it = 0; it < 3; ++it) {
      int row4 = skg[it] * 4, col = sb[it];
      float4 v = ra[it];
      eT[p][(row4 + 0) * 68 + col] = v.x; eT[p][(row4 + 1) * 68 + col] = v.y;
      eT[p][(row4 + 2) * 68 + col] = v.z; eT[p][(row4 + 3) * 68 + col] = v.w;
      float4 w = rw[it];
      wT[p][(row4 + 0) * 68 + col] = w.x; wT[p][(row4 + 1) * 68 + col] = w.y;
      wT[p][(row4 + 2) * 68 + col] = w.z; wT[p][(row4 + 3) * 68 + col] = w.w;
    }
    __syncthreads();
    // prefetch chunk c+1 (latency hidden under compute below)
    if (c + 1 < nch) {
      int k0 = kbeg + (c + 1) * 48;
#pragma unroll
      for (int it = 0; it < 3; ++it) {
        int k = k0 + skg[it] * 4;
        float4 v;
        if (asplit) {
          v = (k < asplit) ? *(const float4*)&A0[sb[it] * 1920 + zo + k]
                           : *(const float4*)&A1[sb[it] * 1920 + zo + k - asplit];
        } else {
          v = *(const float4*)&A0[zo + sb[it] * K + k];
        }
        if (reluA) {
          v.x = fmaxf(v.x, 0.f); v.y = fmaxf(v.y, 0.f);
          v.z = fmaxf(v.z, 0.f); v.w = fmaxf(v.w, 0.f);
        }
        ra[it] = v;
        rw[it] = *(const float4*)&W[(otile * 64 + sb[it]) * K + k0 + skg[it] * 4];
      }
    }
    // compute chunk c from buffer p
#pragma unroll 4
    for (int kk = 0; kk < 48; ++kk) {
      float av[4], wv[4];
      *(float4*)av = *(const float4*)&eT[p][kk * 68 + bt * 4];
      *(float4*)wv = *(const float4*)&wT[p][kk * 68 + ot * 4];
#pragma unroll
      for (int i = 0; i < 4; ++i)
#pragma unroll
        for (int j = 0; j < 4; ++j) acc[i][j] += av[i] * wv[j];
    }
  }
#pragma unroll
  for (int i = 0; i < 4; ++i)
#pragma unroll
    for (int j = 0; j < 4; ++j)
      atomicAdd(&C[(bt * 4 + i) * N + otile * 64 + ot * 4 + j], acc[i][j]);
}

// ------- classifier layer 1 (with fused group-pooling) -------
__global__ __launch_bounds__(256) void k_cls1(
    const float* __restrict__ em3, const float* __restrict__ b2m,
    const float* __restrict__ b2e, const float* __restrict__ w1mT,
    const float* __restrict__ b1m, const float* __restrict__ w1eT,
    const float* __restrict__ b1e, float* __restrict__ h2) {
  int which = blockIdx.z, g = blockIdx.y, t = threadIdx.x;
  const float* em = em3 + which * 61440 + g * 7680;
  const float* b2 = which ? b2e : b2m;
  const float* WT = which ? w1eT : w1mT;
  const float* b1 = which ? b1e : b1m;
  __shared__ float pl[960];
  for (int d = t; d < 960; d += 256) {
    float s = 0.f;
#pragma unroll
    for (int r = 0; r < 8; ++r) s += em[r * 960 + d];
    pl[d] = s * 0.125f + b2[d];
  }
  __syncthreads();
  int o = blockIdx.x * 256 + t;
  if (o >= 1920) return;
  float acc = 0.f;
#pragma unroll 8
  for (int k = 0; k < 960; ++k) acc += WT[k * 1920 + o] * pl[k];
  float z = acc + b1[o];
  h2[which * 15360 + g * 1920 + o] = z * fminf(fmaxf(z + 3.f, 0.f), 6.f) * (1.f / 6.f);
}

// ------- classifier layer 2 + final concat -------
__global__ __launch_bounds__(128) void k_cls2(
    const float* __restrict__ h2, const float* __restrict__ w2m,
    const float* __restrict__ b2m, const float* __restrict__ w2e,
    const float* __restrict__ b2e, float* __restrict__ out) {
  int g = blockIdx.x, which = blockIdx.y;
  int t = threadIdx.x, j = t >> 6, lane = t & 63;
  const float* h = h2 + which * 15360 + g * 1920;
  const float* W = (which ? w2e : w2m) + j * 1920;
  const float* bb = which ? b2e : b2m;
  float s = 0.f;
  for (int k = lane; k < 1920; k += 64) s += h[k] * W[k];
  for (int off = 32; off >= 1; off >>= 1) s += __shfl_down(s, off);
  if (lane == 0) out[g * 4 + which * 2 + j] = s + bb[j];
}

// =======================================================================
extern "C" void kernel_launch(void* const* d_in, const int* in_sizes, int n_in,
                              void* d_out, int out_size, void* d_ws, size_t ws_size,
                              hipStream_t stream) {
  const float* x_p = (const float*)d_in[0];
  const float* x_i = (const float*)d_in[1];
  const float* scr_w_in = (const float*)d_in[2];
  const float* scr_bn_in = (const float*)d_in[3];
  const float* scr_w1 = (const float*)d_in[4];
  const float* scr_bn1 = (const float*)d_in[5];
  const float* scr_w2 = (const float*)d_in[6];
  const float* scr_bn2 = (const float*)d_in[7];
  const float* scr_w_out = (const float*)d_in[8];
  const float* scr_bn_out = (const float*)d_in[9];
  const float* cca1x1_w = (const float*)d_in[10];
  const float* cca1x1_bn = (const float*)d_in[11];
  const float* cca0_c2_w = (const float*)d_in[12];
  const float* cca0_c2_bn = (const float*)d_in[13];
  const float* cca0_c1_w = (const float*)d_in[14];
  const float* cca0_c1_bn = (const float*)d_in[15];
  const float* cca0_p_w = (const float*)d_in[16];
  const float* cca0_p_bn = (const float*)d_in[17];
  const float* cca1_c2_w = (const float*)d_in[18];
  const float* cca1_c2_bn = (const float*)d_in[19];
  const float* cca1_c1_w = (const float*)d_in[20];
  const float* cca1_c1_bn = (const float*)d_in[21];
  const float* cca1_p_w = (const float*)d_in[22];
  const float* cca1_p_bn = (const float*)d_in[23];
  const float* meta_w1 = (const float*)d_in[24];
  const float* meta_w2 = (const float*)d_in[25];
  const float* meta_b2 = (const float*)d_in[26];
  const float* ene_w1 = (const float*)d_in[27];
  const float* ene_w2 = (const float*)d_in[28];
  const float* ene_b2 = (const float*)d_in[29];
  const float* mcls_w1 = (const float*)d_in[30];
  const float* mcls_b1 = (const float*)d_in[31];
  const float* mcls_w2 = (const float*)d_in[32];
  const float* mcls_b2 = (const float*)d_in[33];
  const float* ecls_w1 = (const float*)d_in[34];
  const float* ecls_b1 = (const float*)d_in[35];
  const float* ecls_w2 = (const float*)d_in[36];
  const float* ecls_b2 = (const float*)d_in[37];

  float* ws = (float*)d_ws;
  float* PART = ws + OFF_XN;   // 64x8x49 partial sums
  unsigned short* Y1BF = (unsigned short*)(ws + OFF_Y1BF);
  unsigned* KMTU = (unsigned*)(ws + OFF_KMT);
  unsigned short* W2BF = (unsigned short*)(ws + OFF_W2BF);
  unsigned short* Y2BF = (unsigned short*)(ws + OFF_Y2BF);
  float* T = ws + OFF_T;
  float* XPN = ws + OFF_XPN;
  float* SQ = ws + OFF_SQ;
  float* S0P = ws + OFF_S0P;
  float* S1Y1 = ws + OFF_S1Y1;
  float* S1Y2 = ws + OFF_S1Y2;
  float* ATT = ws + OFF_ATT;
  float* EPI = ws + OFF_EPI;
  float* H1 = ws + OFF_H1;
  float* EM3 = ws + OFF_EM3;
  float* H2 = ws + OFF_H2;
  float* WOUTT = ws + OFF_WOUTT;
  float* CCAT = ws + OFF_CCAT;
  float* MCLST = ws + OFF_MCLST;
  float* ECLST = ws + OFF_ECLST;
  unsigned* WBF = (unsigned*)(ws + OFF_WBF);

  // weight preps
  k_transpose_t<<<dim3(3, 30), 256, 0, stream>>>(scr_w_out, WOUTT, 960, 96);
  k_transpose_t<<<dim3(30, 3), 256, 0, stream>>>(cca1x1_w, CCAT, 96, 960);
  k_transpose_t<<<dim3(30, 60), 256, 0, stream>>>(mcls_w1, MCLST, 1920, 960);
  k_transpose_t<<<dim3(30, 60), 256, 0, stream>>>(ecls_w1, ECLST, 1920, 960);
  k_prepwbf<<<180, 256, 0, stream>>>(scr_w_in, WBF);
  k_kmat<<<4256, 256, 0, stream>>>(scr_w1, KMTU);
  k_w2bf<<<336, 256, 0, stream>>>(scr_w2, W2BF);

  for (int br = 0; br < 2; ++br) {
    const float* x = br ? x_i : x_p;
    k_l2npart<<<dim3(64, 8), 256, 0, stream>>>(x, PART);
    k_scr_in<<<dim3(64, 7), 512, 0, stream>>>(x, PART, WBF, scr_bn_in, Y1BF);
    k_conv1g<<<dim3(64, 7), 256, 0, stream>>>((const unsigned*)Y1BF, KMTU,
                                              scr_bn1, Y2BF);
    k_conv2g<<<98, 256, 0, stream>>>((const unsigned*)Y2BF, (const unsigned*)W2BF,
                                     scr_bn2, T);
    k_out_cca<<<dim3(64, 7), 512, 0, stream>>>(T, WOUTT, scr_bn_out, x, CCAT,
                                               cca1x1_bn, XPN + br * 3010560,
                                               SQ + br * 301056);
  }
  k_mid<<<64, 512, 0, stream>>>(SQ, SQ + 301056, cca0_c2_w, cca0_c2_bn,
                                cca0_c1_w, cca0_c1_bn, cca0_p_w, cca0_p_bn, S0P);
  k_sep1a<<<dim3(64, 7), 512, 0, stream>>>(S0P, cca1_c2_w, cca1_c2_bn, S1Y1);
  k_sep1b<<<dim3(64, 7), 512, 0, stream>>>(S1Y1, cca1_c1_w, cca1_c1_bn, S1Y2);
  k_c4attn<<<64, 256, 0, stream>>>(S1Y2, cca1_p_w, cca1_p_bn, ATT, ATT + 3136);
  k_pool<<<dim3(64, 2), 256, 0, stream>>>(XPN, ATT, EPI);

  hipMemsetAsync(H1, 0, (245760u + 122880u) * sizeof(float), stream);
  k_gemm64<<<dim3(30, 8, 2), 256, 0, stream>>>(EPI, EPI + 122880, 960, 0,
                                               meta_w1, ene_w1, 1920, 240,
                                               H1, H1 + 122880, 1920, 960);
  k_gemm64<<<dim3(15, 8, 2), 256, 0, stream>>>(H1, nullptr, 0, 1,
                                               meta_w2, ene_w2, 1920, 240,
                                               EM3, EM3 + 61440, 960, 122880);
  k_cls1<<<dim3(8, 8, 2), 256, 0, stream>>>(EM3, meta_b2, ene_b2, MCLST, mcls_b1,
                                            ECLST, ecls_b1, H2);
  k_cls2<<<dim3(8, 2), 128, 0, stream>>>(H2, mcls_w2, mcls_b2, ecls_w2, ecls_b2,
                                         (float*)d_out);
}

// Round 9
// 722.325 us; speedup vs baseline: 1.0146x; 1.0146x over previous
//
#include <hip/hip_runtime.h>
#include <hip/hip_bf16.h>

// RtNet25DDualRENet forward. Round 14:
//  - k_scr_in v8: XOR-swizzle xc k-groups: word addr = j*36 + 4*(k4 ^ ((j>>3)&7)).
//    R8 counters: 6.28M conflict-cycles (~40% of kernel) from r2 window reads —
//    j2=12du+wp+dv collapses onto ~5/8 bank groups (12 ≡ 4 mod 8 defeats linear
//    remaps). (j>>3) is non-linear across the du-family {j,j+12,j+24,j+36,j+48}
//    => distinct XOR masks per du => <=2-way (free). Stores stay float4-aligned
//    and spread; store & read use the identical mapping.
//  - k_gemm64 v2 (verified R8) kept; everything else unchanged.

#define BNINV 0.9999950000374997f  // 1/sqrt(1+1e-5)

typedef __attribute__((ext_vector_type(8))) short bf16x8;
typedef __attribute__((ext_vector_type(4))) float f32x4;

__device__ inline unsigned short f2bf(float f) {
  union { float f; unsigned u; } x; x.f = f;
  unsigned r = x.u + 0x7fffu + ((x.u >> 16) & 1u);  // RNE
  return (unsigned short)(r >> 16);
}

// ---------------- workspace layout (float offsets) ----------------
#define OFF_XN      0u          // PART (64 x 8 x 49 partial sums)
#define OFF_Y1BF    3010560u    // bf16 [3136 pairs][2432]
#define OFF_KMT     6823936u    // bf16 [896 n][2432 k]
#define OFF_W2BF    7913472u    // bf16 [96][896]
#define OFF_Y2BF    7956480u    // bf16 [3136][896]
#define OFF_T       9361408u    // (b,49,96)
#define OFF_XPN     9662464u    // 2 x (b,49,960)
#define OFF_SQ      15683584u   // 2 x (b,49,96)
#define OFF_S0P     16285696u   // (b,16,49,49)
#define OFF_S1Y1    18744320u
#define OFF_S1Y2    21202944u
#define OFF_ATT     23661568u
#define OFF_EPI     23667840u
#define OFF_H1      23913600u   // 2 x (64,1920)
#define OFF_EM3     24159360u   // 2 x (64,960)
#define OFF_H2      24297600u
#define OFF_WOUTT   24328320u
#define OFF_CCAT    24420480u
#define OFF_MCLST   24512640u
#define OFF_ECLST   26355840u
#define OFF_WBF     28199040u   // 46080 uints (96x960 bf16 pairs)

// ---------------- tiled transpose ----------------
__global__ __launch_bounds__(256) void k_transpose_t(const float* __restrict__ in,
                                                     float* __restrict__ out,
                                                     int R, int C) {
  __shared__ float tl[32][33];
  int c0 = blockIdx.x * 32, r0 = blockIdx.y * 32;
  int tx = threadIdx.x & 31, ty = threadIdx.x >> 5;
#pragma unroll
  for (int i = 0; i < 4; ++i)
    tl[ty + i * 8][tx] = in[(r0 + ty + i * 8) * C + c0 + tx];
  __syncthreads();
#pragma unroll
  for (int i = 0; i < 4; ++i)
    out[(c0 + ty + i * 8) * R + r0 + tx] = tl[tx][ty + i * 8];
}

// ---- prep: scr_w_in -> packed bf16 pairs ----
__global__ void k_prepwbf(const float* __restrict__ w_in, unsigned* __restrict__ WbfU) {
  int i = blockIdx.x * 256 + threadIdx.x;
  if (i >= 46080) return;
  float a = w_in[2 * i], b = w_in[2 * i + 1];
  WbfU[i] = (unsigned)f2bf(a) | ((unsigned)f2bf(b) << 16);
}

// ---- prep: conv1 kernel matrix Kmat_t[n=(o,d)][k=(ic,pos)] bf16 [896][2432] ----
__global__ void k_kmat(const float* __restrict__ w1, unsigned* __restrict__ kmtu) {
  int i = blockIdx.x * 256 + threadIdx.x;
  if (i >= 896 * 1216) return;
  int n = i / 1216, ku = i % 1216;
  unsigned out = 0;
#pragma unroll
  for (int h = 0; h < 2; ++h) {
    int k = ku * 2 + h;
    float v = 0.f;
    if (n < 864 && k < 2400) {
      int o = n / 9, d = n % 9, i2 = d / 3, j2 = d % 3;
      int ic = k / 25, pos = k % 25, u = pos / 5, vv = pos % 5;
      int di = u - i2, dj = vv - j2;
      if ((unsigned)di < 3u && (unsigned)dj < 3u)
        v = w1[(o * 96 + ic) * 9 + di * 3 + dj];
    }
    out |= ((unsigned)f2bf(v)) << (16 * h);
  }
  kmtu[i] = out;
}

// ---- prep: w2 -> bf16 [96][896] ----
__global__ void k_w2bf(const float* __restrict__ w2, unsigned short* __restrict__ w2b) {
  int i = blockIdx.x * 256 + threadIdx.x;
  if (i >= 86016) return;
  int o2 = i / 896, k = i % 896;
  w2b[i] = (k < 864) ? f2bf(w2[o2 * 864 + k]) : (unsigned short)0;
}

// ---------------- K1: partial sum-of-squares of relu(x) per (b,p) ----------------
__global__ __launch_bounds__(256) void k_l2npart(const float* __restrict__ x,
                                                 float* __restrict__ part) {
  int b = blockIdx.x, sl = blockIdx.y, t = threadIdx.x;
  __shared__ float red[256];
  const float* xb = x + b * 47040 + sl * 5880;
  int p = t & 63, s2 = t >> 6;
  float s = 0.f;
  if (p < 49) {
#pragma unroll 6
    for (int c = 0; c < 30; ++c) {
      float v = xb[(s2 * 30 + c) * 49 + p];
      if (v > 0.f) s += v * v;
    }
  }
  red[t] = s;
  __syncthreads();
  if (t < 49)
    part[(b * 8 + sl) * 49 + t] = red[t] + red[t + 64] + red[t + 128] + red[t + 192];
}

// ------- K2: fused l2norm + self-corr x scr_w_in einsum + BN + relu (bf16 MFMA) -------
// grid (64 b, 7 h). v8: XOR-swizzled xc (conflict-free window reads).
__global__ __launch_bounds__(512) void k_scr_in(
    const float* __restrict__ x, const float* __restrict__ part,
    const unsigned* __restrict__ WbfU,
    const float* __restrict__ bn, unsigned short* __restrict__ y1bf) {
  const int b = blockIdx.x, h = blockIdx.y, t = threadIdx.x;
  const int wave = t >> 6, lane = t & 63, quad = lane >> 4, lr = lane & 15;
  const int mh = wave >> 2, ng = wave & 3;
  __shared__ __align__(16) short Pl[2][192 * 40];
  __shared__ __align__(16) short Wl[2][96 * 40];
  __shared__ __align__(16) float xc[2][2160];   // [j][k4 swizzled] stride 36
  __shared__ float invL[60];
  // zero-pad y1bf[pair][2400..2432)
  if (t < 112) {
    int pairL = t >> 4, ku = t & 15;
    ((unsigned*)y1bf)[(unsigned)(b * 49 + h * 7 + pairL) * 1216u + 1200u + ku] = 0u;
  }
  // per-padded-pixel inverse norms
  if (t < 60) {
    int r = t / 12, wc = t - r * 12;
    int row = h + r - 2, w = wc - 2;
    float iv = 0.f;
    if ((unsigned)row < 7u && (unsigned)w < 7u) {
      int p = row * 7 + w;
      float s = 0.f;
#pragma unroll
      for (int sl = 0; sl < 8; ++sl) s += part[(b * 8 + sl) * 49 + p];
      iv = 1.f / fmaxf(sqrtf(s), 1e-12f);
    }
    invL[t] = iv;
  }
  f32x4 acc[3][3];
#pragma unroll
  for (int m = 0; m < 3; ++m)
#pragma unroll
    for (int n = 0; n < 3; ++n) acc[m][n] = (f32x4){0.f, 0.f, 0.f, 0.f};
  const float* xb = x + b * 47040;
  // staging geometry: thread u<480 owns pixel j = u%60, k-group k4 = u/60 (4 k's)
  const int sj = t % 60, sk4 = t / 60;
  const bool sOk = (t < 480);
  const int sSwz = (sj >> 3) & 7;
  int pixOff = 0;
  bool pixIn = false;
  if (sOk) {
    int r = sj / 12, wc = sj - r * 12;
    int row = h + r - 2, w = wc - 2;
    pixIn = ((unsigned)row < 7u && (unsigned)w < 7u);
    pixOff = row * 7 + w;
  }
  const int colB = t >> 1, halfB = t & 1;
  int j1 = 0, j2 = 0;
  if (t < 384) {
    int cc = colB < 175 ? colB : 174;
    int wp = cc / 25, uv = cc - wp * 25, du = uv / 5, dv = uv - du * 5;
    j1 = 26 + wp;
    j2 = du * 12 + wp + dv;
  }
  const int swz1 = (j1 >> 3) & 7, swz2 = (j2 >> 3) & 7;
  float xr0[4] = {0.f, 0.f, 0.f, 0.f};
  unsigned wr0[3];
  // prefetch chunk 0
  {
    if (sOk && pixIn) {
      const float* src = &xb[(sk4 * 4) * 49 + pixOff];
#pragma unroll
      for (int q = 0; q < 4; ++q) xr0[q] = src[q * 49];
    }
#pragma unroll
    for (int it = 0; it < 3; ++it) {
      int i = t + it * 512;
      wr0[it] = WbfU[(i >> 4) * 480 + (i & 15)];
    }
  }
  __syncthreads();   // invL ready before first LDS store
  int p = 0;
  for (int c = 0; c < 30; ++c, p ^= 1) {
    // store prefetched regs into LDS buffer p (normalized); one float4/thread
    float* xcb = xc[p];
    if (sOk) {
      float iv = invL[sj];
      float4 v;
      v.x = fmaxf(xr0[0], 0.f) * iv;
      v.y = fmaxf(xr0[1], 0.f) * iv;
      v.z = fmaxf(xr0[2], 0.f) * iv;
      v.w = fmaxf(xr0[3], 0.f) * iv;
      *(float4*)&xcb[sj * 36 + 4 * (sk4 ^ sSwz)] = v;
    }
    unsigned* Wlu = (unsigned*)Wl[p];
#pragma unroll
    for (int it = 0; it < 3; ++it) {
      int i = t + it * 512;
      Wlu[(i >> 4) * 20 + (i & 15)] = wr0[it];
    }
    __syncthreads();
    // build P[p]: b128 reads at swizzled k-groups (window now <=2-way)
    if (t < 384) {
      float a[16], cc[16];
#pragma unroll
      for (int q = 0; q < 4; ++q) {
        int g = halfB * 4 + q;
        *(float4*)&a[q * 4]  = *(const float4*)&xcb[j1 * 36 + 4 * (g ^ swz1)];
        *(float4*)&cc[q * 4] = *(const float4*)&xcb[j2 * 36 + 4 * (g ^ swz2)];
      }
      unsigned pk[8];
#pragma unroll
      for (int q = 0; q < 8; ++q) {
        float v0 = a[q * 2] * cc[q * 2];
        float v1 = a[q * 2 + 1] * cc[q * 2 + 1];
        pk[q] = (unsigned)f2bf(v0) | ((unsigned)f2bf(v1) << 16);
      }
      unsigned* dst = (unsigned*)Pl[p] + colB * 20 + halfB * 8;
      *(uint4*)dst = *(uint4*)&pk[0];
      *(uint4*)(dst + 4) = *(uint4*)&pk[4];
    }
    __syncthreads();
    // prefetch chunk c+1 (rides across the MFMA phase)
    if (c < 29) {
      const int k0 = (c + 1) * 32;
      if (sOk) {
        if (pixIn) {
          const float* src = &xb[(k0 + sk4 * 4) * 49 + pixOff];
#pragma unroll
          for (int q = 0; q < 4; ++q) xr0[q] = src[q * 49];
        }
      }
      int base = k0 >> 1;
#pragma unroll
      for (int it = 0; it < 3; ++it) {
        int i = t + it * 512;
        wr0[it] = WbfU[(i >> 4) * 480 + base + (i & 15)];
      }
    }
    // MFMA on buffer p
    const int ko = quad * 8;
    bf16x8 af[3], bfr[3];
#pragma unroll
    for (int m = 0; m < 3; ++m)
      af[m] = *(const bf16x8*)&Wl[p][((mh * 3 + m) * 16 + lr) * 40 + ko];
#pragma unroll
    for (int n = 0; n < 3; ++n)
      bfr[n] = *(const bf16x8*)&Pl[p][((ng * 3 + n) * 16 + lr) * 40 + ko];
#pragma unroll
    for (int m = 0; m < 3; ++m)
#pragma unroll
      for (int n = 0; n < 3; ++n)
        acc[m][n] = __builtin_amdgcn_mfma_f32_16x16x32_bf16(
            af[m], bfr[n], acc[m][n], 0, 0, 0);
  }
  // epilogue: C/D col=lane&15, row=quad*4+reg
#pragma unroll
  for (int n = 0; n < 3; ++n) {
    int col = (ng * 3 + n) * 16 + lr;
    if (col >= 175) continue;
    int wp = col / 25, uv = col - wp * 25;
    unsigned pairIdx = (unsigned)(b * 49 + h * 7 + wp);
#pragma unroll
    for (int m = 0; m < 3; ++m) {
#pragma unroll
      for (int r = 0; r < 4; ++r) {
        int o = (mh * 3 + m) * 16 + quad * 4 + r;
        float g = BNINV * bn[o], bt = bn[96 + o];
        float v = fmaxf(acc[m][n][r] * g + bt, 0.f);
        y1bf[pairIdx * 2432u + (unsigned)(o * 25 + uv)] = f2bf(v);
      }
    }
  }
}

// ------- K3: conv1 MFMA GEMM. grid (64 m-slots [49 used], 7 n) -------
__global__ __launch_bounds__(256) void k_conv1g(
    const unsigned* __restrict__ y1u, const unsigned* __restrict__ kmtu,
    const float* __restrict__ bn1, unsigned short* __restrict__ y2bf) {
  if (blockIdx.x >= 49) return;
  const int t = threadIdx.x;
  const int wave = t >> 6, lane = t & 63, quad = lane >> 4, lr = lane & 15;
  const int mh = wave >> 1, nh = wave & 1;
  const int pairBase = blockIdx.x * 64, nBase = blockIdx.y * 128;
  __shared__ __align__(16) short Ash[64 * 72];
  __shared__ __align__(16) short Bsh[128 * 72];
  __shared__ float bnl[192];
  unsigned* Au = (unsigned*)Ash;
  unsigned* Bu = (unsigned*)Bsh;
  if (t < 192) bnl[t] = bn1[t];
  f32x4 acc[2][4];
#pragma unroll
  for (int m = 0; m < 2; ++m)
#pragma unroll
    for (int n = 0; n < 4; ++n) acc[m][n] = (f32x4){0.f, 0.f, 0.f, 0.f};
  const int prA = t >> 2, qA = t & 3;
  const int nB = t >> 1, qB = t & 1;
  for (int c = 0; c < 38; ++c) {
    int ku0 = c * 32;
    __syncthreads();
    {
      const unsigned* src = y1u + (unsigned)(pairBase + prA) * 1216u + ku0 + qA * 8;
      unsigned* dst = Au + prA * 36 + qA * 8;
      *(uint4*)dst = *(const uint4*)src;
      *(uint4*)(dst + 4) = *(const uint4*)(src + 4);
    }
    {
      const unsigned* src = kmtu + (unsigned)(nBase + nB) * 1216u + ku0 + qB * 16;
      unsigned* dst = Bu + nB * 36 + qB * 16;
#pragma unroll
      for (int q = 0; q < 4; ++q)
        *(uint4*)(dst + q * 4) = *(const uint4*)(src + q * 4);
    }
    __syncthreads();
#pragma unroll
    for (int s = 0; s < 2; ++s) {
      int ko = s * 32 + quad * 8;
      bf16x8 af[2], bf[4];
#pragma unroll
      for (int m = 0; m < 2; ++m)
        af[m] = *(const bf16x8*)&Ash[((mh * 2 + m) * 16 + lr) * 72 + ko];
#pragma unroll
      for (int n = 0; n < 4; ++n)
        bf[n] = *(const bf16x8*)&Bsh[((nh * 4 + n) * 16 + lr) * 72 + ko];
#pragma unroll
      for (int m = 0; m < 2; ++m)
#pragma unroll
        for (int n = 0; n < 4; ++n)
          acc[m][n] = __builtin_amdgcn_mfma_f32_16x16x32_bf16(
              af[m], bf[n], acc[m][n], 0, 0, 0);
    }
  }
#pragma unroll
  for (int m = 0; m < 2; ++m) {
#pragma unroll
    for (int r = 0; r < 4; ++r) {
      unsigned pair = (unsigned)(pairBase + (mh * 2 + m) * 16 + quad * 4 + r);
#pragma unroll
      for (int n = 0; n < 4; ++n) {
        int nn = nBase + (nh * 4 + n) * 16 + lr;
        unsigned short outv = 0;
        if (nn < 864) {
          int o = nn / 9;
          float v = fmaxf(acc[m][n][r] * (BNINV * bnl[o]) + bnl[96 + o], 0.f);
          outv = f2bf(v);
        }
        y2bf[pair * 896u + nn] = outv;
      }
    }
  }
}

// ------- K4: conv2 MFMA GEMM, 98 blocks of 32 pairs -------
__global__ __launch_bounds__(256) void k_conv2g(
    const unsigned* __restrict__ y2u, const unsigned* __restrict__ w2u,
    const float* __restrict__ bn2, float* __restrict__ tout) {
  const int t = threadIdx.x;
  const int wave = t >> 6, lane = t & 63, quad = lane >> 4, lr = lane & 15;
  const int mh = wave >> 1, nh = wave & 1;
  const int pairBase = blockIdx.x * 32;
  __shared__ __align__(16) short Ash[32 * 72];
  __shared__ __align__(16) short Bsh[96 * 72];
  __shared__ float bnl[192];
  unsigned* Au = (unsigned*)Ash;
  unsigned* Bu = (unsigned*)Bsh;
  if (t < 192) bnl[t] = bn2[t];
  f32x4 acc[3];
#pragma unroll
  for (int n = 0; n < 3; ++n) acc[n] = (f32x4){0.f, 0.f, 0.f, 0.f};
  const int prA = t >> 3, qA = (t & 7) * 4;
  const int nB = t >> 1, qB = (t & 1) * 16;
  for (int c = 0; c < 14; ++c) {
    int ku0 = c * 32;
    __syncthreads();
    {
      const unsigned* src = y2u + (unsigned)(pairBase + prA) * 448u + ku0 + qA;
      *(uint4*)(Au + prA * 36 + qA) = *(const uint4*)src;
    }
    if (t < 192) {
      const unsigned* src = w2u + (unsigned)nB * 448u + ku0 + qB;
      unsigned* dst = Bu + nB * 36 + qB;
#pragma unroll
      for (int q = 0; q < 4; ++q)
        *(uint4*)(dst + q * 4) = *(const uint4*)(src + q * 4);
    }
    __syncthreads();
#pragma unroll
    for (int s = 0; s < 2; ++s) {
      int ko = s * 32 + quad * 8;
      bf16x8 af;
      af = *(const bf16x8*)&Ash[(mh * 16 + lr) * 72 + ko];
#pragma unroll
      for (int n = 0; n < 3; ++n) {
        bf16x8 bf = *(const bf16x8*)&Bsh[((nh * 3 + n) * 16 + lr) * 72 + ko];
        acc[n] = __builtin_amdgcn_mfma_f32_16x16x32_bf16(af, bf, acc[n], 0, 0, 0);
      }
    }
  }
#pragma unroll
  for (int r = 0; r < 4; ++r) {
    unsigned pair = (unsigned)(pairBase + mh * 16 + quad * 4 + r);
#pragma unroll
    for (int n = 0; n < 3; ++n) {
      int o = (nh * 3 + n) * 16 + lr;
      float v = fmaxf(acc[n][r] * (BNINV * bnl[o]) + bnl[96 + o], 0.f);
      tout[pair * 96u + o] = v;
    }
  }
}

// ------- K5: fused w_out GEMM + BN + residual relu + mean-sub + cca1 + l2norm -------
__global__ __launch_bounds__(512) void k_out_cca(
    const float* __restrict__ tin, const float* __restrict__ wouT,
    const float* __restrict__ bno, const float* __restrict__ x,
    const float* __restrict__ ccaT, const float* __restrict__ bnc,
    float* __restrict__ xpn, float* __restrict__ sq) {
  int b = blockIdx.x, pr = blockIdx.y, t = threadIdx.x;
  __shared__ __align__(16) float tl2[96 * 8];     // 3.0 KB  [ic][pl]
  __shared__ __align__(16) float xrT[960 * 8];    // 30.0 KB [o][pl] : x then y
  __shared__ float red[8 * 520];                  // 16.3 KB pl-major scratch
  __shared__ float mean[7];
  __shared__ float sv[7 * 97];
  __shared__ float inv7[7];
  for (int i = t; i < 672; i += 512) {
    int pl = i / 96, ic = i - pl * 96;
    tl2[ic * 8 + pl] = tin[(b * 49 + pr * 7 + pl) * 96 + ic];
  }
  for (int i = t; i < 6720; i += 512) {
    int o = i / 7, pl = i - o * 7;
    xrT[o * 8 + pl] = x[(b * 960 + o) * 49 + pr * 7 + pl];
  }
  __syncthreads();
  float acc0[7] = {0.f, 0.f, 0.f, 0.f, 0.f, 0.f, 0.f};
  float acc1[7] = {0.f, 0.f, 0.f, 0.f, 0.f, 0.f, 0.f};
  const bool has1 = (t < 448);
  const int o1 = has1 ? t + 512 : t;
#pragma unroll 8
  for (int ic = 0; ic < 96; ++ic) {
    float tv[8];
    *(float4*)&tv[0] = *(const float4*)&tl2[ic * 8];
    *(float4*)&tv[4] = *(const float4*)&tl2[ic * 8 + 4];
    float w0 = wouT[ic * 960 + t];
    float w1 = wouT[ic * 960 + o1];
#pragma unroll
    for (int pl = 0; pl < 7; ++pl) {
      acc0[pl] += w0 * tv[pl];
      acc1[pl] += w1 * tv[pl];
    }
  }
  float part[7] = {0.f, 0.f, 0.f, 0.f, 0.f, 0.f, 0.f};
  {
    float xv[8];
    *(float4*)&xv[0] = *(const float4*)&xrT[t * 8];
    *(float4*)&xv[4] = *(const float4*)&xrT[t * 8 + 4];
    float g = BNINV * bno[t], bt = bno[960 + t];
#pragma unroll
    for (int pl = 0; pl < 7; ++pl) {
      float v = fmaxf(xv[pl] + acc0[pl] * g + bt, 0.f);
      acc0[pl] = v; part[pl] += v;
      xrT[t * 8 + pl] = v;
    }
  }
  if (has1) {
    float xv[8];
    *(float4*)&xv[0] = *(const float4*)&xrT[o1 * 8];
    *(float4*)&xv[4] = *(const float4*)&xrT[o1 * 8 + 4];
    float g = BNINV * bno[o1], bt = bno[960 + o1];
#pragma unroll
    for (int pl = 0; pl < 7; ++pl) {
      float v = fmaxf(xv[pl] + acc1[pl] * g + bt, 0.f);
      acc1[pl] = v; part[pl] += v;
      xrT[o1 * 8 + pl] = v;
    }
  }
#pragma unroll
  for (int pl = 0; pl < 7; ++pl) red[pl * 520 + t] = part[pl];
  __syncthreads();
  if (t < 64) {
#pragma unroll
    for (int pl = 0; pl < 7; ++pl) {
      float s = 0.f;
#pragma unroll
      for (int j = 0; j < 8; ++j) s += red[pl * 520 + t + j * 64];
      red[pl * 520 + t] = s;
    }
  }
  __syncthreads();
  if (t < 7) {
    float s = 0.f;
    for (int i = 0; i < 64; ++i) s += red[t * 520 + i];
    mean[t] = s * (1.f / 960.f);
  }
  __syncthreads();
#pragma unroll
  for (int pl = 0; pl < 7; ++pl)
    xpn[(b * 49 + pr * 7 + pl) * 960 + t] = acc0[pl] - mean[pl];
  if (has1) {
#pragma unroll
    for (int pl = 0; pl < 7; ++pl)
      xpn[(b * 49 + pr * 7 + pl) * 960 + o1] = acc1[pl] - mean[pl];
  }
  float acc2[7] = {0.f, 0.f, 0.f, 0.f, 0.f, 0.f, 0.f};
  float sw = 0.f;
  int o2 = t % 96, csl = t / 96;
  if (t < 480) {
    int c0 = csl * 192;
#pragma unroll 8
    for (int c = c0; c < c0 + 192; ++c) {
      float w = ccaT[c * 96 + o2];
      sw += w;
      float tv[8];
      *(float4*)&tv[0] = *(const float4*)&xrT[c * 8];
      *(float4*)&tv[4] = *(const float4*)&xrT[c * 8 + 4];
#pragma unroll
      for (int pl = 0; pl < 7; ++pl) acc2[pl] += w * tv[pl];
    }
#pragma unroll
    for (int pl = 0; pl < 7; ++pl) red[pl * 520 + t] = acc2[pl];
    red[7 * 520 + t] = sw;
  }
  __syncthreads();
  if (t < 96) {
    float g = BNINV * bnc[t], bt = bnc[96 + t];
    float swt = 0.f;
#pragma unroll
    for (int s5 = 0; s5 < 5; ++s5) swt += red[7 * 520 + s5 * 96 + t];
#pragma unroll
    for (int pl = 0; pl < 7; ++pl) {
      float a = 0.f;
#pragma unroll
      for (int s5 = 0; s5 < 5; ++s5) a += red[pl * 520 + s5 * 96 + t];
      a -= mean[pl] * swt;
      sv[pl * 97 + t] = fmaxf(a * g + bt, 0.f);
    }
  }
  __syncthreads();
  if (t < 112) {
    int pl = t >> 4, ln = t & 15;
    float s = 0.f;
    for (int o = ln; o < 96; o += 16) { float v = sv[pl * 97 + o]; s += v * v; }
    red[pl * 16 + ln] = s;
  }
  __syncthreads();
  if (t < 7) {
    float s = 0.f;
    for (int i = 0; i < 16; ++i) s += red[t * 16 + i];
    inv7[t] = 1.f / fmaxf(sqrtf(s), 1e-8f);
  }
  __syncthreads();
  for (int i = t; i < 672; i += 512) {
    int pl = i / 96, o = i - pl * 96;
    sq[(b * 49 + pr * 7 + pl) * 96 + o] = sv[pl * 97 + o] * inv7[pl];
  }
}

// ------- K7: fused corr + sep4d#0 (512 threads) -------
__global__ __launch_bounds__(512) void k_mid(
    const float* __restrict__ sq0, const float* __restrict__ sq1,
    const float* __restrict__ wuv, const float* __restrict__ bnuv,
    const float* __restrict__ wkl, const float* __restrict__ bnkl,
    const float* __restrict__ pw16, const float* __restrict__ pbn16,
    float* __restrict__ s0p) {
  int b = blockIdx.x, t = threadIdx.x;
  __shared__ float smem[12496];
  float* sL = smem;
  float* qL = smem + 5047;
  float* A = smem + 10094;
  for (int i = t; i < 4704; i += 512) {
    int p = i / 96, c = i % 96;
    sL[p * 103 + c] = sq0[b * 4704 + i];
    qL[p * 103 + c] = sq1[b * 4704 + i];
  }
  __syncthreads();
  for (int i = t; i < 2401; i += 512) {
    int ij = i / 49, kl = i % 49;
    float a = 0.f;
#pragma unroll 4
    for (int c = 0; c < 96; ++c) a += sL[ij * 103 + c] * qL[kl * 103 + c];
    A[i] = a;
  }
  __syncthreads();
  float* B = smem;
  {
    float w0[9];
#pragma unroll
    for (int d = 0; d < 9; ++d) w0[d] = wuv[d];
    float g = BNINV * bnuv[0], bt = bnuv[1];
    for (int i = t; i < 2401; i += 512) {
      int ij = i / 49, kl = i % 49;
      int u = ij / 7, v = ij % 7;
      float a = 0.f;
#pragma unroll
      for (int du = 0; du < 3; ++du) {
        int uu = u + du - 1;
        if ((unsigned)uu >= 7u) continue;
#pragma unroll
        for (int dv = 0; dv < 3; ++dv) {
          int vv = v + dv - 1;
          if ((unsigned)vv >= 7u) continue;
          a += w0[du * 3 + dv] * A[(uu * 7 + vv) * 49 + kl];
        }
      }
      B[i] = fmaxf(a * g + bt, 0.f);
    }
  }
  __syncthreads();
  float* Cc = smem + 4900;
  {
    float w1[9];
#pragma unroll
    for (int d = 0; d < 9; ++d) w1[d] = wkl[d];
    float g = BNINV * bnkl[0], bt = bnkl[1];
    for (int i = t; i < 2401; i += 512) {
      int ij = i / 49, kl = i % 49;
      int kk = kl / 7, ll = kl % 7;
      float a = 0.f;
#pragma unroll
      for (int dh = 0; dh < 3; ++dh) {
        int k2 = kk + dh - 1;
        if ((unsigned)k2 >= 7u) continue;
#pragma unroll
        for (int dw = 0; dw < 3; ++dw) {
          int l2 = ll + dw - 1;
          if ((unsigned)l2 >= 7u) continue;
          a += w1[dh * 3 + dw] * B[ij * 49 + k2 * 7 + l2];
        }
      }
      Cc[i] = a * g + bt;
    }
  }
  __syncthreads();
  for (int o = 0; o < 16; ++o) {
    float sc = pw16[o] * BNINV * pbn16[o], bt2 = pbn16[16 + o];
    for (int i = t; i < 2401; i += 512)
      s0p[(b * 16 + o) * 2401 + i] = fmaxf(Cc[i] * sc + bt2, 0.f);
  }
}

// ---------------- sep4d #1 conv a. grid (64 b, 7 kc), 512 thr ----------------
__global__ __launch_bounds__(512) void k_sep1a(
    const float* __restrict__ in, const float* __restrict__ w,
    const float* __restrict__ bnp, float* __restrict__ out) {
  int b = blockIdx.x, kc = blockIdx.y, t = threadIdx.x;
  __shared__ float inS[16 * 345];
  __shared__ __align__(16) float wP[3072];
  for (int i = t; i < 3072; i += 512) {
    int oc = i / 12, d = i % 12;
    wP[i] = (d < 9) ? w[oc * 9 + d] : 0.f;
  }
  for (int i = t; i < 5488; i += 512) {
    int ic = i / 343, r = i - ic * 343;
    int ij = r / 7, s = r - ij * 7;
    inS[ic * 345 + s * 49 + ij] = in[(b * 16 + ic) * 2401 + ij * 49 + kc * 7 + s];
  }
  __syncthreads();
  for (int rho = t; rho < 784; rho += 512) {
    int o = rho / 49, rem = rho - o * 49, u = rem / 7, s = rem - u * 7;
    float acc[7] = {0.f, 0.f, 0.f, 0.f, 0.f, 0.f, 0.f};
    for (int ic = 0; ic < 16; ++ic) {
      float wv[12];
      const float* wb = &wP[(o * 16 + ic) * 12];
      *(float4*)&wv[0] = *(const float4*)&wb[0];
      *(float4*)&wv[4] = *(const float4*)&wb[4];
      *(float4*)&wv[8] = *(const float4*)&wb[8];
      const float* rowb = &inS[ic * 345 + s * 49];
#pragma unroll
      for (int du = 0; du < 3; ++du) {
        int uu = u + du - 1;
        if ((unsigned)uu >= 7u) continue;
        const float* rr = rowb + uu * 7;
        float r7[7];
#pragma unroll
        for (int q = 0; q < 7; ++q) r7[q] = rr[q];
#pragma unroll
        for (int v = 0; v < 7; ++v) {
          float a = acc[v];
          if (v > 0) a += wv[du * 3 + 0] * r7[v - 1];
          a += wv[du * 3 + 1] * r7[v];
          if (v < 6) a += wv[du * 3 + 2] * r7[v + 1];
          acc[v] = a;
        }
      }
    }
    float g = BNINV * bnp[o], bt = bnp[16 + o];
    long ob = (long)(b * 16 + o) * 2401 + kc * 7 + s;
#pragma unroll
    for (int v = 0; v < 7; ++v)
      out[ob + (u * 7 + v) * 49] = fmaxf(acc[v] * g + bt, 0.f);
  }
}

// ---------------- sep4d #1 conv b. grid (64 b, 7 ir), 512 thr ----------------
__global__ __launch_bounds__(512) void k_sep1b(
    const float* __restrict__ in, const float* __restrict__ w,
    const float* __restrict__ bnp, float* __restrict__ out) {
  int b = blockIdx.x, ir = blockIdx.y, t = threadIdx.x;
  __shared__ float inS[16 * 345];
  __shared__ __align__(16) float wP[3072];
  for (int i = t; i < 3072; i += 512) {
    int oc = i / 12, d = i % 12;
    wP[i] = (d < 9) ? w[oc * 9 + d] : 0.f;
  }
  for (int i = t; i < 5488; i += 512) {
    int ic = i / 343, r = i - ic * 343;
    inS[ic * 345 + r] = in[(b * 16 + ic) * 2401 + ir * 343 + r];
  }
  __syncthreads();
  for (int rho = t; rho < 784; rho += 512) {
    int o = rho / 49, rem = rho - o * 49, jj = rem / 7, k = rem - jj * 7;
    float acc[7] = {0.f, 0.f, 0.f, 0.f, 0.f, 0.f, 0.f};
    for (int ic = 0; ic < 16; ++ic) {
      float wv[12];
      const float* wb = &wP[(o * 16 + ic) * 12];
      *(float4*)&wv[0] = *(const float4*)&wb[0];
      *(float4*)&wv[4] = *(const float4*)&wb[4];
      *(float4*)&wv[8] = *(const float4*)&wb[8];
      const float* rowb = &inS[ic * 345 + jj * 49];
#pragma unroll
      for (int dh = 0; dh < 3; ++dh) {
        int k2 = k + dh - 1;
        if ((unsigned)k2 >= 7u) continue;
        const float* rr = rowb + k2 * 7;
        float r7[7];
#pragma unroll
        for (int q = 0; q < 7; ++q) r7[q] = rr[q];
#pragma unroll
        for (int l = 0; l < 7; ++l) {
          float a = acc[l];
          if (l > 0) a += wv[dh * 3 + 0] * r7[l - 1];
          a += wv[dh * 3 + 1] * r7[l];
          if (l < 6) a += wv[dh * 3 + 2] * r7[l + 1];
          acc[l] = a;
        }
      }
    }
    float g = BNINV * bnp[o], bt = bnp[16 + o];
    long ob = (long)(b * 16 + o) * 2401 + ir * 343 + jj * 49 + k * 7;
#pragma unroll
    for (int l = 0; l < 7; ++l)
      out[ob + l] = acc[l] * g + bt;
  }
}

// ------- K10: fused sep1p + gauss-softmax attention (dual-phase concurrent) -------
__global__ __launch_bounds__(256) void k_c4attn(
    const float* __restrict__ in, const float* __restrict__ pw,
    const float* __restrict__ pbn, float* __restrict__ attn_s,
    float* __restrict__ attn_q) {
  int b = blockIdx.x, t = threadIdx.x;
  __shared__ float c[2401];
  __shared__ float nA[2401];
  __shared__ float nB[2401];
  __shared__ float plw[16];
  if (t < 16) plw[t] = pw[t];
  __syncthreads();
  float g0 = BNINV * pbn[0], bt0 = pbn[1];
  for (int i = t; i < 2401; i += 256) {
    float a = 0.f;
#pragma unroll
    for (int ic = 0; ic < 16; ++ic) a += plw[ic] * in[(b * 16 + ic) * 2401 + i];
    c[i] = a * g0 + bt0;
  }
  __syncthreads();
  if (t < 49) {
    float m = 0.f;
    for (int ij = 0; ij < 49; ++ij) m += c[ij * 49 + t];
    m *= (1.f / 49.f);
    float v = 0.f;
    for (int ij = 0; ij < 49; ++ij) { float d = c[ij * 49 + t] - m; v += d * d; }
    v *= (1.f / 48.f);
    float inv = 1.f / sqrtf(v + 1e-5f);
    float mx = -1e30f;
    for (int ij = 0; ij < 49; ++ij) mx = fmaxf(mx, (c[ij * 49 + t] - m) * inv);
    float s = 0.f;
    for (int ij = 0; ij < 49; ++ij) {
      float e = expf((c[ij * 49 + t] - m) * inv - mx);
      nA[ij * 49 + t] = e; s += e;
    }
    float r = 1.f / s;
    for (int ij = 0; ij < 49; ++ij) nA[ij * 49 + t] *= r;
  } else if (t >= 64 && t < 113) {
    int t2 = t - 64;
    float m = 0.f;
    for (int kl = 0; kl < 49; ++kl) m += c[t2 * 49 + kl];
    m *= (1.f / 49.f);
    float v = 0.f;
    for (int kl = 0; kl < 49; ++kl) { float d = c[t2 * 49 + kl] - m; v += d * d; }
    v *= (1.f / 48.f);
    float inv = 1.f / sqrtf(v + 1e-5f);
    float mx = -1e30f;
    for (int kl = 0; kl < 49; ++kl) mx = fmaxf(mx, (c[t2 * 49 + kl] - m) * inv);
    float s = 0.f;
    for (int kl = 0; kl < 49; ++kl) {
      float e = expf((c[t2 * 49 + kl] - m) * inv - mx);
      nB[t2 * 49 + kl] = e; s += e;
    }
    float r = 1.f / s;
    for (int kl = 0; kl < 49; ++kl) nB[t2 * 49 + kl] *= r;
  }
  __syncthreads();
  if (t < 49) {
    float s = 0.f;
    for (int kl = 0; kl < 49; ++kl) s += nA[t * 49 + kl];
    attn_s[b * 49 + t] = s;
  } else if (t >= 64 && t < 113) {
    int t2 = t - 64;
    float s = 0.f;
    for (int ij = 0; ij < 49; ++ij) s += nB[ij * 49 + t2];
    attn_q[b * 49 + t2] = s;
  }
}

// ------- K11: attention-weighted mean/max pooling -------
__global__ __launch_bounds__(256) void k_pool(const float* __restrict__ xpn,
                                              const float* __restrict__ attn,
                                              float* __restrict__ ep) {
  int b = blockIdx.x, br = blockIdx.y, t = threadIdx.x;
  const float* xb = xpn + br * 3010560 + b * 47040;
  const float* a = attn + br * 3136 + b * 49;
  __shared__ float al[49];
  if (t < 49) al[t] = a[t];
  __syncthreads();
  float* eb = ep + br * 122880 + b * 1920;
  for (int c = t; c < 960; c += 256) {
    float s = 0.f, mx = -1e30f;
#pragma unroll 7
    for (int hw = 0; hw < 49; ++hw) {
      float v = al[hw] * xb[hw * 960 + c];
      s += v; mx = fmaxf(mx, v);
    }
    eb[c] = s * (1.f / 49.f);
    eb[960 + c] = mx;
  }
}

// ------- M=64 GEMM, split-K with atomicAdd; z selects meta/ene -------
// v2: register prefetch + double-buffered LDS, one barrier per 48-k chunk.
__global__ __launch_bounds__(256) void k_gemm64(
    const float* __restrict__ A0, const float* __restrict__ A1, int asplit,
    int reluA, const float* __restrict__ Wm, const float* __restrict__ We,
    int K, int Kslice, float* __restrict__ Cm, float* __restrict__ Ce,
    int N, int zAoff) {
  int otile = blockIdx.x, ks = blockIdx.y, z = blockIdx.z;
  const float* W = z ? We : Wm;
  float* C = z ? Ce : Cm;
  int zo = z * zAoff;
  int t = threadIdx.x, bt = t >> 4, ot = t & 15;
  __shared__ __align__(16) float eT[2][48 * 68];
  __shared__ __align__(16) float wT[2][48 * 68];
  float acc[4][4];
#pragma unroll
  for (int i = 0; i < 4; ++i)
#pragma unroll
    for (int j = 0; j < 4; ++j) acc[i][j] = 0.f;
  const int kbeg = ks * Kslice;
  const int nch = Kslice / 48;
  int sb[3], skg[3];
#pragma unroll
  for (int it = 0; it < 3; ++it) {
    int i = t + it * 256;
    sb[it] = i / 12;
    skg[it] = i % 12;
  }
  float4 ra[3], rw[3];
#pragma unroll
  for (int it = 0; it < 3; ++it) {
    int k = kbeg + skg[it] * 4;
    float4 v;
    if (asplit) {
      v = (k < asplit) ? *(const float4*)&A0[sb[it] * 1920 + zo + k]
                       : *(const float4*)&A1[sb[it] * 1920 + zo + k - asplit];
    } else {
      v = *(const float4*)&A0[zo + sb[it] * K + k];
    }
    if (reluA) {
      v.x = fmaxf(v.x, 0.f); v.y = fmaxf(v.y, 0.f);
      v.z = fmaxf(v.z, 0.f); v.w = fmaxf(v.w, 0.f);
    }
    ra[it] = v;
    rw[it] = *(const float4*)&W[(otile * 64 + sb[it]) * K + kbeg + skg[it] * 4];
  }
  int p = 0;
  for (int c = 0; c < nch; ++c, p ^= 1) {
#pragma unroll
    for (int it = 0; it < 3; ++it) {
      int row4 = skg[it] * 4, col = sb[it];
      float4 v = ra[it];
      eT[p][(row4 + 0) * 68 + col] = v.x; eT[p][(row4 + 1) * 68 + col] = v.y;
      eT[p][(row4 + 2) * 68 + col] = v.z; eT[p][(row4 + 3) * 68 + col] = v.w;
      float4 w = rw[it];
      wT[p][(row4 + 0) * 68 + col] = w.x; wT[p][(row4 + 1) * 68 + col] = w.y;
      wT[p][(row4 + 2) * 68 + col] = w.z; wT[p][(row4 + 3) * 68 + col] = w.w;
    }
    __syncthreads();
    if (c + 1 < nch) {
      int k0 = kbeg + (c + 1) * 48;
#pragma unroll
      for (int it = 0; it < 3; ++it) {
        int k = k0 + skg[it] * 4;
        float4 v;
        if (asplit) {
          v = (k < asplit) ? *(const float4*)&A0[sb[it] * 1920 + zo + k]
                           : *(const float4*)&A1[sb[it] * 1920 + zo + k - asplit];
        } else {
          v = *(const float4*)&A0[zo + sb[it] * K + k];
        }
        if (reluA) {
          v.x = fmaxf(v.x, 0.f); v.y = fmaxf(v.y, 0.f);
          v.z = fmaxf(v.z, 0.f); v.w = fmaxf(v.w, 0.f);
        }
        ra[it] = v;
        rw[it] = *(const float4*)&W[(otile * 64 + sb[it]) * K + k0 + skg[it] * 4];
      }
    }
#pragma unroll 4
    for (int kk = 0; kk < 48; ++kk) {
      float av[4], wv[4];
      *(float4*)av = *(const float4*)&eT[p][kk * 68 + bt * 4];
      *(float4*)wv = *(const float4*)&wT[p][kk * 68 + ot * 4];
#pragma unroll
      for (int i = 0; i < 4; ++i)
#pragma unroll
        for (int j = 0; j < 4; ++j) acc[i][j] += av[i] * wv[j];
    }
  }
#pragma unroll
  for (int i = 0; i < 4; ++i)
#pragma unroll
    for (int j = 0; j < 4; ++j)
      atomicAdd(&C[(bt * 4 + i) * N + otile * 64 + ot * 4 + j], acc[i][j]);
}

// ------- classifier layer 1 (with fused group-pooling) -------
__global__ __launch_bounds__(256) void k_cls1(
    const float* __restrict__ em3, const float* __restrict__ b2m,
    const float* __restrict__ b2e, const float* __restrict__ w1mT,
    const float* __restrict__ b1m, const float* __restrict__ w1eT,
    const float* __restrict__ b1e, float* __restrict__ h2) {
  int which = blockIdx.z, g = blockIdx.y, t = threadIdx.x;
  const float* em = em3 + which * 61440 + g * 7680;
  const float* b2 = which ? b2e : b2m;
  const float* WT = which ? w1eT : w1mT;
  const float* b1 = which ? b1e : b1m;
  __shared__ float pl[960];
  for (int d = t; d < 960; d += 256) {
    float s = 0.f;
#pragma unroll
    for (int r = 0; r < 8; ++r) s += em[r * 960 + d];
    pl[d] = s * 0.125f + b2[d];
  }
  __syncthreads();
  int o = blockIdx.x * 256 + t;
  if (o >= 1920) return;
  float acc = 0.f;
#pragma unroll 8
  for (int k = 0; k < 960; ++k) acc += WT[k * 1920 + o] * pl[k];
  float z = acc + b1[o];
  h2[which * 15360 + g * 1920 + o] = z * fminf(fmaxf(z + 3.f, 0.f), 6.f) * (1.f / 6.f);
}

// ------- classifier layer 2 + final concat -------
__global__ __launch_bounds__(128) void k_cls2(
    const float* __restrict__ h2, const float* __restrict__ w2m,
    const float* __restrict__ b2m, const float* __restrict__ w2e,
    const float* __restrict__ b2e, float* __restrict__ out) {
  int g = blockIdx.x, which = blockIdx.y;
  int t = threadIdx.x, j = t >> 6, lane = t & 63;
  const float* h = h2 + which * 15360 + g * 1920;
  const float* W = (which ? w2e : w2m) + j * 1920;
  const float* bb = which ? b2e : b2m;
  float s = 0.f;
  for (int k = lane; k < 1920; k += 64) s += h[k] * W[k];
  for (int off = 32; off >= 1; off >>= 1) s += __shfl_down(s, off);
  if (lane == 0) out[g * 4 + which * 2 + j] = s + bb[j];
}

// =======================================================================
extern "C" void kernel_launch(void* const* d_in, const int* in_sizes, int n_in,
                              void* d_out, int out_size, void* d_ws, size_t ws_size,
                              hipStream_t stream) {
  const float* x_p = (const float*)d_in[0];
  const float* x_i = (const float*)d_in[1];
  const float* scr_w_in = (const float*)d_in[2];
  const float* scr_bn_in = (const float*)d_in[3];
  const float* scr_w1 = (const float*)d_in[4];
  const float* scr_bn1 = (const float*)d_in[5];
  const float* scr_w2 = (const float*)d_in[6];
  const float* scr_bn2 = (const float*)d_in[7];
  const float* scr_w_out = (const float*)d_in[8];
  const float* scr_bn_out = (const float*)d_in[9];
  const float* cca1x1_w = (const float*)d_in[10];
  const float* cca1x1_bn = (const float*)d_in[11];
  const float* cca0_c2_w = (const float*)d_in[12];
  const float* cca0_c2_bn = (const float*)d_in[13];
  const float* cca0_c1_w = (const float*)d_in[14];
  const float* cca0_c1_bn = (const float*)d_in[15];
  const float* cca0_p_w = (const float*)d_in[16];
  const float* cca0_p_bn = (const float*)d_in[17];
  const float* cca1_c2_w = (const float*)d_in[18];
  const float* cca1_c2_bn = (const float*)d_in[19];
  const float* cca1_c1_w = (const float*)d_in[20];
  const float* cca1_c1_bn = (const float*)d_in[21];
  const float* cca1_p_w = (const float*)d_in[22];
  const float* cca1_p_bn = (const float*)d_in[23];
  const float* meta_w1 = (const float*)d_in[24];
  const float* meta_w2 = (const float*)d_in[25];
  const float* meta_b2 = (const float*)d_in[26];
  const float* ene_w1 = (const float*)d_in[27];
  const float* ene_w2 = (const float*)d_in[28];
  const float* ene_b2 = (const float*)d_in[29];
  const float* mcls_w1 = (const float*)d_in[30];
  const float* mcls_b1 = (const float*)d_in[31];
  const float* mcls_w2 = (const float*)d_in[32];
  const float* mcls_b2 = (const float*)d_in[33];
  const float* ecls_w1 = (const float*)d_in[34];
  const float* ecls_b1 = (const float*)d_in[35];
  const float* ecls_w2 = (const float*)d_in[36];
  const float* ecls_b2 = (const float*)d_in[37];

  float* ws = (float*)d_ws;
  float* PART = ws + OFF_XN;   // 64x8x49 partial sums
  unsigned short* Y1BF = (unsigned short*)(ws + OFF_Y1BF);
  unsigned* KMTU = (unsigned*)(ws + OFF_KMT);
  unsigned short* W2BF = (unsigned short*)(ws + OFF_W2BF);
  unsigned short* Y2BF = (unsigned short*)(ws + OFF_Y2BF);
  float* T = ws + OFF_T;
  float* XPN = ws + OFF_XPN;
  float* SQ = ws + OFF_SQ;
  float* S0P = ws + OFF_S0P;
  float* S1Y1 = ws + OFF_S1Y1;
  float* S1Y2 = ws + OFF_S1Y2;
  float* ATT = ws + OFF_ATT;
  float* EPI = ws + OFF_EPI;
  float* H1 = ws + OFF_H1;
  float* EM3 = ws + OFF_EM3;
  float* H2 = ws + OFF_H2;
  float* WOUTT = ws + OFF_WOUTT;
  float* CCAT = ws + OFF_CCAT;
  float* MCLST = ws + OFF_MCLST;
  float* ECLST = ws + OFF_ECLST;
  unsigned* WBF = (unsigned*)(ws + OFF_WBF);

  // weight preps
  k_transpose_t<<<dim3(3, 30), 256, 0, stream>>>(scr_w_out, WOUTT, 960, 96);
  k_transpose_t<<<dim3(30, 3), 256, 0, stream>>>(cca1x1_w, CCAT, 96, 960);
  k_transpose_t<<<dim3(30, 60), 256, 0, stream>>>(mcls_w1, MCLST, 1920, 960);
  k_transpose_t<<<dim3(30, 60), 256, 0, stream>>>(ecls_w1, ECLST, 1920, 960);
  k_prepwbf<<<180, 256, 0, stream>>>(scr_w_in, WBF);
  k_kmat<<<4256, 256, 0, stream>>>(scr_w1, KMTU);
  k_w2bf<<<336, 256, 0, stream>>>(scr_w2, W2BF);

  for (int br = 0; br < 2; ++br) {
    const float* x = br ? x_i : x_p;
    k_l2npart<<<dim3(64, 8), 256, 0, stream>>>(x, PART);
    k_scr_in<<<dim3(64, 7), 512, 0, stream>>>(x, PART, WBF, scr_bn_in, Y1BF);
    k_conv1g<<<dim3(64, 7), 256, 0, stream>>>((const unsigned*)Y1BF, KMTU,
                                              scr_bn1, Y2BF);
    k_conv2g<<<98, 256, 0, stream>>>((const unsigned*)Y2BF, (const unsigned*)W2BF,
                                     scr_bn2, T);
    k_out_cca<<<dim3(64, 7), 512, 0, stream>>>(T, WOUTT, scr_bn_out, x, CCAT,
                                               cca1x1_bn, XPN + br * 3010560,
                                               SQ + br * 301056);
  }
  k_mid<<<64, 512, 0, stream>>>(SQ, SQ + 301056, cca0_c2_w, cca0_c2_bn,
                                cca0_c1_w, cca0_c1_bn, cca0_p_w, cca0_p_bn, S0P);
  k_sep1a<<<dim3(64, 7), 512, 0, stream>>>(S0P, cca1_c2_w, cca1_c2_bn, S1Y1);
  k_sep1b<<<dim3(64, 7), 512, 0, stream>>>(S1Y1, cca1_c1_w, cca1_c1_bn, S1Y2);
  k_c4attn<<<64, 256, 0, stream>>>(S1Y2, cca1_p_w, cca1_p_bn, ATT, ATT + 3136);
  k_pool<<<dim3(64, 2), 256, 0, stream>>>(XPN, ATT, EPI);

  hipMemsetAsync(H1, 0, (245760u + 122880u) * sizeof(float), stream);
  k_gemm64<<<dim3(30, 8, 2), 256, 0, stream>>>(EPI, EPI + 122880, 960, 0,
                                               meta_w1, ene_w1, 1920, 240,
                                               H1, H1 + 122880, 1920, 960);
  k_gemm64<<<dim3(15, 8, 2), 256, 0, stream>>>(H1, nullptr, 0, 1,
                                               meta_w2, ene_w2, 1920, 240,
                                               EM3, EM3 + 61440, 960, 122880);
  k_cls1<<<dim3(8, 8, 2), 256, 0, stream>>>(EM3, meta_b2, ene_b2, MCLST, mcls_b1,
                                            ECLST, ecls_b1, H2);
  k_cls2<<<dim3(8, 2), 128, 0, stream>>>(H2, mcls_w2, mcls_b2, ecls_w2, ecls_b2,
                                         (float*)d_out);
}

// Round 10
// 713.359 us; speedup vs baseline: 1.0274x; 1.0126x over previous
//
#include <hip/hip_runtime.h>
#include <hip/hip_bf16.h>

// RtNet25DDualRENet forward. Round 15:
//  - k_scr_in v9: revert to v7 layout (R14's XOR swizzle raised conflicts
//    7.18M vs 6.28M and cost 1us — bank model exhausted, per pre-commit).
//    NEW: P-build packs bf16 pairs with v_cvt_pk_bf16_f32 (inline asm, RNE,
//    bit-identical) — replaces 16 software-RNE f2bf + 8 shift-or packs
//    (~96 VALU) with 8 cvt_pk per thread per chunk. VALUBusy 34% -> ~27%.
//  - k_gemm64 v2 (verified) kept; everything else unchanged.

#define BNINV 0.9999950000374997f  // 1/sqrt(1+1e-5)

typedef __attribute__((ext_vector_type(8))) short bf16x8;
typedef __attribute__((ext_vector_type(4))) float f32x4;

__device__ inline unsigned short f2bf(float f) {
  union { float f; unsigned u; } x; x.f = f;
  unsigned r = x.u + 0x7fffu + ((x.u >> 16) & 1u);  // RNE
  return (unsigned short)(r >> 16);
}

// ---------------- workspace layout (float offsets) ----------------
#define OFF_XN      0u          // PART (64 x 8 x 49 partial sums)
#define OFF_Y1BF    3010560u    // bf16 [3136 pairs][2432]
#define OFF_KMT     6823936u    // bf16 [896 n][2432 k]
#define OFF_W2BF    7913472u    // bf16 [96][896]
#define OFF_Y2BF    7956480u    // bf16 [3136][896]
#define OFF_T       9361408u    // (b,49,96)
#define OFF_XPN     9662464u    // 2 x (b,49,960)
#define OFF_SQ      15683584u   // 2 x (b,49,96)
#define OFF_S0P     16285696u   // (b,16,49,49)
#define OFF_S1Y1    18744320u
#define OFF_S1Y2    21202944u
#define OFF_ATT     23661568u
#define OFF_EPI     23667840u
#define OFF_H1      23913600u   // 2 x (64,1920)
#define OFF_EM3     24159360u   // 2 x (64,960)
#define OFF_H2      24297600u
#define OFF_WOUTT   24328320u
#define OFF_CCAT    24420480u
#define OFF_MCLST   24512640u
#define OFF_ECLST   26355840u
#define OFF_WBF     28199040u   // 46080 uints (96x960 bf16 pairs)

// ---------------- tiled transpose ----------------
__global__ __launch_bounds__(256) void k_transpose_t(const float* __restrict__ in,
                                                     float* __restrict__ out,
                                                     int R, int C) {
  __shared__ float tl[32][33];
  int c0 = blockIdx.x * 32, r0 = blockIdx.y * 32;
  int tx = threadIdx.x & 31, ty = threadIdx.x >> 5;
#pragma unroll
  for (int i = 0; i < 4; ++i)
    tl[ty + i * 8][tx] = in[(r0 + ty + i * 8) * C + c0 + tx];
  __syncthreads();
#pragma unroll
  for (int i = 0; i < 4; ++i)
    out[(c0 + ty + i * 8) * R + r0 + tx] = tl[tx][ty + i * 8];
}

// ---- prep: scr_w_in -> packed bf16 pairs ----
__global__ void k_prepwbf(const float* __restrict__ w_in, unsigned* __restrict__ WbfU) {
  int i = blockIdx.x * 256 + threadIdx.x;
  if (i >= 46080) return;
  float a = w_in[2 * i], b = w_in[2 * i + 1];
  WbfU[i] = (unsigned)f2bf(a) | ((unsigned)f2bf(b) << 16);
}

// ---- prep: conv1 kernel matrix Kmat_t[n=(o,d)][k=(ic,pos)] bf16 [896][2432] ----
__global__ void k_kmat(const float* __restrict__ w1, unsigned* __restrict__ kmtu) {
  int i = blockIdx.x * 256 + threadIdx.x;
  if (i >= 896 * 1216) return;
  int n = i / 1216, ku = i % 1216;
  unsigned out = 0;
#pragma unroll
  for (int h = 0; h < 2; ++h) {
    int k = ku * 2 + h;
    float v = 0.f;
    if (n < 864 && k < 2400) {
      int o = n / 9, d = n % 9, i2 = d / 3, j2 = d % 3;
      int ic = k / 25, pos = k % 25, u = pos / 5, vv = pos % 5;
      int di = u - i2, dj = vv - j2;
      if ((unsigned)di < 3u && (unsigned)dj < 3u)
        v = w1[(o * 96 + ic) * 9 + di * 3 + dj];
    }
    out |= ((unsigned)f2bf(v)) << (16 * h);
  }
  kmtu[i] = out;
}

// ---- prep: w2 -> bf16 [96][896] ----
__global__ void k_w2bf(const float* __restrict__ w2, unsigned short* __restrict__ w2b) {
  int i = blockIdx.x * 256 + threadIdx.x;
  if (i >= 86016) return;
  int o2 = i / 896, k = i % 896;
  w2b[i] = (k < 864) ? f2bf(w2[o2 * 864 + k]) : (unsigned short)0;
}

// ---------------- K1: partial sum-of-squares of relu(x) per (b,p) ----------------
__global__ __launch_bounds__(256) void k_l2npart(const float* __restrict__ x,
                                                 float* __restrict__ part) {
  int b = blockIdx.x, sl = blockIdx.y, t = threadIdx.x;
  __shared__ float red[256];
  const float* xb = x + b * 47040 + sl * 5880;
  int p = t & 63, s2 = t >> 6;
  float s = 0.f;
  if (p < 49) {
#pragma unroll 6
    for (int c = 0; c < 30; ++c) {
      float v = xb[(s2 * 30 + c) * 49 + p];
      if (v > 0.f) s += v * v;
    }
  }
  red[t] = s;
  __syncthreads();
  if (t < 49)
    part[(b * 8 + sl) * 49 + t] = red[t] + red[t + 64] + red[t + 128] + red[t + 192];
}

// ------- K2: fused l2norm + self-corr x scr_w_in einsum + BN + relu (bf16 MFMA) -------
// grid (64 b, 7 h). v9: v7 layout + v_cvt_pk_bf16_f32 packing in P-build.
__global__ __launch_bounds__(512) void k_scr_in(
    const float* __restrict__ x, const float* __restrict__ part,
    const unsigned* __restrict__ WbfU,
    const float* __restrict__ bn, unsigned short* __restrict__ y1bf) {
  const int b = blockIdx.x, h = blockIdx.y, t = threadIdx.x;
  const int wave = t >> 6, lane = t & 63, quad = lane >> 4, lr = lane & 15;
  const int mh = wave >> 2, ng = wave & 3;
  __shared__ __align__(16) short Pl[2][192 * 40];
  __shared__ __align__(16) short Wl[2][96 * 40];
  __shared__ __align__(16) float xc[2][2160];   // [j][k] stride 36
  __shared__ float invL[60];
  // zero-pad y1bf[pair][2400..2432)
  if (t < 112) {
    int pairL = t >> 4, ku = t & 15;
    ((unsigned*)y1bf)[(unsigned)(b * 49 + h * 7 + pairL) * 1216u + 1200u + ku] = 0u;
  }
  // per-padded-pixel inverse norms
  if (t < 60) {
    int r = t / 12, wc = t - r * 12;
    int row = h + r - 2, w = wc - 2;
    float iv = 0.f;
    if ((unsigned)row < 7u && (unsigned)w < 7u) {
      int p = row * 7 + w;
      float s = 0.f;
#pragma unroll
      for (int sl = 0; sl < 8; ++sl) s += part[(b * 8 + sl) * 49 + p];
      iv = 1.f / fmaxf(sqrtf(s), 1e-12f);
    }
    invL[t] = iv;
  }
  f32x4 acc[3][3];
#pragma unroll
  for (int m = 0; m < 3; ++m)
#pragma unroll
    for (int n = 0; n < 3; ++n) acc[m][n] = (f32x4){0.f, 0.f, 0.f, 0.f};
  const float* xb = x + b * 47040;
  // staging geometry: thread u<480 owns pixel j = u%60, k-group k4 = u/60 (4 k's)
  const int sj = t % 60, sk4 = t / 60;
  const bool sOk = (t < 480);
  int pixOff = 0;
  bool pixIn = false;
  if (sOk) {
    int r = sj / 12, wc = sj - r * 12;
    int row = h + r - 2, w = wc - 2;
    pixIn = ((unsigned)row < 7u && (unsigned)w < 7u);
    pixOff = row * 7 + w;
  }
  const int colB = t >> 1, halfB = t & 1;
  int i1 = 0, i2 = 0;
  if (t < 384) {
    int cc = colB < 175 ? colB : 174;
    int wp = cc / 25, uv = cc - wp * 25, du = uv / 5, dv = uv - du * 5;
    i1 = (26 + wp) * 36;
    i2 = (du * 12 + wp + dv) * 36;
  }
  float xr0[4] = {0.f, 0.f, 0.f, 0.f};
  unsigned wr0[3];
  // prefetch chunk 0
  {
    if (sOk && pixIn) {
      const float* src = &xb[(sk4 * 4) * 49 + pixOff];
#pragma unroll
      for (int q = 0; q < 4; ++q) xr0[q] = src[q * 49];
    }
#pragma unroll
    for (int it = 0; it < 3; ++it) {
      int i = t + it * 512;
      wr0[it] = WbfU[(i >> 4) * 480 + (i & 15)];
    }
  }
  __syncthreads();   // invL ready before first LDS store
  int p = 0;
  for (int c = 0; c < 30; ++c, p ^= 1) {
    // store prefetched regs into LDS buffer p (normalized); one float4/thread
    float* xcb = xc[p];
    if (sOk) {
      float iv = invL[sj];
      float4 v;
      v.x = fmaxf(xr0[0], 0.f) * iv;
      v.y = fmaxf(xr0[1], 0.f) * iv;
      v.z = fmaxf(xr0[2], 0.f) * iv;
      v.w = fmaxf(xr0[3], 0.f) * iv;
      *(float4*)&xcb[sj * 36 + sk4 * 4] = v;
    }
    unsigned* Wlu = (unsigned*)Wl[p];
#pragma unroll
    for (int it = 0; it < 3; ++it) {
      int i = t + it * 512;
      Wlu[(i >> 4) * 20 + (i & 15)] = wr0[it];
    }
    __syncthreads();
    // build P[p]: b128 reads; pack with v_cvt_pk_bf16_f32 (RNE, 1 instr/pair)
    if (t < 384) {
      const float* r1 = &xcb[i1 + halfB * 16];
      const float* r2 = &xcb[i2 + halfB * 16];
      float a[16], cc[16];
#pragma unroll
      for (int q = 0; q < 4; ++q) {
        *(float4*)&a[q * 4] = *(const float4*)&r1[q * 4];
        *(float4*)&cc[q * 4] = *(const float4*)&r2[q * 4];
      }
      unsigned pk[8];
#pragma unroll
      for (int q = 0; q < 8; ++q) {
        float v0 = a[q * 2] * cc[q * 2];
        float v1 = a[q * 2 + 1] * cc[q * 2 + 1];
        asm("v_cvt_pk_bf16_f32 %0, %1, %2" : "=v"(pk[q]) : "v"(v0), "v"(v1));
      }
      unsigned* dst = (unsigned*)Pl[p] + colB * 20 + halfB * 8;
      *(uint4*)dst = *(uint4*)&pk[0];
      *(uint4*)(dst + 4) = *(uint4*)&pk[4];
    }
    __syncthreads();
    // prefetch chunk c+1 (rides across the MFMA phase)
    if (c < 29) {
      const int k0 = (c + 1) * 32;
      if (sOk) {
        if (pixIn) {
          const float* src = &xb[(k0 + sk4 * 4) * 49 + pixOff];
#pragma unroll
          for (int q = 0; q < 4; ++q) xr0[q] = src[q * 49];
        }
      }
      int base = k0 >> 1;
#pragma unroll
      for (int it = 0; it < 3; ++it) {
        int i = t + it * 512;
        wr0[it] = WbfU[(i >> 4) * 480 + base + (i & 15)];
      }
    }
    // MFMA on buffer p
    const int ko = quad * 8;
    bf16x8 af[3], bfr[3];
#pragma unroll
    for (int m = 0; m < 3; ++m)
      af[m] = *(const bf16x8*)&Wl[p][((mh * 3 + m) * 16 + lr) * 40 + ko];
#pragma unroll
    for (int n = 0; n < 3; ++n)
      bfr[n] = *(const bf16x8*)&Pl[p][((ng * 3 + n) * 16 + lr) * 40 + ko];
#pragma unroll
    for (int m = 0; m < 3; ++m)
#pragma unroll
      for (int n = 0; n < 3; ++n)
        acc[m][n] = __builtin_amdgcn_mfma_f32_16x16x32_bf16(
            af[m], bfr[n], acc[m][n], 0, 0, 0);
  }
  // epilogue: C/D col=lane&15, row=quad*4+reg
#pragma unroll
  for (int n = 0; n < 3; ++n) {
    int col = (ng * 3 + n) * 16 + lr;
    if (col >= 175) continue;
    int wp = col / 25, uv = col - wp * 25;
    unsigned pairIdx = (unsigned)(b * 49 + h * 7 + wp);
#pragma unroll
    for (int m = 0; m < 3; ++m) {
#pragma unroll
      for (int r = 0; r < 4; ++r) {
        int o = (mh * 3 + m) * 16 + quad * 4 + r;
        float g = BNINV * bn[o], bt = bn[96 + o];
        float v = fmaxf(acc[m][n][r] * g + bt, 0.f);
        y1bf[pairIdx * 2432u + (unsigned)(o * 25 + uv)] = f2bf(v);
      }
    }
  }
}

// ------- K3: conv1 MFMA GEMM. grid (64 m-slots [49 used], 7 n) -------
__global__ __launch_bounds__(256) void k_conv1g(
    const unsigned* __restrict__ y1u, const unsigned* __restrict__ kmtu,
    const float* __restrict__ bn1, unsigned short* __restrict__ y2bf) {
  if (blockIdx.x >= 49) return;
  const int t = threadIdx.x;
  const int wave = t >> 6, lane = t & 63, quad = lane >> 4, lr = lane & 15;
  const int mh = wave >> 1, nh = wave & 1;
  const int pairBase = blockIdx.x * 64, nBase = blockIdx.y * 128;
  __shared__ __align__(16) short Ash[64 * 72];
  __shared__ __align__(16) short Bsh[128 * 72];
  __shared__ float bnl[192];
  unsigned* Au = (unsigned*)Ash;
  unsigned* Bu = (unsigned*)Bsh;
  if (t < 192) bnl[t] = bn1[t];
  f32x4 acc[2][4];
#pragma unroll
  for (int m = 0; m < 2; ++m)
#pragma unroll
    for (int n = 0; n < 4; ++n) acc[m][n] = (f32x4){0.f, 0.f, 0.f, 0.f};
  const int prA = t >> 2, qA = t & 3;
  const int nB = t >> 1, qB = t & 1;
  for (int c = 0; c < 38; ++c) {
    int ku0 = c * 32;
    __syncthreads();
    {
      const unsigned* src = y1u + (unsigned)(pairBase + prA) * 1216u + ku0 + qA * 8;
      unsigned* dst = Au + prA * 36 + qA * 8;
      *(uint4*)dst = *(const uint4*)src;
      *(uint4*)(dst + 4) = *(const uint4*)(src + 4);
    }
    {
      const unsigned* src = kmtu + (unsigned)(nBase + nB) * 1216u + ku0 + qB * 16;
      unsigned* dst = Bu + nB * 36 + qB * 16;
#pragma unroll
      for (int q = 0; q < 4; ++q)
        *(uint4*)(dst + q * 4) = *(const uint4*)(src + q * 4);
    }
    __syncthreads();
#pragma unroll
    for (int s = 0; s < 2; ++s) {
      int ko = s * 32 + quad * 8;
      bf16x8 af[2], bf[4];
#pragma unroll
      for (int m = 0; m < 2; ++m)
        af[m] = *(const bf16x8*)&Ash[((mh * 2 + m) * 16 + lr) * 72 + ko];
#pragma unroll
      for (int n = 0; n < 4; ++n)
        bf[n] = *(const bf16x8*)&Bsh[((nh * 4 + n) * 16 + lr) * 72 + ko];
#pragma unroll
      for (int m = 0; m < 2; ++m)
#pragma unroll
        for (int n = 0; n < 4; ++n)
          acc[m][n] = __builtin_amdgcn_mfma_f32_16x16x32_bf16(
              af[m], bf[n], acc[m][n], 0, 0, 0);
    }
  }
#pragma unroll
  for (int m = 0; m < 2; ++m) {
#pragma unroll
    for (int r = 0; r < 4; ++r) {
      unsigned pair = (unsigned)(pairBase + (mh * 2 + m) * 16 + quad * 4 + r);
#pragma unroll
      for (int n = 0; n < 4; ++n) {
        int nn = nBase + (nh * 4 + n) * 16 + lr;
        unsigned short outv = 0;
        if (nn < 864) {
          int o = nn / 9;
          float v = fmaxf(acc[m][n][r] * (BNINV * bnl[o]) + bnl[96 + o], 0.f);
          outv = f2bf(v);
        }
        y2bf[pair * 896u + nn] = outv;
      }
    }
  }
}

// ------- K4: conv2 MFMA GEMM, 98 blocks of 32 pairs -------
__global__ __launch_bounds__(256) void k_conv2g(
    const unsigned* __restrict__ y2u, const unsigned* __restrict__ w2u,
    const float* __restrict__ bn2, float* __restrict__ tout) {
  const int t = threadIdx.x;
  const int wave = t >> 6, lane = t & 63, quad = lane >> 4, lr = lane & 15;
  const int mh = wave >> 1, nh = wave & 1;
  const int pairBase = blockIdx.x * 32;
  __shared__ __align__(16) short Ash[32 * 72];
  __shared__ __align__(16) short Bsh[96 * 72];
  __shared__ float bnl[192];
  unsigned* Au = (unsigned*)Ash;
  unsigned* Bu = (unsigned*)Bsh;
  if (t < 192) bnl[t] = bn2[t];
  f32x4 acc[3];
#pragma unroll
  for (int n = 0; n < 3; ++n) acc[n] = (f32x4){0.f, 0.f, 0.f, 0.f};
  const int prA = t >> 3, qA = (t & 7) * 4;
  const int nB = t >> 1, qB = (t & 1) * 16;
  for (int c = 0; c < 14; ++c) {
    int ku0 = c * 32;
    __syncthreads();
    {
      const unsigned* src = y2u + (unsigned)(pairBase + prA) * 448u + ku0 + qA;
      *(uint4*)(Au + prA * 36 + qA) = *(const uint4*)src;
    }
    if (t < 192) {
      const unsigned* src = w2u + (unsigned)nB * 448u + ku0 + qB;
      unsigned* dst = Bu + nB * 36 + qB;
#pragma unroll
      for (int q = 0; q < 4; ++q)
        *(uint4*)(dst + q * 4) = *(const uint4*)(src + q * 4);
    }
    __syncthreads();
#pragma unroll
    for (int s = 0; s < 2; ++s) {
      int ko = s * 32 + quad * 8;
      bf16x8 af;
      af = *(const bf16x8*)&Ash[(mh * 16 + lr) * 72 + ko];
#pragma unroll
      for (int n = 0; n < 3; ++n) {
        bf16x8 bf = *(const bf16x8*)&Bsh[((nh * 3 + n) * 16 + lr) * 72 + ko];
        acc[n] = __builtin_amdgcn_mfma_f32_16x16x32_bf16(af, bf, acc[n], 0, 0, 0);
      }
    }
  }
#pragma unroll
  for (int r = 0; r < 4; ++r) {
    unsigned pair = (unsigned)(pairBase + mh * 16 + quad * 4 + r);
#pragma unroll
    for (int n = 0; n < 3; ++n) {
      int o = (nh * 3 + n) * 16 + lr;
      float v = fmaxf(acc[n][r] * (BNINV * bnl[o]) + bnl[96 + o], 0.f);
      tout[pair * 96u + o] = v;
    }
  }
}

// ------- K5: fused w_out GEMM + BN + residual relu + mean-sub + cca1 + l2norm -------
__global__ __launch_bounds__(512) void k_out_cca(
    const float* __restrict__ tin, const float* __restrict__ wouT,
    const float* __restrict__ bno, const float* __restrict__ x,
    const float* __restrict__ ccaT, const float* __restrict__ bnc,
    float* __restrict__ xpn, float* __restrict__ sq) {
  int b = blockIdx.x, pr = blockIdx.y, t = threadIdx.x;
  __shared__ __align__(16) float tl2[96 * 8];     // 3.0 KB  [ic][pl]
  __shared__ __align__(16) float xrT[960 * 8];    // 30.0 KB [o][pl] : x then y
  __shared__ float red[8 * 520];                  // 16.3 KB pl-major scratch
  __shared__ float mean[7];
  __shared__ float sv[7 * 97];
  __shared__ float inv7[7];
  for (int i = t; i < 672; i += 512) {
    int pl = i / 96, ic = i - pl * 96;
    tl2[ic * 8 + pl] = tin[(b * 49 + pr * 7 + pl) * 96 + ic];
  }
  for (int i = t; i < 6720; i += 512) {
    int o = i / 7, pl = i - o * 7;
    xrT[o * 8 + pl] = x[(b * 960 + o) * 49 + pr * 7 + pl];
  }
  __syncthreads();
  float acc0[7] = {0.f, 0.f, 0.f, 0.f, 0.f, 0.f, 0.f};
  float acc1[7] = {0.f, 0.f, 0.f, 0.f, 0.f, 0.f, 0.f};
  const bool has1 = (t < 448);
  const int o1 = has1 ? t + 512 : t;
#pragma unroll 8
  for (int ic = 0; ic < 96; ++ic) {
    float tv[8];
    *(float4*)&tv[0] = *(const float4*)&tl2[ic * 8];
    *(float4*)&tv[4] = *(const float4*)&tl2[ic * 8 + 4];
    float w0 = wouT[ic * 960 + t];
    float w1 = wouT[ic * 960 + o1];
#pragma unroll
    for (int pl = 0; pl < 7; ++pl) {
      acc0[pl] += w0 * tv[pl];
      acc1[pl] += w1 * tv[pl];
    }
  }
  float part[7] = {0.f, 0.f, 0.f, 0.f, 0.f, 0.f, 0.f};
  {
    float xv[8];
    *(float4*)&xv[0] = *(const float4*)&xrT[t * 8];
    *(float4*)&xv[4] = *(const float4*)&xrT[t * 8 + 4];
    float g = BNINV * bno[t], bt = bno[960 + t];
#pragma unroll
    for (int pl = 0; pl < 7; ++pl) {
      float v = fmaxf(xv[pl] + acc0[pl] * g + bt, 0.f);
      acc0[pl] = v; part[pl] += v;
      xrT[t * 8 + pl] = v;
    }
  }
  if (has1) {
    float xv[8];
    *(float4*)&xv[0] = *(const float4*)&xrT[o1 * 8];
    *(float4*)&xv[4] = *(const float4*)&xrT[o1 * 8 + 4];
    float g = BNINV * bno[o1], bt = bno[960 + o1];
#pragma unroll
    for (int pl = 0; pl < 7; ++pl) {
      float v = fmaxf(xv[pl] + acc1[pl] * g + bt, 0.f);
      acc1[pl] = v; part[pl] += v;
      xrT[o1 * 8 + pl] = v;
    }
  }
#pragma unroll
  for (int pl = 0; pl < 7; ++pl) red[pl * 520 + t] = part[pl];
  __syncthreads();
  if (t < 64) {
#pragma unroll
    for (int pl = 0; pl < 7; ++pl) {
      float s = 0.f;
#pragma unroll
      for (int j = 0; j < 8; ++j) s += red[pl * 520 + t + j * 64];
      red[pl * 520 + t] = s;
    }
  }
  __syncthreads();
  if (t < 7) {
    float s = 0.f;
    for (int i = 0; i < 64; ++i) s += red[t * 520 + i];
    mean[t] = s * (1.f / 960.f);
  }
  __syncthreads();
#pragma unroll
  for (int pl = 0; pl < 7; ++pl)
    xpn[(b * 49 + pr * 7 + pl) * 960 + t] = acc0[pl] - mean[pl];
  if (has1) {
#pragma unroll
    for (int pl = 0; pl < 7; ++pl)
      xpn[(b * 49 + pr * 7 + pl) * 960 + o1] = acc1[pl] - mean[pl];
  }
  float acc2[7] = {0.f, 0.f, 0.f, 0.f, 0.f, 0.f, 0.f};
  float sw = 0.f;
  int o2 = t % 96, csl = t / 96;
  if (t < 480) {
    int c0 = csl * 192;
#pragma unroll 8
    for (int c = c0; c < c0 + 192; ++c) {
      float w = ccaT[c * 96 + o2];
      sw += w;
      float tv[8];
      *(float4*)&tv[0] = *(const float4*)&xrT[c * 8];
      *(float4*)&tv[4] = *(const float4*)&xrT[c * 8 + 4];
#pragma unroll
      for (int pl = 0; pl < 7; ++pl) acc2[pl] += w * tv[pl];
    }
#pragma unroll
    for (int pl = 0; pl < 7; ++pl) red[pl * 520 + t] = acc2[pl];
    red[7 * 520 + t] = sw;
  }
  __syncthreads();
  if (t < 96) {
    float g = BNINV * bnc[t], bt = bnc[96 + t];
    float swt = 0.f;
#pragma unroll
    for (int s5 = 0; s5 < 5; ++s5) swt += red[7 * 520 + s5 * 96 + t];
#pragma unroll
    for (int pl = 0; pl < 7; ++pl) {
      float a = 0.f;
#pragma unroll
      for (int s5 = 0; s5 < 5; ++s5) a += red[pl * 520 + s5 * 96 + t];
      a -= mean[pl] * swt;
      sv[pl * 97 + t] = fmaxf(a * g + bt, 0.f);
    }
  }
  __syncthreads();
  if (t < 112) {
    int pl = t >> 4, ln = t & 15;
    float s = 0.f;
    for (int o = ln; o < 96; o += 16) { float v = sv[pl * 97 + o]; s += v * v; }
    red[pl * 16 + ln] = s;
  }
  __syncthreads();
  if (t < 7) {
    float s = 0.f;
    for (int i = 0; i < 16; ++i) s += red[t * 16 + i];
    inv7[t] = 1.f / fmaxf(sqrtf(s), 1e-8f);
  }
  __syncthreads();
  for (int i = t; i < 672; i += 512) {
    int pl = i / 96, o = i - pl * 96;
    sq[(b * 49 + pr * 7 + pl) * 96 + o] = sv[pl * 97 + o] * inv7[pl];
  }
}

// ------- K7: fused corr + sep4d#0 (512 threads) -------
__global__ __launch_bounds__(512) void k_mid(
    const float* __restrict__ sq0, const float* __restrict__ sq1,
    const float* __restrict__ wuv, const float* __restrict__ bnuv,
    const float* __restrict__ wkl, const float* __restrict__ bnkl,
    const float* __restrict__ pw16, const float* __restrict__ pbn16,
    float* __restrict__ s0p) {
  int b = blockIdx.x, t = threadIdx.x;
  __shared__ float smem[12496];
  float* sL = smem;
  float* qL = smem + 5047;
  float* A = smem + 10094;
  for (int i = t; i < 4704; i += 512) {
    int p = i / 96, c = i % 96;
    sL[p * 103 + c] = sq0[b * 4704 + i];
    qL[p * 103 + c] = sq1[b * 4704 + i];
  }
  __syncthreads();
  for (int i = t; i < 2401; i += 512) {
    int ij = i / 49, kl = i % 49;
    float a = 0.f;
#pragma unroll 4
    for (int c = 0; c < 96; ++c) a += sL[ij * 103 + c] * qL[kl * 103 + c];
    A[i] = a;
  }
  __syncthreads();
  float* B = smem;
  {
    float w0[9];
#pragma unroll
    for (int d = 0; d < 9; ++d) w0[d] = wuv[d];
    float g = BNINV * bnuv[0], bt = bnuv[1];
    for (int i = t; i < 2401; i += 512) {
      int ij = i / 49, kl = i % 49;
      int u = ij / 7, v = ij % 7;
      float a = 0.f;
#pragma unroll
      for (int du = 0; du < 3; ++du) {
        int uu = u + du - 1;
        if ((unsigned)uu >= 7u) continue;
#pragma unroll
        for (int dv = 0; dv < 3; ++dv) {
          int vv = v + dv - 1;
          if ((unsigned)vv >= 7u) continue;
          a += w0[du * 3 + dv] * A[(uu * 7 + vv) * 49 + kl];
        }
      }
      B[i] = fmaxf(a * g + bt, 0.f);
    }
  }
  __syncthreads();
  float* Cc = smem + 4900;
  {
    float w1[9];
#pragma unroll
    for (int d = 0; d < 9; ++d) w1[d] = wkl[d];
    float g = BNINV * bnkl[0], bt = bnkl[1];
    for (int i = t; i < 2401; i += 512) {
      int ij = i / 49, kl = i % 49;
      int kk = kl / 7, ll = kl % 7;
      float a = 0.f;
#pragma unroll
      for (int dh = 0; dh < 3; ++dh) {
        int k2 = kk + dh - 1;
        if ((unsigned)k2 >= 7u) continue;
#pragma unroll
        for (int dw = 0; dw < 3; ++dw) {
          int l2 = ll + dw - 1;
          if ((unsigned)l2 >= 7u) continue;
          a += w1[dh * 3 + dw] * B[ij * 49 + k2 * 7 + l2];
        }
      }
      Cc[i] = a * g + bt;
    }
  }
  __syncthreads();
  for (int o = 0; o < 16; ++o) {
    float sc = pw16[o] * BNINV * pbn16[o], bt2 = pbn16[16 + o];
    for (int i = t; i < 2401; i += 512)
      s0p[(b * 16 + o) * 2401 + i] = fmaxf(Cc[i] * sc + bt2, 0.f);
  }
}

// ---------------- sep4d #1 conv a. grid (64 b, 7 kc), 512 thr ----------------
__global__ __launch_bounds__(512) void k_sep1a(
    const float* __restrict__ in, const float* __restrict__ w,
    const float* __restrict__ bnp, float* __restrict__ out) {
  int b = blockIdx.x, kc = blockIdx.y, t = threadIdx.x;
  __shared__ float inS[16 * 345];
  __shared__ __align__(16) float wP[3072];
  for (int i = t; i < 3072; i += 512) {
    int oc = i / 12, d = i % 12;
    wP[i] = (d < 9) ? w[oc * 9 + d] : 0.f;
  }
  for (int i = t; i < 5488; i += 512) {
    int ic = i / 343, r = i - ic * 343;
    int ij = r / 7, s = r - ij * 7;
    inS[ic * 345 + s * 49 + ij] = in[(b * 16 + ic) * 2401 + ij * 49 + kc * 7 + s];
  }
  __syncthreads();
  for (int rho = t; rho < 784; rho += 512) {
    int o = rho / 49, rem = rho - o * 49, u = rem / 7, s = rem - u * 7;
    float acc[7] = {0.f, 0.f, 0.f, 0.f, 0.f, 0.f, 0.f};
    for (int ic = 0; ic < 16; ++ic) {
      float wv[12];
      const float* wb = &wP[(o * 16 + ic) * 12];
      *(float4*)&wv[0] = *(const float4*)&wb[0];
      *(float4*)&wv[4] = *(const float4*)&wb[4];
      *(float4*)&wv[8] = *(const float4*)&wb[8];
      const float* rowb = &inS[ic * 345 + s * 49];
#pragma unroll
      for (int du = 0; du < 3; ++du) {
        int uu = u + du - 1;
        if ((unsigned)uu >= 7u) continue;
        const float* rr = rowb + uu * 7;
        float r7[7];
#pragma unroll
        for (int q = 0; q < 7; ++q) r7[q] = rr[q];
#pragma unroll
        for (int v = 0; v < 7; ++v) {
          float a = acc[v];
          if (v > 0) a += wv[du * 3 + 0] * r7[v - 1];
          a += wv[du * 3 + 1] * r7[v];
          if (v < 6) a += wv[du * 3 + 2] * r7[v + 1];
          acc[v] = a;
        }
      }
    }
    float g = BNINV * bnp[o], bt = bnp[16 + o];
    long ob = (long)(b * 16 + o) * 2401 + kc * 7 + s;
#pragma unroll
    for (int v = 0; v < 7; ++v)
      out[ob + (u * 7 + v) * 49] = fmaxf(acc[v] * g + bt, 0.f);
  }
}

// ---------------- sep4d #1 conv b. grid (64 b, 7 ir), 512 thr ----------------
__global__ __launch_bounds__(512) void k_sep1b(
    const float* __restrict__ in, const float* __restrict__ w,
    const float* __restrict__ bnp, float* __restrict__ out) {
  int b = blockIdx.x, ir = blockIdx.y, t = threadIdx.x;
  __shared__ float inS[16 * 345];
  __shared__ __align__(16) float wP[3072];
  for (int i = t; i < 3072; i += 512) {
    int oc = i / 12, d = i % 12;
    wP[i] = (d < 9) ? w[oc * 9 + d] : 0.f;
  }
  for (int i = t; i < 5488; i += 512) {
    int ic = i / 343, r = i - ic * 343;
    inS[ic * 345 + r] = in[(b * 16 + ic) * 2401 + ir * 343 + r];
  }
  __syncthreads();
  for (int rho = t; rho < 784; rho += 512) {
    int o = rho / 49, rem = rho - o * 49, jj = rem / 7, k = rem - jj * 7;
    float acc[7] = {0.f, 0.f, 0.f, 0.f, 0.f, 0.f, 0.f};
    for (int ic = 0; ic < 16; ++ic) {
      float wv[12];
      const float* wb = &wP[(o * 16 + ic) * 12];
      *(float4*)&wv[0] = *(const float4*)&wb[0];
      *(float4*)&wv[4] = *(const float4*)&wb[4];
      *(float4*)&wv[8] = *(const float4*)&wb[8];
      const float* rowb = &inS[ic * 345 + jj * 49];
#pragma unroll
      for (int dh = 0; dh < 3; ++dh) {
        int k2 = k + dh - 1;
        if ((unsigned)k2 >= 7u) continue;
        const float* rr = rowb + k2 * 7;
        float r7[7];
#pragma unroll
        for (int q = 0; q < 7; ++q) r7[q] = rr[q];
#pragma unroll
        for (int l = 0; l < 7; ++l) {
          float a = acc[l];
          if (l > 0) a += wv[dh * 3 + 0] * r7[l - 1];
          a += wv[dh * 3 + 1] * r7[l];
          if (l < 6) a += wv[dh * 3 + 2] * r7[l + 1];
          acc[l] = a;
        }
      }
    }
    float g = BNINV * bnp[o], bt = bnp[16 + o];
    long ob = (long)(b * 16 + o) * 2401 + ir * 343 + jj * 49 + k * 7;
#pragma unroll
    for (int l = 0; l < 7; ++l)
      out[ob + l] = acc[l] * g + bt;
  }
}

// ------- K10: fused sep1p + gauss-softmax attention (dual-phase concurrent) -------
__global__ __launch_bounds__(256) void k_c4attn(
    const float* __restrict__ in, const float* __restrict__ pw,
    const float* __restrict__ pbn, float* __restrict__ attn_s,
    float* __restrict__ attn_q) {
  int b = blockIdx.x, t = threadIdx.x;
  __shared__ float c[2401];
  __shared__ float nA[2401];
  __shared__ float nB[2401];
  __shared__ float plw[16];
  if (t < 16) plw[t] = pw[t];
  __syncthreads();
  float g0 = BNINV * pbn[0], bt0 = pbn[1];
  for (int i = t; i < 2401; i += 256) {
    float a = 0.f;
#pragma unroll
    for (int ic = 0; ic < 16; ++ic) a += plw[ic] * in[(b * 16 + ic) * 2401 + i];
    c[i] = a * g0 + bt0;
  }
  __syncthreads();
  if (t < 49) {
    float m = 0.f;
    for (int ij = 0; ij < 49; ++ij) m += c[ij * 49 + t];
    m *= (1.f / 49.f);
    float v = 0.f;
    for (int ij = 0; ij < 49; ++ij) { float d = c[ij * 49 + t] - m; v += d * d; }
    v *= (1.f / 48.f);
    float inv = 1.f / sqrtf(v + 1e-5f);
    float mx = -1e30f;
    for (int ij = 0; ij < 49; ++ij) mx = fmaxf(mx, (c[ij * 49 + t] - m) * inv);
    float s = 0.f;
    for (int ij = 0; ij < 49; ++ij) {
      float e = expf((c[ij * 49 + t] - m) * inv - mx);
      nA[ij * 49 + t] = e; s += e;
    }
    float r = 1.f / s;
    for (int ij = 0; ij < 49; ++ij) nA[ij * 49 + t] *= r;
  } else if (t >= 64 && t < 113) {
    int t2 = t - 64;
    float m = 0.f;
    for (int kl = 0; kl < 49; ++kl) m += c[t2 * 49 + kl];
    m *= (1.f / 49.f);
    float v = 0.f;
    for (int kl = 0; kl < 49; ++kl) { float d = c[t2 * 49 + kl] - m; v += d * d; }
    v *= (1.f / 48.f);
    float inv = 1.f / sqrtf(v + 1e-5f);
    float mx = -1e30f;
    for (int kl = 0; kl < 49; ++kl) mx = fmaxf(mx, (c[t2 * 49 + kl] - m) * inv);
    float s = 0.f;
    for (int kl = 0; kl < 49; ++kl) {
      float e = expf((c[t2 * 49 + kl] - m) * inv - mx);
      nB[t2 * 49 + kl] = e; s += e;
    }
    float r = 1.f / s;
    for (int kl = 0; kl < 49; ++kl) nB[t2 * 49 + kl] *= r;
  }
  __syncthreads();
  if (t < 49) {
    float s = 0.f;
    for (int kl = 0; kl < 49; ++kl) s += nA[t * 49 + kl];
    attn_s[b * 49 + t] = s;
  } else if (t >= 64 && t < 113) {
    int t2 = t - 64;
    float s = 0.f;
    for (int ij = 0; ij < 49; ++ij) s += nB[ij * 49 + t2];
    attn_q[b * 49 + t2] = s;
  }
}

// ------- K11: attention-weighted mean/max pooling -------
__global__ __launch_bounds__(256) void k_pool(const float* __restrict__ xpn,
                                              const float* __restrict__ attn,
                                              float* __restrict__ ep) {
  int b = blockIdx.x, br = blockIdx.y, t = threadIdx.x;
  const float* xb = xpn + br * 3010560 + b * 47040;
  const float* a = attn + br * 3136 + b * 49;
  __shared__ float al[49];
  if (t < 49) al[t] = a[t];
  __syncthreads();
  float* eb = ep + br * 122880 + b * 1920;
  for (int c = t; c < 960; c += 256) {
    float s = 0.f, mx = -1e30f;
#pragma unroll 7
    for (int hw = 0; hw < 49; ++hw) {
      float v = al[hw] * xb[hw * 960 + c];
      s += v; mx = fmaxf(mx, v);
    }
    eb[c] = s * (1.f / 49.f);
    eb[960 + c] = mx;
  }
}

// ------- M=64 GEMM, split-K with atomicAdd; z selects meta/ene -------
// v2: register prefetch + double-buffered LDS, one barrier per 48-k chunk.
__global__ __launch_bounds__(256) void k_gemm64(
    const float* __restrict__ A0, const float* __restrict__ A1, int asplit,
    int reluA, const float* __restrict__ Wm, const float* __restrict__ We,
    int K, int Kslice, float* __restrict__ Cm, float* __restrict__ Ce,
    int N, int zAoff) {
  int otile = blockIdx.x, ks = blockIdx.y, z = blockIdx.z;
  const float* W = z ? We : Wm;
  float* C = z ? Ce : Cm;
  int zo = z * zAoff;
  int t = threadIdx.x, bt = t >> 4, ot = t & 15;
  __shared__ __align__(16) float eT[2][48 * 68];
  __shared__ __align__(16) float wT[2][48 * 68];
  float acc[4][4];
#pragma unroll
  for (int i = 0; i < 4; ++i)
#pragma unroll
    for (int j = 0; j < 4; ++j) acc[i][j] = 0.f;
  const int kbeg = ks * Kslice;
  const int nch = Kslice / 48;
  int sb[3], skg[3];
#pragma unroll
  for (int it = 0; it < 3; ++it) {
    int i = t + it * 256;
    sb[it] = i / 12;
    skg[it] = i % 12;
  }
  float4 ra[3], rw[3];
#pragma unroll
  for (int it = 0; it < 3; ++it) {
    int k = kbeg + skg[it] * 4;
    float4 v;
    if (asplit) {
      v = (k < asplit) ? *(const float4*)&A0[sb[it] * 1920 + zo + k]
                       : *(const float4*)&A1[sb[it] * 1920 + zo + k - asplit];
    } else {
      v = *(const float4*)&A0[zo + sb[it] * K + k];
    }
    if (reluA) {
      v.x = fmaxf(v.x, 0.f); v.y = fmaxf(v.y, 0.f);
      v.z = fmaxf(v.z, 0.f); v.w = fmaxf(v.w, 0.f);
    }
    ra[it] = v;
    rw[it] = *(const float4*)&W[(otile * 64 + sb[it]) * K + kbeg + skg[it] * 4];
  }
  int p = 0;
  for (int c = 0; c < nch; ++c, p ^= 1) {
#pragma unroll
    for (int it = 0; it < 3; ++it) {
      int row4 = skg[it] * 4, col = sb[it];
      float4 v = ra[it];
      eT[p][(row4 + 0) * 68 + col] = v.x; eT[p][(row4 + 1) * 68 + col] = v.y;
      eT[p][(row4 + 2) * 68 + col] = v.z; eT[p][(row4 + 3) * 68 + col] = v.w;
      float4 w = rw[it];
      wT[p][(row4 + 0) * 68 + col] = w.x; wT[p][(row4 + 1) * 68 + col] = w.y;
      wT[p][(row4 + 2) * 68 + col] = w.z; wT[p][(row4 + 3) * 68 + col] = w.w;
    }
    __syncthreads();
    if (c + 1 < nch) {
      int k0 = kbeg + (c + 1) * 48;
#pragma unroll
      for (int it = 0; it < 3; ++it) {
        int k = k0 + skg[it] * 4;
        float4 v;
        if (asplit) {
          v = (k < asplit) ? *(const float4*)&A0[sb[it] * 1920 + zo + k]
                           : *(const float4*)&A1[sb[it] * 1920 + zo + k - asplit];
        } else {
          v = *(const float4*)&A0[zo + sb[it] * K + k];
        }
        if (reluA) {
          v.x = fmaxf(v.x, 0.f); v.y = fmaxf(v.y, 0.f);
          v.z = fmaxf(v.z, 0.f); v.w = fmaxf(v.w, 0.f);
        }
        ra[it] = v;
        rw[it] = *(const float4*)&W[(otile * 64 + sb[it]) * K + k0 + skg[it] * 4];
      }
    }
#pragma unroll 4
    for (int kk = 0; kk < 48; ++kk) {
      float av[4], wv[4];
      *(float4*)av = *(const float4*)&eT[p][kk * 68 + bt * 4];
      *(float4*)wv = *(const float4*)&wT[p][kk * 68 + ot * 4];
#pragma unroll
      for (int i = 0; i < 4; ++i)
#pragma unroll
        for (int j = 0; j < 4; ++j) acc[i][j] += av[i] * wv[j];
    }
  }
#pragma unroll
  for (int i = 0; i < 4; ++i)
#pragma unroll
    for (int j = 0; j < 4; ++j)
      atomicAdd(&C[(bt * 4 + i) * N + otile * 64 + ot * 4 + j], acc[i][j]);
}

// ------- classifier layer 1 (with fused group-pooling) -------
__global__ __launch_bounds__(256) void k_cls1(
    const float* __restrict__ em3, const float* __restrict__ b2m,
    const float* __restrict__ b2e, const float* __restrict__ w1mT,
    const float* __restrict__ b1m, const float* __restrict__ w1eT,
    const float* __restrict__ b1e, float* __restrict__ h2) {
  int which = blockIdx.z, g = blockIdx.y, t = threadIdx.x;
  const float* em = em3 + which * 61440 + g * 7680;
  const float* b2 = which ? b2e : b2m;
  const float* WT = which ? w1eT : w1mT;
  const float* b1 = which ? b1e : b1m;
  __shared__ float pl[960];
  for (int d = t; d < 960; d += 256) {
    float s = 0.f;
#pragma unroll
    for (int r = 0; r < 8; ++r) s += em[r * 960 + d];
    pl[d] = s * 0.125f + b2[d];
  }
  __syncthreads();
  int o = blockIdx.x * 256 + t;
  if (o >= 1920) return;
  float acc = 0.f;
#pragma unroll 8
  for (int k = 0; k < 960; ++k) acc += WT[k * 1920 + o] * pl[k];
  float z = acc + b1[o];
  h2[which * 15360 + g * 1920 + o] = z * fminf(fmaxf(z + 3.f, 0.f), 6.f) * (1.f / 6.f);
}

// ------- classifier layer 2 + final concat -------
__global__ __launch_bounds__(128) void k_cls2(
    const float* __restrict__ h2, const float* __restrict__ w2m,
    const float* __restrict__ b2m, const float* __restrict__ w2e,
    const float* __restrict__ b2e, float* __restrict__ out) {
  int g = blockIdx.x, which = blockIdx.y;
  int t = threadIdx.x, j = t >> 6, lane = t & 63;
  const float* h = h2 + which * 15360 + g * 1920;
  const float* W = (which ? w2e : w2m) + j * 1920;
  const float* bb = which ? b2e : b2m;
  float s = 0.f;
  for (int k = lane; k < 1920; k += 64) s += h[k] * W[k];
  for (int off = 32; off >= 1; off >>= 1) s += __shfl_down(s, off);
  if (lane == 0) out[g * 4 + which * 2 + j] = s + bb[j];
}

// =======================================================================
extern "C" void kernel_launch(void* const* d_in, const int* in_sizes, int n_in,
                              void* d_out, int out_size, void* d_ws, size_t ws_size,
                              hipStream_t stream) {
  const float* x_p = (const float*)d_in[0];
  const float* x_i = (const float*)d_in[1];
  const float* scr_w_in = (const float*)d_in[2];
  const float* scr_bn_in = (const float*)d_in[3];
  const float* scr_w1 = (const float*)d_in[4];
  const float* scr_bn1 = (const float*)d_in[5];
  const float* scr_w2 = (const float*)d_in[6];
  const float* scr_bn2 = (const float*)d_in[7];
  const float* scr_w_out = (const float*)d_in[8];
  const float* scr_bn_out = (const float*)d_in[9];
  const float* cca1x1_w = (const float*)d_in[10];
  const float* cca1x1_bn = (const float*)d_in[11];
  const float* cca0_c2_w = (const float*)d_in[12];
  const float* cca0_c2_bn = (const float*)d_in[13];
  const float* cca0_c1_w = (const float*)d_in[14];
  const float* cca0_c1_bn = (const float*)d_in[15];
  const float* cca0_p_w = (const float*)d_in[16];
  const float* cca0_p_bn = (const float*)d_in[17];
  const float* cca1_c2_w = (const float*)d_in[18];
  const float* cca1_c2_bn = (const float*)d_in[19];
  const float* cca1_c1_w = (const float*)d_in[20];
  const float* cca1_c1_bn = (const float*)d_in[21];
  const float* cca1_p_w = (const float*)d_in[22];
  const float* cca1_p_bn = (const float*)d_in[23];
  const float* meta_w1 = (const float*)d_in[24];
  const float* meta_w2 = (const float*)d_in[25];
  const float* meta_b2 = (const float*)d_in[26];
  const float* ene_w1 = (const float*)d_in[27];
  const float* ene_w2 = (const float*)d_in[28];
  const float* ene_b2 = (const float*)d_in[29];
  const float* mcls_w1 = (const float*)d_in[30];
  const float* mcls_b1 = (const float*)d_in[31];
  const float* mcls_w2 = (const float*)d_in[32];
  const float* mcls_b2 = (const float*)d_in[33];
  const float* ecls_w1 = (const float*)d_in[34];
  const float* ecls_b1 = (const float*)d_in[35];
  const float* ecls_w2 = (const float*)d_in[36];
  const float* ecls_b2 = (const float*)d_in[37];

  float* ws = (float*)d_ws;
  float* PART = ws + OFF_XN;   // 64x8x49 partial sums
  unsigned short* Y1BF = (unsigned short*)(ws + OFF_Y1BF);
  unsigned* KMTU = (unsigned*)(ws + OFF_KMT);
  unsigned short* W2BF = (unsigned short*)(ws + OFF_W2BF);
  unsigned short* Y2BF = (unsigned short*)(ws + OFF_Y2BF);
  float* T = ws + OFF_T;
  float* XPN = ws + OFF_XPN;
  float* SQ = ws + OFF_SQ;
  float* S0P = ws + OFF_S0P;
  float* S1Y1 = ws + OFF_S1Y1;
  float* S1Y2 = ws + OFF_S1Y2;
  float* ATT = ws + OFF_ATT;
  float* EPI = ws + OFF_EPI;
  float* H1 = ws + OFF_H1;
  float* EM3 = ws + OFF_EM3;
  float* H2 = ws + OFF_H2;
  float* WOUTT = ws + OFF_WOUTT;
  float* CCAT = ws + OFF_CCAT;
  float* MCLST = ws + OFF_MCLST;
  float* ECLST = ws + OFF_ECLST;
  unsigned* WBF = (unsigned*)(ws + OFF_WBF);

  // weight preps
  k_transpose_t<<<dim3(3, 30), 256, 0, stream>>>(scr_w_out, WOUTT, 960, 96);
  k_transpose_t<<<dim3(30, 3), 256, 0, stream>>>(cca1x1_w, CCAT, 96, 960);
  k_transpose_t<<<dim3(30, 60), 256, 0, stream>>>(mcls_w1, MCLST, 1920, 960);
  k_transpose_t<<<dim3(30, 60), 256, 0, stream>>>(ecls_w1, ECLST, 1920, 960);
  k_prepwbf<<<180, 256, 0, stream>>>(scr_w_in, WBF);
  k_kmat<<<4256, 256, 0, stream>>>(scr_w1, KMTU);
  k_w2bf<<<336, 256, 0, stream>>>(scr_w2, W2BF);

  for (int br = 0; br < 2; ++br) {
    const float* x = br ? x_i : x_p;
    k_l2npart<<<dim3(64, 8), 256, 0, stream>>>(x, PART);
    k_scr_in<<<dim3(64, 7), 512, 0, stream>>>(x, PART, WBF, scr_bn_in, Y1BF);
    k_conv1g<<<dim3(64, 7), 256, 0, stream>>>((const unsigned*)Y1BF, KMTU,
                                              scr_bn1, Y2BF);
    k_conv2g<<<98, 256, 0, stream>>>((const unsigned*)Y2BF, (const unsigned*)W2BF,
                                     scr_bn2, T);
    k_out_cca<<<dim3(64, 7), 512, 0, stream>>>(T, WOUTT, scr_bn_out, x, CCAT,
                                               cca1x1_bn, XPN + br * 3010560,
                                               SQ + br * 301056);
  }
  k_mid<<<64, 512, 0, stream>>>(SQ, SQ + 301056, cca0_c2_w, cca0_c2_bn,
                                cca0_c1_w, cca0_c1_bn, cca0_p_w, cca0_p_bn, S0P);
  k_sep1a<<<dim3(64, 7), 512, 0, stream>>>(S0P, cca1_c2_w, cca1_c2_bn, S1Y1);
  k_sep1b<<<dim3(64, 7), 512, 0, stream>>>(S1Y1, cca1_c1_w, cca1_c1_bn, S1Y2);
  k_c4attn<<<64, 256, 0, stream>>>(S1Y2, cca1_p_w, cca1_p_bn, ATT, ATT + 3136);
  k_pool<<<dim3(64, 2), 256, 0, stream>>>(XPN, ATT, EPI);

  hipMemsetAsync(H1, 0, (245760u + 122880u) * sizeof(float), stream);
  k_gemm64<<<dim3(30, 8, 2), 256, 0, stream>>>(EPI, EPI + 122880, 960, 0,
                                               meta_w1, ene_w1, 1920, 240,
                                               H1, H1 + 122880, 1920, 960);
  k_gemm64<<<dim3(15, 8, 2), 256, 0, stream>>>(H1, nullptr, 0, 1,
                                               meta_w2, ene_w2, 1920, 240,
                                               EM3, EM3 + 61440, 960, 122880);
  k_cls1<<<dim3(8, 8, 2), 256, 0, stream>>>(EM3, meta_b2, ene_b2, MCLST, mcls_b1,
                                            ECLST, ecls_b1, H2);
  k_cls2<<<dim3(8, 2), 128, 0, stream>>>(H2, mcls_w2, mcls_b2, ecls_w2, ecls_b2,
                                         (float*)d_out);
}

// Round 11
// 686.550 us; speedup vs baseline: 1.0675x; 1.0390x over previous
//
#include <hip/hip_runtime.h>
#include <hip/hip_bf16.h>

// RtNet25DDualRENet forward. Round 16:
//  - k_cls1 v2: was grid (8,8,2)=128 blocks (0.5/CU, occupancy 4.5%, VALUBusy
//    5.3%, 49us vs ~1us work floor — pure grid starvation). Now grid (30,8,2)
//    =480 blocks; per block 64 outputs x 4-way K-split (t&63 / t>>6), LDS
//    reduce, bias+hardswish by t<64. 5x waves, 4x shorter serial chain.
//  - k_scr_in v9 (cvt_pk, verified R10: VALU 34->24.6%) kept, declared at
//    structural floor per pre-commit. k_gemm64 v2 kept.

#define BNINV 0.9999950000374997f  // 1/sqrt(1+1e-5)

typedef __attribute__((ext_vector_type(8))) short bf16x8;
typedef __attribute__((ext_vector_type(4))) float f32x4;

__device__ inline unsigned short f2bf(float f) {
  union { float f; unsigned u; } x; x.f = f;
  unsigned r = x.u + 0x7fffu + ((x.u >> 16) & 1u);  // RNE
  return (unsigned short)(r >> 16);
}

// ---------------- workspace layout (float offsets) ----------------
#define OFF_XN      0u          // PART (64 x 8 x 49 partial sums)
#define OFF_Y1BF    3010560u    // bf16 [3136 pairs][2432]
#define OFF_KMT     6823936u    // bf16 [896 n][2432 k]
#define OFF_W2BF    7913472u    // bf16 [96][896]
#define OFF_Y2BF    7956480u    // bf16 [3136][896]
#define OFF_T       9361408u    // (b,49,96)
#define OFF_XPN     9662464u    // 2 x (b,49,960)
#define OFF_SQ      15683584u   // 2 x (b,49,96)
#define OFF_S0P     16285696u   // (b,16,49,49)
#define OFF_S1Y1    18744320u
#define OFF_S1Y2    21202944u
#define OFF_ATT     23661568u
#define OFF_EPI     23667840u
#define OFF_H1      23913600u   // 2 x (64,1920)
#define OFF_EM3     24159360u   // 2 x (64,960)
#define OFF_H2      24297600u
#define OFF_WOUTT   24328320u
#define OFF_CCAT    24420480u
#define OFF_MCLST   24512640u
#define OFF_ECLST   26355840u
#define OFF_WBF     28199040u   // 46080 uints (96x960 bf16 pairs)

// ---------------- tiled transpose ----------------
__global__ __launch_bounds__(256) void k_transpose_t(const float* __restrict__ in,
                                                     float* __restrict__ out,
                                                     int R, int C) {
  __shared__ float tl[32][33];
  int c0 = blockIdx.x * 32, r0 = blockIdx.y * 32;
  int tx = threadIdx.x & 31, ty = threadIdx.x >> 5;
#pragma unroll
  for (int i = 0; i < 4; ++i)
    tl[ty + i * 8][tx] = in[(r0 + ty + i * 8) * C + c0 + tx];
  __syncthreads();
#pragma unroll
  for (int i = 0; i < 4; ++i)
    out[(c0 + ty + i * 8) * R + r0 + tx] = tl[tx][ty + i * 8];
}

// ---- prep: scr_w_in -> packed bf16 pairs ----
__global__ void k_prepwbf(const float* __restrict__ w_in, unsigned* __restrict__ WbfU) {
  int i = blockIdx.x * 256 + threadIdx.x;
  if (i >= 46080) return;
  float a = w_in[2 * i], b = w_in[2 * i + 1];
  WbfU[i] = (unsigned)f2bf(a) | ((unsigned)f2bf(b) << 16);
}

// ---- prep: conv1 kernel matrix Kmat_t[n=(o,d)][k=(ic,pos)] bf16 [896][2432] ----
__global__ void k_kmat(const float* __restrict__ w1, unsigned* __restrict__ kmtu) {
  int i = blockIdx.x * 256 + threadIdx.x;
  if (i >= 896 * 1216) return;
  int n = i / 1216, ku = i % 1216;
  unsigned out = 0;
#pragma unroll
  for (int h = 0; h < 2; ++h) {
    int k = ku * 2 + h;
    float v = 0.f;
    if (n < 864 && k < 2400) {
      int o = n / 9, d = n % 9, i2 = d / 3, j2 = d % 3;
      int ic = k / 25, pos = k % 25, u = pos / 5, vv = pos % 5;
      int di = u - i2, dj = vv - j2;
      if ((unsigned)di < 3u && (unsigned)dj < 3u)
        v = w1[(o * 96 + ic) * 9 + di * 3 + dj];
    }
    out |= ((unsigned)f2bf(v)) << (16 * h);
  }
  kmtu[i] = out;
}

// ---- prep: w2 -> bf16 [96][896] ----
__global__ void k_w2bf(const float* __restrict__ w2, unsigned short* __restrict__ w2b) {
  int i = blockIdx.x * 256 + threadIdx.x;
  if (i >= 86016) return;
  int o2 = i / 896, k = i % 896;
  w2b[i] = (k < 864) ? f2bf(w2[o2 * 864 + k]) : (unsigned short)0;
}

// ---------------- K1: partial sum-of-squares of relu(x) per (b,p) ----------------
__global__ __launch_bounds__(256) void k_l2npart(const float* __restrict__ x,
                                                 float* __restrict__ part) {
  int b = blockIdx.x, sl = blockIdx.y, t = threadIdx.x;
  __shared__ float red[256];
  const float* xb = x + b * 47040 + sl * 5880;
  int p = t & 63, s2 = t >> 6;
  float s = 0.f;
  if (p < 49) {
#pragma unroll 6
    for (int c = 0; c < 30; ++c) {
      float v = xb[(s2 * 30 + c) * 49 + p];
      if (v > 0.f) s += v * v;
    }
  }
  red[t] = s;
  __syncthreads();
  if (t < 49)
    part[(b * 8 + sl) * 49 + t] = red[t] + red[t + 64] + red[t + 128] + red[t + 192];
}

// ------- K2: fused l2norm + self-corr x scr_w_in einsum + BN + relu (bf16 MFMA) -------
// grid (64 b, 7 h). v9: float4 staging, b128 reads, cvt_pk packing.
__global__ __launch_bounds__(512) void k_scr_in(
    const float* __restrict__ x, const float* __restrict__ part,
    const unsigned* __restrict__ WbfU,
    const float* __restrict__ bn, unsigned short* __restrict__ y1bf) {
  const int b = blockIdx.x, h = blockIdx.y, t = threadIdx.x;
  const int wave = t >> 6, lane = t & 63, quad = lane >> 4, lr = lane & 15;
  const int mh = wave >> 2, ng = wave & 3;
  __shared__ __align__(16) short Pl[2][192 * 40];
  __shared__ __align__(16) short Wl[2][96 * 40];
  __shared__ __align__(16) float xc[2][2160];   // [j][k] stride 36
  __shared__ float invL[60];
  // zero-pad y1bf[pair][2400..2432)
  if (t < 112) {
    int pairL = t >> 4, ku = t & 15;
    ((unsigned*)y1bf)[(unsigned)(b * 49 + h * 7 + pairL) * 1216u + 1200u + ku] = 0u;
  }
  // per-padded-pixel inverse norms
  if (t < 60) {
    int r = t / 12, wc = t - r * 12;
    int row = h + r - 2, w = wc - 2;
    float iv = 0.f;
    if ((unsigned)row < 7u && (unsigned)w < 7u) {
      int p = row * 7 + w;
      float s = 0.f;
#pragma unroll
      for (int sl = 0; sl < 8; ++sl) s += part[(b * 8 + sl) * 49 + p];
      iv = 1.f / fmaxf(sqrtf(s), 1e-12f);
    }
    invL[t] = iv;
  }
  f32x4 acc[3][3];
#pragma unroll
  for (int m = 0; m < 3; ++m)
#pragma unroll
    for (int n = 0; n < 3; ++n) acc[m][n] = (f32x4){0.f, 0.f, 0.f, 0.f};
  const float* xb = x + b * 47040;
  const int sj = t % 60, sk4 = t / 60;
  const bool sOk = (t < 480);
  int pixOff = 0;
  bool pixIn = false;
  if (sOk) {
    int r = sj / 12, wc = sj - r * 12;
    int row = h + r - 2, w = wc - 2;
    pixIn = ((unsigned)row < 7u && (unsigned)w < 7u);
    pixOff = row * 7 + w;
  }
  const int colB = t >> 1, halfB = t & 1;
  int i1 = 0, i2 = 0;
  if (t < 384) {
    int cc = colB < 175 ? colB : 174;
    int wp = cc / 25, uv = cc - wp * 25, du = uv / 5, dv = uv - du * 5;
    i1 = (26 + wp) * 36;
    i2 = (du * 12 + wp + dv) * 36;
  }
  float xr0[4] = {0.f, 0.f, 0.f, 0.f};
  unsigned wr0[3];
  // prefetch chunk 0
  {
    if (sOk && pixIn) {
      const float* src = &xb[(sk4 * 4) * 49 + pixOff];
#pragma unroll
      for (int q = 0; q < 4; ++q) xr0[q] = src[q * 49];
    }
#pragma unroll
    for (int it = 0; it < 3; ++it) {
      int i = t + it * 512;
      wr0[it] = WbfU[(i >> 4) * 480 + (i & 15)];
    }
  }
  __syncthreads();   // invL ready before first LDS store
  int p = 0;
  for (int c = 0; c < 30; ++c, p ^= 1) {
    float* xcb = xc[p];
    if (sOk) {
      float iv = invL[sj];
      float4 v;
      v.x = fmaxf(xr0[0], 0.f) * iv;
      v.y = fmaxf(xr0[1], 0.f) * iv;
      v.z = fmaxf(xr0[2], 0.f) * iv;
      v.w = fmaxf(xr0[3], 0.f) * iv;
      *(float4*)&xcb[sj * 36 + sk4 * 4] = v;
    }
    unsigned* Wlu = (unsigned*)Wl[p];
#pragma unroll
    for (int it = 0; it < 3; ++it) {
      int i = t + it * 512;
      Wlu[(i >> 4) * 20 + (i & 15)] = wr0[it];
    }
    __syncthreads();
    if (t < 384) {
      const float* r1 = &xcb[i1 + halfB * 16];
      const float* r2 = &xcb[i2 + halfB * 16];
      float a[16], cc[16];
#pragma unroll
      for (int q = 0; q < 4; ++q) {
        *(float4*)&a[q * 4] = *(const float4*)&r1[q * 4];
        *(float4*)&cc[q * 4] = *(const float4*)&r2[q * 4];
      }
      unsigned pk[8];
#pragma unroll
      for (int q = 0; q < 8; ++q) {
        float v0 = a[q * 2] * cc[q * 2];
        float v1 = a[q * 2 + 1] * cc[q * 2 + 1];
        asm("v_cvt_pk_bf16_f32 %0, %1, %2" : "=v"(pk[q]) : "v"(v0), "v"(v1));
      }
      unsigned* dst = (unsigned*)Pl[p] + colB * 20 + halfB * 8;
      *(uint4*)dst = *(uint4*)&pk[0];
      *(uint4*)(dst + 4) = *(uint4*)&pk[4];
    }
    __syncthreads();
    if (c < 29) {
      const int k0 = (c + 1) * 32;
      if (sOk) {
        if (pixIn) {
          const float* src = &xb[(k0 + sk4 * 4) * 49 + pixOff];
#pragma unroll
          for (int q = 0; q < 4; ++q) xr0[q] = src[q * 49];
        }
      }
      int base = k0 >> 1;
#pragma unroll
      for (int it = 0; it < 3; ++it) {
        int i = t + it * 512;
        wr0[it] = WbfU[(i >> 4) * 480 + base + (i & 15)];
      }
    }
    const int ko = quad * 8;
    bf16x8 af[3], bfr[3];
#pragma unroll
    for (int m = 0; m < 3; ++m)
      af[m] = *(const bf16x8*)&Wl[p][((mh * 3 + m) * 16 + lr) * 40 + ko];
#pragma unroll
    for (int n = 0; n < 3; ++n)
      bfr[n] = *(const bf16x8*)&Pl[p][((ng * 3 + n) * 16 + lr) * 40 + ko];
#pragma unroll
    for (int m = 0; m < 3; ++m)
#pragma unroll
      for (int n = 0; n < 3; ++n)
        acc[m][n] = __builtin_amdgcn_mfma_f32_16x16x32_bf16(
            af[m], bfr[n], acc[m][n], 0, 0, 0);
  }
#pragma unroll
  for (int n = 0; n < 3; ++n) {
    int col = (ng * 3 + n) * 16 + lr;
    if (col >= 175) continue;
    int wp = col / 25, uv = col - wp * 25;
    unsigned pairIdx = (unsigned)(b * 49 + h * 7 + wp);
#pragma unroll
    for (int m = 0; m < 3; ++m) {
#pragma unroll
      for (int r = 0; r < 4; ++r) {
        int o = (mh * 3 + m) * 16 + quad * 4 + r;
        float g = BNINV * bn[o], bt = bn[96 + o];
        float v = fmaxf(acc[m][n][r] * g + bt, 0.f);
        y1bf[pairIdx * 2432u + (unsigned)(o * 25 + uv)] = f2bf(v);
      }
    }
  }
}

// ------- K3: conv1 MFMA GEMM. grid (64 m-slots [49 used], 7 n) -------
__global__ __launch_bounds__(256) void k_conv1g(
    const unsigned* __restrict__ y1u, const unsigned* __restrict__ kmtu,
    const float* __restrict__ bn1, unsigned short* __restrict__ y2bf) {
  if (blockIdx.x >= 49) return;
  const int t = threadIdx.x;
  const int wave = t >> 6, lane = t & 63, quad = lane >> 4, lr = lane & 15;
  const int mh = wave >> 1, nh = wave & 1;
  const int pairBase = blockIdx.x * 64, nBase = blockIdx.y * 128;
  __shared__ __align__(16) short Ash[64 * 72];
  __shared__ __align__(16) short Bsh[128 * 72];
  __shared__ float bnl[192];
  unsigned* Au = (unsigned*)Ash;
  unsigned* Bu = (unsigned*)Bsh;
  if (t < 192) bnl[t] = bn1[t];
  f32x4 acc[2][4];
#pragma unroll
  for (int m = 0; m < 2; ++m)
#pragma unroll
    for (int n = 0; n < 4; ++n) acc[m][n] = (f32x4){0.f, 0.f, 0.f, 0.f};
  const int prA = t >> 2, qA = t & 3;
  const int nB = t >> 1, qB = t & 1;
  for (int c = 0; c < 38; ++c) {
    int ku0 = c * 32;
    __syncthreads();
    {
      const unsigned* src = y1u + (unsigned)(pairBase + prA) * 1216u + ku0 + qA * 8;
      unsigned* dst = Au + prA * 36 + qA * 8;
      *(uint4*)dst = *(const uint4*)src;
      *(uint4*)(dst + 4) = *(const uint4*)(src + 4);
    }
    {
      const unsigned* src = kmtu + (unsigned)(nBase + nB) * 1216u + ku0 + qB * 16;
      unsigned* dst = Bu + nB * 36 + qB * 16;
#pragma unroll
      for (int q = 0; q < 4; ++q)
        *(uint4*)(dst + q * 4) = *(const uint4*)(src + q * 4);
    }
    __syncthreads();
#pragma unroll
    for (int s = 0; s < 2; ++s) {
      int ko = s * 32 + quad * 8;
      bf16x8 af[2], bf[4];
#pragma unroll
      for (int m = 0; m < 2; ++m)
        af[m] = *(const bf16x8*)&Ash[((mh * 2 + m) * 16 + lr) * 72 + ko];
#pragma unroll
      for (int n = 0; n < 4; ++n)
        bf[n] = *(const bf16x8*)&Bsh[((nh * 4 + n) * 16 + lr) * 72 + ko];
#pragma unroll
      for (int m = 0; m < 2; ++m)
#pragma unroll
        for (int n = 0; n < 4; ++n)
          acc[m][n] = __builtin_amdgcn_mfma_f32_16x16x32_bf16(
              af[m], bf[n], acc[m][n], 0, 0, 0);
    }
  }
#pragma unroll
  for (int m = 0; m < 2; ++m) {
#pragma unroll
    for (int r = 0; r < 4; ++r) {
      unsigned pair = (unsigned)(pairBase + (mh * 2 + m) * 16 + quad * 4 + r);
#pragma unroll
      for (int n = 0; n < 4; ++n) {
        int nn = nBase + (nh * 4 + n) * 16 + lr;
        unsigned short outv = 0;
        if (nn < 864) {
          int o = nn / 9;
          float v = fmaxf(acc[m][n][r] * (BNINV * bnl[o]) + bnl[96 + o], 0.f);
          outv = f2bf(v);
        }
        y2bf[pair * 896u + nn] = outv;
      }
    }
  }
}

// ------- K4: conv2 MFMA GEMM, 98 blocks of 32 pairs -------
__global__ __launch_bounds__(256) void k_conv2g(
    const unsigned* __restrict__ y2u, const unsigned* __restrict__ w2u,
    const float* __restrict__ bn2, float* __restrict__ tout) {
  const int t = threadIdx.x;
  const int wave = t >> 6, lane = t & 63, quad = lane >> 4, lr = lane & 15;
  const int mh = wave >> 1, nh = wave & 1;
  const int pairBase = blockIdx.x * 32;
  __shared__ __align__(16) short Ash[32 * 72];
  __shared__ __align__(16) short Bsh[96 * 72];
  __shared__ float bnl[192];
  unsigned* Au = (unsigned*)Ash;
  unsigned* Bu = (unsigned*)Bsh;
  if (t < 192) bnl[t] = bn2[t];
  f32x4 acc[3];
#pragma unroll
  for (int n = 0; n < 3; ++n) acc[n] = (f32x4){0.f, 0.f, 0.f, 0.f};
  const int prA = t >> 3, qA = (t & 7) * 4;
  const int nB = t >> 1, qB = (t & 1) * 16;
  for (int c = 0; c < 14; ++c) {
    int ku0 = c * 32;
    __syncthreads();
    {
      const unsigned* src = y2u + (unsigned)(pairBase + prA) * 448u + ku0 + qA;
      *(uint4*)(Au + prA * 36 + qA) = *(const uint4*)src;
    }
    if (t < 192) {
      const unsigned* src = w2u + (unsigned)nB * 448u + ku0 + qB;
      unsigned* dst = Bu + nB * 36 + qB;
#pragma unroll
      for (int q = 0; q < 4; ++q)
        *(uint4*)(dst + q * 4) = *(const uint4*)(src + q * 4);
    }
    __syncthreads();
#pragma unroll
    for (int s = 0; s < 2; ++s) {
      int ko = s * 32 + quad * 8;
      bf16x8 af;
      af = *(const bf16x8*)&Ash[(mh * 16 + lr) * 72 + ko];
#pragma unroll
      for (int n = 0; n < 3; ++n) {
        bf16x8 bf = *(const bf16x8*)&Bsh[((nh * 3 + n) * 16 + lr) * 72 + ko];
        acc[n] = __builtin_amdgcn_mfma_f32_16x16x32_bf16(af, bf, acc[n], 0, 0, 0);
      }
    }
  }
#pragma unroll
  for (int r = 0; r < 4; ++r) {
    unsigned pair = (unsigned)(pairBase + mh * 16 + quad * 4 + r);
#pragma unroll
    for (int n = 0; n < 3; ++n) {
      int o = (nh * 3 + n) * 16 + lr;
      float v = fmaxf(acc[n][r] * (BNINV * bnl[o]) + bnl[96 + o], 0.f);
      tout[pair * 96u + o] = v;
    }
  }
}

// ------- K5: fused w_out GEMM + BN + residual relu + mean-sub + cca1 + l2norm -------
__global__ __launch_bounds__(512) void k_out_cca(
    const float* __restrict__ tin, const float* __restrict__ wouT,
    const float* __restrict__ bno, const float* __restrict__ x,
    const float* __restrict__ ccaT, const float* __restrict__ bnc,
    float* __restrict__ xpn, float* __restrict__ sq) {
  int b = blockIdx.x, pr = blockIdx.y, t = threadIdx.x;
  __shared__ __align__(16) float tl2[96 * 8];     // 3.0 KB  [ic][pl]
  __shared__ __align__(16) float xrT[960 * 8];    // 30.0 KB [o][pl] : x then y
  __shared__ float red[8 * 520];                  // 16.3 KB pl-major scratch
  __shared__ float mean[7];
  __shared__ float sv[7 * 97];
  __shared__ float inv7[7];
  for (int i = t; i < 672; i += 512) {
    int pl = i / 96, ic = i - pl * 96;
    tl2[ic * 8 + pl] = tin[(b * 49 + pr * 7 + pl) * 96 + ic];
  }
  for (int i = t; i < 6720; i += 512) {
    int o = i / 7, pl = i - o * 7;
    xrT[o * 8 + pl] = x[(b * 960 + o) * 49 + pr * 7 + pl];
  }
  __syncthreads();
  float acc0[7] = {0.f, 0.f, 0.f, 0.f, 0.f, 0.f, 0.f};
  float acc1[7] = {0.f, 0.f, 0.f, 0.f, 0.f, 0.f, 0.f};
  const bool has1 = (t < 448);
  const int o1 = has1 ? t + 512 : t;
#pragma unroll 8
  for (int ic = 0; ic < 96; ++ic) {
    float tv[8];
    *(float4*)&tv[0] = *(const float4*)&tl2[ic * 8];
    *(float4*)&tv[4] = *(const float4*)&tl2[ic * 8 + 4];
    float w0 = wouT[ic * 960 + t];
    float w1 = wouT[ic * 960 + o1];
#pragma unroll
    for (int pl = 0; pl < 7; ++pl) {
      acc0[pl] += w0 * tv[pl];
      acc1[pl] += w1 * tv[pl];
    }
  }
  float part[7] = {0.f, 0.f, 0.f, 0.f, 0.f, 0.f, 0.f};
  {
    float xv[8];
    *(float4*)&xv[0] = *(const float4*)&xrT[t * 8];
    *(float4*)&xv[4] = *(const float4*)&xrT[t * 8 + 4];
    float g = BNINV * bno[t], bt = bno[960 + t];
#pragma unroll
    for (int pl = 0; pl < 7; ++pl) {
      float v = fmaxf(xv[pl] + acc0[pl] * g + bt, 0.f);
      acc0[pl] = v; part[pl] += v;
      xrT[t * 8 + pl] = v;
    }
  }
  if (has1) {
    float xv[8];
    *(float4*)&xv[0] = *(const float4*)&xrT[o1 * 8];
    *(float4*)&xv[4] = *(const float4*)&xrT[o1 * 8 + 4];
    float g = BNINV * bno[o1], bt = bno[960 + o1];
#pragma unroll
    for (int pl = 0; pl < 7; ++pl) {
      float v = fmaxf(xv[pl] + acc1[pl] * g + bt, 0.f);
      acc1[pl] = v; part[pl] += v;
      xrT[o1 * 8 + pl] = v;
    }
  }
#pragma unroll
  for (int pl = 0; pl < 7; ++pl) red[pl * 520 + t] = part[pl];
  __syncthreads();
  if (t < 64) {
#pragma unroll
    for (int pl = 0; pl < 7; ++pl) {
      float s = 0.f;
#pragma unroll
      for (int j = 0; j < 8; ++j) s += red[pl * 520 + t + j * 64];
      red[pl * 520 + t] = s;
    }
  }
  __syncthreads();
  if (t < 7) {
    float s = 0.f;
    for (int i = 0; i < 64; ++i) s += red[t * 520 + i];
    mean[t] = s * (1.f / 960.f);
  }
  __syncthreads();
#pragma unroll
  for (int pl = 0; pl < 7; ++pl)
    xpn[(b * 49 + pr * 7 + pl) * 960 + t] = acc0[pl] - mean[pl];
  if (has1) {
#pragma unroll
    for (int pl = 0; pl < 7; ++pl)
      xpn[(b * 49 + pr * 7 + pl) * 960 + o1] = acc1[pl] - mean[pl];
  }
  float acc2[7] = {0.f, 0.f, 0.f, 0.f, 0.f, 0.f, 0.f};
  float sw = 0.f;
  int o2 = t % 96, csl = t / 96;
  if (t < 480) {
    int c0 = csl * 192;
#pragma unroll 8
    for (int c = c0; c < c0 + 192; ++c) {
      float w = ccaT[c * 96 + o2];
      sw += w;
      float tv[8];
      *(float4*)&tv[0] = *(const float4*)&xrT[c * 8];
      *(float4*)&tv[4] = *(const float4*)&xrT[c * 8 + 4];
#pragma unroll
      for (int pl = 0; pl < 7; ++pl) acc2[pl] += w * tv[pl];
    }
#pragma unroll
    for (int pl = 0; pl < 7; ++pl) red[pl * 520 + t] = acc2[pl];
    red[7 * 520 + t] = sw;
  }
  __syncthreads();
  if (t < 96) {
    float g = BNINV * bnc[t], bt = bnc[96 + t];
    float swt = 0.f;
#pragma unroll
    for (int s5 = 0; s5 < 5; ++s5) swt += red[7 * 520 + s5 * 96 + t];
#pragma unroll
    for (int pl = 0; pl < 7; ++pl) {
      float a = 0.f;
#pragma unroll
      for (int s5 = 0; s5 < 5; ++s5) a += red[pl * 520 + s5 * 96 + t];
      a -= mean[pl] * swt;
      sv[pl * 97 + t] = fmaxf(a * g + bt, 0.f);
    }
  }
  __syncthreads();
  if (t < 112) {
    int pl = t >> 4, ln = t & 15;
    float s = 0.f;
    for (int o = ln; o < 96; o += 16) { float v = sv[pl * 97 + o]; s += v * v; }
    red[pl * 16 + ln] = s;
  }
  __syncthreads();
  if (t < 7) {
    float s = 0.f;
    for (int i = 0; i < 16; ++i) s += red[t * 16 + i];
    inv7[t] = 1.f / fmaxf(sqrtf(s), 1e-8f);
  }
  __syncthreads();
  for (int i = t; i < 672; i += 512) {
    int pl = i / 96, o = i - pl * 96;
    sq[(b * 49 + pr * 7 + pl) * 96 + o] = sv[pl * 97 + o] * inv7[pl];
  }
}

// ------- K7: fused corr + sep4d#0 (512 threads) -------
__global__ __launch_bounds__(512) void k_mid(
    const float* __restrict__ sq0, const float* __restrict__ sq1,
    const float* __restrict__ wuv, const float* __restrict__ bnuv,
    const float* __restrict__ wkl, const float* __restrict__ bnkl,
    const float* __restrict__ pw16, const float* __restrict__ pbn16,
    float* __restrict__ s0p) {
  int b = blockIdx.x, t = threadIdx.x;
  __shared__ float smem[12496];
  float* sL = smem;
  float* qL = smem + 5047;
  float* A = smem + 10094;
  for (int i = t; i < 4704; i += 512) {
    int p = i / 96, c = i % 96;
    sL[p * 103 + c] = sq0[b * 4704 + i];
    qL[p * 103 + c] = sq1[b * 4704 + i];
  }
  __syncthreads();
  for (int i = t; i < 2401; i += 512) {
    int ij = i / 49, kl = i % 49;
    float a = 0.f;
#pragma unroll 4
    for (int c = 0; c < 96; ++c) a += sL[ij * 103 + c] * qL[kl * 103 + c];
    A[i] = a;
  }
  __syncthreads();
  float* B = smem;
  {
    float w0[9];
#pragma unroll
    for (int d = 0; d < 9; ++d) w0[d] = wuv[d];
    float g = BNINV * bnuv[0], bt = bnuv[1];
    for (int i = t; i < 2401; i += 512) {
      int ij = i / 49, kl = i % 49;
      int u = ij / 7, v = ij % 7;
      float a = 0.f;
#pragma unroll
      for (int du = 0; du < 3; ++du) {
        int uu = u + du - 1;
        if ((unsigned)uu >= 7u) continue;
#pragma unroll
        for (int dv = 0; dv < 3; ++dv) {
          int vv = v + dv - 1;
          if ((unsigned)vv >= 7u) continue;
          a += w0[du * 3 + dv] * A[(uu * 7 + vv) * 49 + kl];
        }
      }
      B[i] = fmaxf(a * g + bt, 0.f);
    }
  }
  __syncthreads();
  float* Cc = smem + 4900;
  {
    float w1[9];
#pragma unroll
    for (int d = 0; d < 9; ++d) w1[d] = wkl[d];
    float g = BNINV * bnkl[0], bt = bnkl[1];
    for (int i = t; i < 2401; i += 512) {
      int ij = i / 49, kl = i % 49;
      int kk = kl / 7, ll = kl % 7;
      float a = 0.f;
#pragma unroll
      for (int dh = 0; dh < 3; ++dh) {
        int k2 = kk + dh - 1;
        if ((unsigned)k2 >= 7u) continue;
#pragma unroll
        for (int dw = 0; dw < 3; ++dw) {
          int l2 = ll + dw - 1;
          if ((unsigned)l2 >= 7u) continue;
          a += w1[dh * 3 + dw] * B[ij * 49 + k2 * 7 + l2];
        }
      }
      Cc[i] = a * g + bt;
    }
  }
  __syncthreads();
  for (int o = 0; o < 16; ++o) {
    float sc = pw16[o] * BNINV * pbn16[o], bt2 = pbn16[16 + o];
    for (int i = t; i < 2401; i += 512)
      s0p[(b * 16 + o) * 2401 + i] = fmaxf(Cc[i] * sc + bt2, 0.f);
  }
}

// ---------------- sep4d #1 conv a. grid (64 b, 7 kc), 512 thr ----------------
__global__ __launch_bounds__(512) void k_sep1a(
    const float* __restrict__ in, const float* __restrict__ w,
    const float* __restrict__ bnp, float* __restrict__ out) {
  int b = blockIdx.x, kc = blockIdx.y, t = threadIdx.x;
  __shared__ float inS[16 * 345];
  __shared__ __align__(16) float wP[3072];
  for (int i = t; i < 3072; i += 512) {
    int oc = i / 12, d = i % 12;
    wP[i] = (d < 9) ? w[oc * 9 + d] : 0.f;
  }
  for (int i = t; i < 5488; i += 512) {
    int ic = i / 343, r = i - ic * 343;
    int ij = r / 7, s = r - ij * 7;
    inS[ic * 345 + s * 49 + ij] = in[(b * 16 + ic) * 2401 + ij * 49 + kc * 7 + s];
  }
  __syncthreads();
  for (int rho = t; rho < 784; rho += 512) {
    int o = rho / 49, rem = rho - o * 49, u = rem / 7, s = rem - u * 7;
    float acc[7] = {0.f, 0.f, 0.f, 0.f, 0.f, 0.f, 0.f};
    for (int ic = 0; ic < 16; ++ic) {
      float wv[12];
      const float* wb = &wP[(o * 16 + ic) * 12];
      *(float4*)&wv[0] = *(const float4*)&wb[0];
      *(float4*)&wv[4] = *(const float4*)&wb[4];
      *(float4*)&wv[8] = *(const float4*)&wb[8];
      const float* rowb = &inS[ic * 345 + s * 49];
#pragma unroll
      for (int du = 0; du < 3; ++du) {
        int uu = u + du - 1;
        if ((unsigned)uu >= 7u) continue;
        const float* rr = rowb + uu * 7;
        float r7[7];
#pragma unroll
        for (int q = 0; q < 7; ++q) r7[q] = rr[q];
#pragma unroll
        for (int v = 0; v < 7; ++v) {
          float a = acc[v];
          if (v > 0) a += wv[du * 3 + 0] * r7[v - 1];
          a += wv[du * 3 + 1] * r7[v];
          if (v < 6) a += wv[du * 3 + 2] * r7[v + 1];
          acc[v] = a;
        }
      }
    }
    float g = BNINV * bnp[o], bt = bnp[16 + o];
    long ob = (long)(b * 16 + o) * 2401 + kc * 7 + s;
#pragma unroll
    for (int v = 0; v < 7; ++v)
      out[ob + (u * 7 + v) * 49] = fmaxf(acc[v] * g + bt, 0.f);
  }
}

// ---------------- sep4d #1 conv b. grid (64 b, 7 ir), 512 thr ----------------
__global__ __launch_bounds__(512) void k_sep1b(
    const float* __restrict__ in, const float* __restrict__ w,
    const float* __restrict__ bnp, float* __restrict__ out) {
  int b = blockIdx.x, ir = blockIdx.y, t = threadIdx.x;
  __shared__ float inS[16 * 345];
  __shared__ __align__(16) float wP[3072];
  for (int i = t; i < 3072; i += 512) {
    int oc = i / 12, d = i % 12;
    wP[i] = (d < 9) ? w[oc * 9 + d] : 0.f;
  }
  for (int i = t; i < 5488; i += 512) {
    int ic = i / 343, r = i - ic * 343;
    inS[ic * 345 + r] = in[(b * 16 + ic) * 2401 + ir * 343 + r];
  }
  __syncthreads();
  for (int rho = t; rho < 784; rho += 512) {
    int o = rho / 49, rem = rho - o * 49, jj = rem / 7, k = rem - jj * 7;
    float acc[7] = {0.f, 0.f, 0.f, 0.f, 0.f, 0.f, 0.f};
    for (int ic = 0; ic < 16; ++ic) {
      float wv[12];
      const float* wb = &wP[(o * 16 + ic) * 12];
      *(float4*)&wv[0] = *(const float4*)&wb[0];
      *(float4*)&wv[4] = *(const float4*)&wb[4];
      *(float4*)&wv[8] = *(const float4*)&wb[8];
      const float* rowb = &inS[ic * 345 + jj * 49];
#pragma unroll
      for (int dh = 0; dh < 3; ++dh) {
        int k2 = k + dh - 1;
        if ((unsigned)k2 >= 7u) continue;
        const float* rr = rowb + k2 * 7;
        float r7[7];
#pragma unroll
        for (int q = 0; q < 7; ++q) r7[q] = rr[q];
#pragma unroll
        for (int l = 0; l < 7; ++l) {
          float a = acc[l];
          if (l > 0) a += wv[dh * 3 + 0] * r7[l - 1];
          a += wv[dh * 3 + 1] * r7[l];
          if (l < 6) a += wv[dh * 3 + 2] * r7[l + 1];
          acc[l] = a;
        }
      }
    }
    float g = BNINV * bnp[o], bt = bnp[16 + o];
    long ob = (long)(b * 16 + o) * 2401 + ir * 343 + jj * 49 + k * 7;
#pragma unroll
    for (int l = 0; l < 7; ++l)
      out[ob + l] = acc[l] * g + bt;
  }
}

// ------- K10: fused sep1p + gauss-softmax attention (dual-phase concurrent) -------
__global__ __launch_bounds__(256) void k_c4attn(
    const float* __restrict__ in, const float* __restrict__ pw,
    const float* __restrict__ pbn, float* __restrict__ attn_s,
    float* __restrict__ attn_q) {
  int b = blockIdx.x, t = threadIdx.x;
  __shared__ float c[2401];
  __shared__ float nA[2401];
  __shared__ float nB[2401];
  __shared__ float plw[16];
  if (t < 16) plw[t] = pw[t];
  __syncthreads();
  float g0 = BNINV * pbn[0], bt0 = pbn[1];
  for (int i = t; i < 2401; i += 256) {
    float a = 0.f;
#pragma unroll
    for (int ic = 0; ic < 16; ++ic) a += plw[ic] * in[(b * 16 + ic) * 2401 + i];
    c[i] = a * g0 + bt0;
  }
  __syncthreads();
  if (t < 49) {
    float m = 0.f;
    for (int ij = 0; ij < 49; ++ij) m += c[ij * 49 + t];
    m *= (1.f / 49.f);
    float v = 0.f;
    for (int ij = 0; ij < 49; ++ij) { float d = c[ij * 49 + t] - m; v += d * d; }
    v *= (1.f / 48.f);
    float inv = 1.f / sqrtf(v + 1e-5f);
    float mx = -1e30f;
    for (int ij = 0; ij < 49; ++ij) mx = fmaxf(mx, (c[ij * 49 + t] - m) * inv);
    float s = 0.f;
    for (int ij = 0; ij < 49; ++ij) {
      float e = expf((c[ij * 49 + t] - m) * inv - mx);
      nA[ij * 49 + t] = e; s += e;
    }
    float r = 1.f / s;
    for (int ij = 0; ij < 49; ++ij) nA[ij * 49 + t] *= r;
  } else if (t >= 64 && t < 113) {
    int t2 = t - 64;
    float m = 0.f;
    for (int kl = 0; kl < 49; ++kl) m += c[t2 * 49 + kl];
    m *= (1.f / 49.f);
    float v = 0.f;
    for (int kl = 0; kl < 49; ++kl) { float d = c[t2 * 49 + kl] - m; v += d * d; }
    v *= (1.f / 48.f);
    float inv = 1.f / sqrtf(v + 1e-5f);
    float mx = -1e30f;
    for (int kl = 0; kl < 49; ++kl) mx = fmaxf(mx, (c[t2 * 49 + kl] - m) * inv);
    float s = 0.f;
    for (int kl = 0; kl < 49; ++kl) {
      float e = expf((c[t2 * 49 + kl] - m) * inv - mx);
      nB[t2 * 49 + kl] = e; s += e;
    }
    float r = 1.f / s;
    for (int kl = 0; kl < 49; ++kl) nB[t2 * 49 + kl] *= r;
  }
  __syncthreads();
  if (t < 49) {
    float s = 0.f;
    for (int kl = 0; kl < 49; ++kl) s += nA[t * 49 + kl];
    attn_s[b * 49 + t] = s;
  } else if (t >= 64 && t < 113) {
    int t2 = t - 64;
    float s = 0.f;
    for (int ij = 0; ij < 49; ++ij) s += nB[ij * 49 + t2];
    attn_q[b * 49 + t2] = s;
  }
}

// ------- K11: attention-weighted mean/max pooling -------
__global__ __launch_bounds__(256) void k_pool(const float* __restrict__ xpn,
                                              const float* __restrict__ attn,
                                              float* __restrict__ ep) {
  int b = blockIdx.x, br = blockIdx.y, t = threadIdx.x;
  const float* xb = xpn + br * 3010560 + b * 47040;
  const float* a = attn + br * 3136 + b * 49;
  __shared__ float al[49];
  if (t < 49) al[t] = a[t];
  __syncthreads();
  float* eb = ep + br * 122880 + b * 1920;
  for (int c = t; c < 960; c += 256) {
    float s = 0.f, mx = -1e30f;
#pragma unroll 7
    for (int hw = 0; hw < 49; ++hw) {
      float v = al[hw] * xb[hw * 960 + c];
      s += v; mx = fmaxf(mx, v);
    }
    eb[c] = s * (1.f / 49.f);
    eb[960 + c] = mx;
  }
}

// ------- M=64 GEMM, split-K with atomicAdd; z selects meta/ene -------
// v2: register prefetch + double-buffered LDS, one barrier per 48-k chunk.
__global__ __launch_bounds__(256) void k_gemm64(
    const float* __restrict__ A0, const float* __restrict__ A1, int asplit,
    int reluA, const float* __restrict__ Wm, const float* __restrict__ We,
    int K, int Kslice, float* __restrict__ Cm, float* __restrict__ Ce,
    int N, int zAoff) {
  int otile = blockIdx.x, ks = blockIdx.y, z = blockIdx.z;
  const float* W = z ? We : Wm;
  float* C = z ? Ce : Cm;
  int zo = z * zAoff;
  int t = threadIdx.x, bt = t >> 4, ot = t & 15;
  __shared__ __align__(16) float eT[2][48 * 68];
  __shared__ __align__(16) float wT[2][48 * 68];
  float acc[4][4];
#pragma unroll
  for (int i = 0; i < 4; ++i)
#pragma unroll
    for (int j = 0; j < 4; ++j) acc[i][j] = 0.f;
  const int kbeg = ks * Kslice;
  const int nch = Kslice / 48;
  int sb[3], skg[3];
#pragma unroll
  for (int it = 0; it < 3; ++it) {
    int i = t + it * 256;
    sb[it] = i / 12;
    skg[it] = i % 12;
  }
  float4 ra[3], rw[3];
#pragma unroll
  for (int it = 0; it < 3; ++it) {
    int k = kbeg + skg[it] * 4;
    float4 v;
    if (asplit) {
      v = (k < asplit) ? *(const float4*)&A0[sb[it] * 1920 + zo + k]
                       : *(const float4*)&A1[sb[it] * 1920 + zo + k - asplit];
    } else {
      v = *(const float4*)&A0[zo + sb[it] * K + k];
    }
    if (reluA) {
      v.x = fmaxf(v.x, 0.f); v.y = fmaxf(v.y, 0.f);
      v.z = fmaxf(v.z, 0.f); v.w = fmaxf(v.w, 0.f);
    }
    ra[it] = v;
    rw[it] = *(const float4*)&W[(otile * 64 + sb[it]) * K + kbeg + skg[it] * 4];
  }
  int p = 0;
  for (int c = 0; c < nch; ++c, p ^= 1) {
#pragma unroll
    for (int it = 0; it < 3; ++it) {
      int row4 = skg[it] * 4, col = sb[it];
      float4 v = ra[it];
      eT[p][(row4 + 0) * 68 + col] = v.x; eT[p][(row4 + 1) * 68 + col] = v.y;
      eT[p][(row4 + 2) * 68 + col] = v.z; eT[p][(row4 + 3) * 68 + col] = v.w;
      float4 w = rw[it];
      wT[p][(row4 + 0) * 68 + col] = w.x; wT[p][(row4 + 1) * 68 + col] = w.y;
      wT[p][(row4 + 2) * 68 + col] = w.z; wT[p][(row4 + 3) * 68 + col] = w.w;
    }
    __syncthreads();
    if (c + 1 < nch) {
      int k0 = kbeg + (c + 1) * 48;
#pragma unroll
      for (int it = 0; it < 3; ++it) {
        int k = k0 + skg[it] * 4;
        float4 v;
        if (asplit) {
          v = (k < asplit) ? *(const float4*)&A0[sb[it] * 1920 + zo + k]
                           : *(const float4*)&A1[sb[it] * 1920 + zo + k - asplit];
        } else {
          v = *(const float4*)&A0[zo + sb[it] * K + k];
        }
        if (reluA) {
          v.x = fmaxf(v.x, 0.f); v.y = fmaxf(v.y, 0.f);
          v.z = fmaxf(v.z, 0.f); v.w = fmaxf(v.w, 0.f);
        }
        ra[it] = v;
        rw[it] = *(const float4*)&W[(otile * 64 + sb[it]) * K + k0 + skg[it] * 4];
      }
    }
#pragma unroll 4
    for (int kk = 0; kk < 48; ++kk) {
      float av[4], wv[4];
      *(float4*)av = *(const float4*)&eT[p][kk * 68 + bt * 4];
      *(float4*)wv = *(const float4*)&wT[p][kk * 68 + ot * 4];
#pragma unroll
      for (int i = 0; i < 4; ++i)
#pragma unroll
        for (int j = 0; j < 4; ++j) acc[i][j] += av[i] * wv[j];
    }
  }
#pragma unroll
  for (int i = 0; i < 4; ++i)
#pragma unroll
    for (int j = 0; j < 4; ++j)
      atomicAdd(&C[(bt * 4 + i) * N + otile * 64 + ot * 4 + j], acc[i][j]);
}

// ------- classifier layer 1 v2: grid (30 otile, 8 g, 2 which), N=64/K-split-4 -------
__global__ __launch_bounds__(256) void k_cls1(
    const float* __restrict__ em3, const float* __restrict__ b2m,
    const float* __restrict__ b2e, const float* __restrict__ w1mT,
    const float* __restrict__ b1m, const float* __restrict__ w1eT,
    const float* __restrict__ b1e, float* __restrict__ h2) {
  int which = blockIdx.z, g = blockIdx.y, otile = blockIdx.x, t = threadIdx.x;
  const float* em = em3 + which * 61440 + g * 7680;
  const float* b2 = which ? b2e : b2m;
  const float* WT = which ? w1eT : w1mT;
  const float* b1 = which ? b1e : b1m;
  __shared__ float pl[960];
  __shared__ float red[256];
  for (int d = t; d < 960; d += 256) {
    float s = 0.f;
#pragma unroll
    for (int r = 0; r < 8; ++r) s += em[r * 960 + d];
    pl[d] = s * 0.125f + b2[d];
  }
  __syncthreads();
  int ot = t & 63, ks = t >> 6;
  int o = otile * 64 + ot;
  float acc = 0.f;
  const int k0 = ks * 240;
#pragma unroll 8
  for (int k = k0; k < k0 + 240; ++k) acc += WT[k * 1920 + o] * pl[k];
  red[t] = acc;
  __syncthreads();
  if (t < 64) {
    float s = red[t] + red[t + 64] + red[t + 128] + red[t + 192];
    float z = s + b1[o];
    h2[which * 15360 + g * 1920 + o] =
        z * fminf(fmaxf(z + 3.f, 0.f), 6.f) * (1.f / 6.f);
  }
}

// ------- classifier layer 2 + final concat -------
__global__ __launch_bounds__(128) void k_cls2(
    const float* __restrict__ h2, const float* __restrict__ w2m,
    const float* __restrict__ b2m, const float* __restrict__ w2e,
    const float* __restrict__ b2e, float* __restrict__ out) {
  int g = blockIdx.x, which = blockIdx.y;
  int t = threadIdx.x, j = t >> 6, lane = t & 63;
  const float* h = h2 + which * 15360 + g * 1920;
  const float* W = (which ? w2e : w2m) + j * 1920;
  const float* bb = which ? b2e : b2m;
  float s = 0.f;
  for (int k = lane; k < 1920; k += 64) s += h[k] * W[k];
  for (int off = 32; off >= 1; off >>= 1) s += __shfl_down(s, off);
  if (lane == 0) out[g * 4 + which * 2 + j] = s + bb[j];
}

// =======================================================================
extern "C" void kernel_launch(void* const* d_in, const int* in_sizes, int n_in,
                              void* d_out, int out_size, void* d_ws, size_t ws_size,
                              hipStream_t stream) {
  const float* x_p = (const float*)d_in[0];
  const float* x_i = (const float*)d_in[1];
  const float* scr_w_in = (const float*)d_in[2];
  const float* scr_bn_in = (const float*)d_in[3];
  const float* scr_w1 = (const float*)d_in[4];
  const float* scr_bn1 = (const float*)d_in[5];
  const float* scr_w2 = (const float*)d_in[6];
  const float* scr_bn2 = (const float*)d_in[7];
  const float* scr_w_out = (const float*)d_in[8];
  const float* scr_bn_out = (const float*)d_in[9];
  const float* cca1x1_w = (const float*)d_in[10];
  const float* cca1x1_bn = (const float*)d_in[11];
  const float* cca0_c2_w = (const float*)d_in[12];
  const float* cca0_c2_bn = (const float*)d_in[13];
  const float* cca0_c1_w = (const float*)d_in[14];
  const float* cca0_c1_bn = (const float*)d_in[15];
  const float* cca0_p_w = (const float*)d_in[16];
  const float* cca0_p_bn = (const float*)d_in[17];
  const float* cca1_c2_w = (const float*)d_in[18];
  const float* cca1_c2_bn = (const float*)d_in[19];
  const float* cca1_c1_w = (const float*)d_in[20];
  const float* cca1_c1_bn = (const float*)d_in[21];
  const float* cca1_p_w = (const float*)d_in[22];
  const float* cca1_p_bn = (const float*)d_in[23];
  const float* meta_w1 = (const float*)d_in[24];
  const float* meta_w2 = (const float*)d_in[25];
  const float* meta_b2 = (const float*)d_in[26];
  const float* ene_w1 = (const float*)d_in[27];
  const float* ene_w2 = (const float*)d_in[28];
  const float* ene_b2 = (const float*)d_in[29];
  const float* mcls_w1 = (const float*)d_in[30];
  const float* mcls_b1 = (const float*)d_in[31];
  const float* mcls_w2 = (const float*)d_in[32];
  const float* mcls_b2 = (const float*)d_in[33];
  const float* ecls_w1 = (const float*)d_in[34];
  const float* ecls_b1 = (const float*)d_in[35];
  const float* ecls_w2 = (const float*)d_in[36];
  const float* ecls_b2 = (const float*)d_in[37];

  float* ws = (float*)d_ws;
  float* PART = ws + OFF_XN;   // 64x8x49 partial sums
  unsigned short* Y1BF = (unsigned short*)(ws + OFF_Y1BF);
  unsigned* KMTU = (unsigned*)(ws + OFF_KMT);
  unsigned short* W2BF = (unsigned short*)(ws + OFF_W2BF);
  unsigned short* Y2BF = (unsigned short*)(ws + OFF_Y2BF);
  float* T = ws + OFF_T;
  float* XPN = ws + OFF_XPN;
  float* SQ = ws + OFF_SQ;
  float* S0P = ws + OFF_S0P;
  float* S1Y1 = ws + OFF_S1Y1;
  float* S1Y2 = ws + OFF_S1Y2;
  float* ATT = ws + OFF_ATT;
  float* EPI = ws + OFF_EPI;
  float* H1 = ws + OFF_H1;
  float* EM3 = ws + OFF_EM3;
  float* H2 = ws + OFF_H2;
  float* WOUTT = ws + OFF_WOUTT;
  float* CCAT = ws + OFF_CCAT;
  float* MCLST = ws + OFF_MCLST;
  float* ECLST = ws + OFF_ECLST;
  unsigned* WBF = (unsigned*)(ws + OFF_WBF);

  // weight preps
  k_transpose_t<<<dim3(3, 30), 256, 0, stream>>>(scr_w_out, WOUTT, 960, 96);
  k_transpose_t<<<dim3(30, 3), 256, 0, stream>>>(cca1x1_w, CCAT, 96, 960);
  k_transpose_t<<<dim3(30, 60), 256, 0, stream>>>(mcls_w1, MCLST, 1920, 960);
  k_transpose_t<<<dim3(30, 60), 256, 0, stream>>>(ecls_w1, ECLST, 1920, 960);
  k_prepwbf<<<180, 256, 0, stream>>>(scr_w_in, WBF);
  k_kmat<<<4256, 256, 0, stream>>>(scr_w1, KMTU);
  k_w2bf<<<336, 256, 0, stream>>>(scr_w2, W2BF);

  for (int br = 0; br < 2; ++br) {
    const float* x = br ? x_i : x_p;
    k_l2npart<<<dim3(64, 8), 256, 0, stream>>>(x, PART);
    k_scr_in<<<dim3(64, 7), 512, 0, stream>>>(x, PART, WBF, scr_bn_in, Y1BF);
    k_conv1g<<<dim3(64, 7), 256, 0, stream>>>((const unsigned*)Y1BF, KMTU,
                                              scr_bn1, Y2BF);
    k_conv2g<<<98, 256, 0, stream>>>((const unsigned*)Y2BF, (const unsigned*)W2BF,
                                     scr_bn2, T);
    k_out_cca<<<dim3(64, 7), 512, 0, stream>>>(T, WOUTT, scr_bn_out, x, CCAT,
                                               cca1x1_bn, XPN + br * 3010560,
                                               SQ + br * 301056);
  }
  k_mid<<<64, 512, 0, stream>>>(SQ, SQ + 301056, cca0_c2_w, cca0_c2_bn,
                                cca0_c1_w, cca0_c1_bn, cca0_p_w, cca0_p_bn, S0P);
  k_sep1a<<<dim3(64, 7), 512, 0, stream>>>(S0P, cca1_c2_w, cca1_c2_bn, S1Y1);
  k_sep1b<<<dim3(64, 7), 512, 0, stream>>>(S1Y1, cca1_c1_w, cca1_c1_bn, S1Y2);
  k_c4attn<<<64, 256, 0, stream>>>(S1Y2, cca1_p_w, cca1_p_bn, ATT, ATT + 3136);
  k_pool<<<dim3(64, 2), 256, 0, stream>>>(XPN, ATT, EPI);

  hipMemsetAsync(H1, 0, (245760u + 122880u) * sizeof(float), stream);
  k_gemm64<<<dim3(30, 8, 2), 256, 0, stream>>>(EPI, EPI + 122880, 960, 0,
                                               meta_w1, ene_w1, 1920, 240,
                                               H1, H1 + 122880, 1920, 960);
  k_gemm64<<<dim3(15, 8, 2), 256, 0, stream>>>(H1, nullptr, 0, 1,
                                               meta_w2, ene_w2, 1920, 240,
                                               EM3, EM3 + 61440, 960, 122880);
  k_cls1<<<dim3(30, 8, 2), 256, 0, stream>>>(EM3, meta_b2, ene_b2, MCLST, mcls_b1,
                                             ECLST, ecls_b1, H2);
  k_cls2<<<dim3(8, 2), 128, 0, stream>>>(H2, mcls_w2, mcls_b2, ecls_w2, ecls_b2,
                                         (float*)d_out);
}

// Round 12
// 648.970 us; speedup vs baseline: 1.1293x; 1.0579x over previous
//
#include <hip/hip_runtime.h>
#include <hip/hip_bf16.h>

// RtNet25DDualRENet forward. Round 17:
//  - Branch merge: the SCR chain (l2npart/scr_in/conv1g/conv2g/out_cca) now
//    processes BOTH branches (x_p, x_i) in single 2x-grid dispatches (10->5
//    launches). Kills per-branch occupancy tails (scr_in is LDS-capped at
//    2 blk/CU; 448 blocks = 1.75/CU avg serial, 896 saturates the cap).
//    Branch-1 temporaries alias the S0P/S1Y1/S1Y2 region (dead until k_mid):
//    Y1BF1@16285696, Y2BF1@20099072, T1@21504000 (ends < OFF_ATT).
//  - k_cls1 v2 (verified R11: 49us -> off-profile), k_scr_in v9, k_gemm64 v2 kept.

#define BNINV 0.9999950000374997f  // 1/sqrt(1+1e-5)

typedef __attribute__((ext_vector_type(8))) short bf16x8;
typedef __attribute__((ext_vector_type(4))) float f32x4;

__device__ inline unsigned short f2bf(float f) {
  union { float f; unsigned u; } x; x.f = f;
  unsigned r = x.u + 0x7fffu + ((x.u >> 16) & 1u);  // RNE
  return (unsigned short)(r >> 16);
}

// ---------------- workspace layout (float offsets) ----------------
#define OFF_XN      0u          // PART (2 x 64 x 8 x 49 partial sums)
#define OFF_Y1BF    3010560u    // bf16 [3136 pairs][2432] (branch 0)
#define OFF_KMT     6823936u    // bf16 [896 n][2432 k]
#define OFF_W2BF    7913472u    // bf16 [96][896]
#define OFF_Y2BF    7956480u    // bf16 [3136][896] (branch 0)
#define OFF_T       9361408u    // (b,49,96) (branch 0)
#define OFF_XPN     9662464u    // 2 x (b,49,960)
#define OFF_SQ      15683584u   // 2 x (b,49,96)
#define OFF_S0P     16285696u   // (b,16,49,49) — branch-phase alias: Y1BF1
#define OFF_Y1BF1   16285696u
#define OFF_Y2BF1   20099072u
#define OFF_T1      21504000u
#define OFF_S1Y1    18744320u
#define OFF_S1Y2    21202944u
#define OFF_ATT     23661568u
#define OFF_EPI     23667840u
#define OFF_H1      23913600u   // 2 x (64,1920)
#define OFF_EM3     24159360u   // 2 x (64,960)
#define OFF_H2      24297600u
#define OFF_WOUTT   24328320u
#define OFF_CCAT    24420480u
#define OFF_MCLST   24512640u
#define OFF_ECLST   26355840u
#define OFF_WBF     28199040u   // 46080 uints (96x960 bf16 pairs)

// ---------------- tiled transpose ----------------
__global__ __launch_bounds__(256) void k_transpose_t(const float* __restrict__ in,
                                                     float* __restrict__ out,
                                                     int R, int C) {
  __shared__ float tl[32][33];
  int c0 = blockIdx.x * 32, r0 = blockIdx.y * 32;
  int tx = threadIdx.x & 31, ty = threadIdx.x >> 5;
#pragma unroll
  for (int i = 0; i < 4; ++i)
    tl[ty + i * 8][tx] = in[(r0 + ty + i * 8) * C + c0 + tx];
  __syncthreads();
#pragma unroll
  for (int i = 0; i < 4; ++i)
    out[(c0 + ty + i * 8) * R + r0 + tx] = tl[tx][ty + i * 8];
}

// ---- prep: scr_w_in -> packed bf16 pairs ----
__global__ void k_prepwbf(const float* __restrict__ w_in, unsigned* __restrict__ WbfU) {
  int i = blockIdx.x * 256 + threadIdx.x;
  if (i >= 46080) return;
  float a = w_in[2 * i], b = w_in[2 * i + 1];
  WbfU[i] = (unsigned)f2bf(a) | ((unsigned)f2bf(b) << 16);
}

// ---- prep: conv1 kernel matrix Kmat_t[n=(o,d)][k=(ic,pos)] bf16 [896][2432] ----
__global__ void k_kmat(const float* __restrict__ w1, unsigned* __restrict__ kmtu) {
  int i = blockIdx.x * 256 + threadIdx.x;
  if (i >= 896 * 1216) return;
  int n = i / 1216, ku = i % 1216;
  unsigned out = 0;
#pragma unroll
  for (int h = 0; h < 2; ++h) {
    int k = ku * 2 + h;
    float v = 0.f;
    if (n < 864 && k < 2400) {
      int o = n / 9, d = n % 9, i2 = d / 3, j2 = d % 3;
      int ic = k / 25, pos = k % 25, u = pos / 5, vv = pos % 5;
      int di = u - i2, dj = vv - j2;
      if ((unsigned)di < 3u && (unsigned)dj < 3u)
        v = w1[(o * 96 + ic) * 9 + di * 3 + dj];
    }
    out |= ((unsigned)f2bf(v)) << (16 * h);
  }
  kmtu[i] = out;
}

// ---- prep: w2 -> bf16 [96][896] ----
__global__ void k_w2bf(const float* __restrict__ w2, unsigned short* __restrict__ w2b) {
  int i = blockIdx.x * 256 + threadIdx.x;
  if (i >= 86016) return;
  int o2 = i / 896, k = i % 896;
  w2b[i] = (k < 864) ? f2bf(w2[o2 * 864 + k]) : (unsigned short)0;
}

// ---------------- K1: partial sum-of-squares of relu(x), both branches ----------------
// grid (128 = 2br x 64 b, 8 sl)
__global__ __launch_bounds__(256) void k_l2npart(const float* __restrict__ x_p,
                                                 const float* __restrict__ x_i,
                                                 float* __restrict__ part) {
  int bb = blockIdx.x, sl = blockIdx.y, t = threadIdx.x;
  int br = bb >> 6, b = bb & 63;
  __shared__ float red[256];
  const float* xb = (br ? x_i : x_p) + b * 47040 + sl * 5880;
  int p = t & 63, s2 = t >> 6;
  float s = 0.f;
  if (p < 49) {
#pragma unroll 6
    for (int c = 0; c < 30; ++c) {
      float v = xb[(s2 * 30 + c) * 49 + p];
      if (v > 0.f) s += v * v;
    }
  }
  red[t] = s;
  __syncthreads();
  if (t < 49)
    part[((br * 64 + b) * 8 + sl) * 49 + t] =
        red[t] + red[t + 64] + red[t + 128] + red[t + 192];
}

// ------- K2: fused l2norm + self-corr x scr_w_in einsum + BN + relu, both branches -------
// grid (128 = 2br x 64 b, 7 h). v9 body: float4 staging, b128 reads, cvt_pk.
__global__ __launch_bounds__(512) void k_scr_in(
    const float* __restrict__ x_p, const float* __restrict__ x_i,
    const float* __restrict__ part, const unsigned* __restrict__ WbfU,
    const float* __restrict__ bn,
    unsigned short* __restrict__ y1b0, unsigned short* __restrict__ y1b1) {
  const int bb = blockIdx.x, h = blockIdx.y, t = threadIdx.x;
  const int br = bb >> 6, b = bb & 63;
  const float* x = br ? x_i : x_p;
  unsigned short* y1bf = br ? y1b1 : y1b0;
  const float* partb = part + br * 25088;
  const int wave = t >> 6, lane = t & 63, quad = lane >> 4, lr = lane & 15;
  const int mh = wave >> 2, ng = wave & 3;
  __shared__ __align__(16) short Pl[2][192 * 40];
  __shared__ __align__(16) short Wl[2][96 * 40];
  __shared__ __align__(16) float xc[2][2160];   // [j][k] stride 36
  __shared__ float invL[60];
  // zero-pad y1bf[pair][2400..2432)
  if (t < 112) {
    int pairL = t >> 4, ku = t & 15;
    ((unsigned*)y1bf)[(unsigned)(b * 49 + h * 7 + pairL) * 1216u + 1200u + ku] = 0u;
  }
  // per-padded-pixel inverse norms
  if (t < 60) {
    int r = t / 12, wc = t - r * 12;
    int row = h + r - 2, w = wc - 2;
    float iv = 0.f;
    if ((unsigned)row < 7u && (unsigned)w < 7u) {
      int p = row * 7 + w;
      float s = 0.f;
#pragma unroll
      for (int sl = 0; sl < 8; ++sl) s += partb[(b * 8 + sl) * 49 + p];
      iv = 1.f / fmaxf(sqrtf(s), 1e-12f);
    }
    invL[t] = iv;
  }
  f32x4 acc[3][3];
#pragma unroll
  for (int m = 0; m < 3; ++m)
#pragma unroll
    for (int n = 0; n < 3; ++n) acc[m][n] = (f32x4){0.f, 0.f, 0.f, 0.f};
  const float* xb = x + b * 47040;
  const int sj = t % 60, sk4 = t / 60;
  const bool sOk = (t < 480);
  int pixOff = 0;
  bool pixIn = false;
  if (sOk) {
    int r = sj / 12, wc = sj - r * 12;
    int row = h + r - 2, w = wc - 2;
    pixIn = ((unsigned)row < 7u && (unsigned)w < 7u);
    pixOff = row * 7 + w;
  }
  const int colB = t >> 1, halfB = t & 1;
  int i1 = 0, i2 = 0;
  if (t < 384) {
    int cc = colB < 175 ? colB : 174;
    int wp = cc / 25, uv = cc - wp * 25, du = uv / 5, dv = uv - du * 5;
    i1 = (26 + wp) * 36;
    i2 = (du * 12 + wp + dv) * 36;
  }
  float xr0[4] = {0.f, 0.f, 0.f, 0.f};
  unsigned wr0[3];
  // prefetch chunk 0
  {
    if (sOk && pixIn) {
      const float* src = &xb[(sk4 * 4) * 49 + pixOff];
#pragma unroll
      for (int q = 0; q < 4; ++q) xr0[q] = src[q * 49];
    }
#pragma unroll
    for (int it = 0; it < 3; ++it) {
      int i = t + it * 512;
      wr0[it] = WbfU[(i >> 4) * 480 + (i & 15)];
    }
  }
  __syncthreads();   // invL ready before first LDS store
  int p = 0;
  for (int c = 0; c < 30; ++c, p ^= 1) {
    float* xcb = xc[p];
    if (sOk) {
      float iv = invL[sj];
      float4 v;
      v.x = fmaxf(xr0[0], 0.f) * iv;
      v.y = fmaxf(xr0[1], 0.f) * iv;
      v.z = fmaxf(xr0[2], 0.f) * iv;
      v.w = fmaxf(xr0[3], 0.f) * iv;
      *(float4*)&xcb[sj * 36 + sk4 * 4] = v;
    }
    unsigned* Wlu = (unsigned*)Wl[p];
#pragma unroll
    for (int it = 0; it < 3; ++it) {
      int i = t + it * 512;
      Wlu[(i >> 4) * 20 + (i & 15)] = wr0[it];
    }
    __syncthreads();
    if (t < 384) {
      const float* r1 = &xcb[i1 + halfB * 16];
      const float* r2 = &xcb[i2 + halfB * 16];
      float a[16], cc[16];
#pragma unroll
      for (int q = 0; q < 4; ++q) {
        *(float4*)&a[q * 4] = *(const float4*)&r1[q * 4];
        *(float4*)&cc[q * 4] = *(const float4*)&r2[q * 4];
      }
      unsigned pk[8];
#pragma unroll
      for (int q = 0; q < 8; ++q) {
        float v0 = a[q * 2] * cc[q * 2];
        float v1 = a[q * 2 + 1] * cc[q * 2 + 1];
        asm("v_cvt_pk_bf16_f32 %0, %1, %2" : "=v"(pk[q]) : "v"(v0), "v"(v1));
      }
      unsigned* dst = (unsigned*)Pl[p] + colB * 20 + halfB * 8;
      *(uint4*)dst = *(uint4*)&pk[0];
      *(uint4*)(dst + 4) = *(uint4*)&pk[4];
    }
    __syncthreads();
    if (c < 29) {
      const int k0 = (c + 1) * 32;
      if (sOk) {
        if (pixIn) {
          const float* src = &xb[(k0 + sk4 * 4) * 49 + pixOff];
#pragma unroll
          for (int q = 0; q < 4; ++q) xr0[q] = src[q * 49];
        }
      }
      int base = k0 >> 1;
#pragma unroll
      for (int it = 0; it < 3; ++it) {
        int i = t + it * 512;
        wr0[it] = WbfU[(i >> 4) * 480 + base + (i & 15)];
      }
    }
    const int ko = quad * 8;
    bf16x8 af[3], bfr[3];
#pragma unroll
    for (int m = 0; m < 3; ++m)
      af[m] = *(const bf16x8*)&Wl[p][((mh * 3 + m) * 16 + lr) * 40 + ko];
#pragma unroll
    for (int n = 0; n < 3; ++n)
      bfr[n] = *(const bf16x8*)&Pl[p][((ng * 3 + n) * 16 + lr) * 40 + ko];
#pragma unroll
    for (int m = 0; m < 3; ++m)
#pragma unroll
      for (int n = 0; n < 3; ++n)
        acc[m][n] = __builtin_amdgcn_mfma_f32_16x16x32_bf16(
            af[m], bfr[n], acc[m][n], 0, 0, 0);
  }
#pragma unroll
  for (int n = 0; n < 3; ++n) {
    int col = (ng * 3 + n) * 16 + lr;
    if (col >= 175) continue;
    int wp = col / 25, uv = col - wp * 25;
    unsigned pairIdx = (unsigned)(b * 49 + h * 7 + wp);
#pragma unroll
    for (int m = 0; m < 3; ++m) {
#pragma unroll
      for (int r = 0; r < 4; ++r) {
        int o = (mh * 3 + m) * 16 + quad * 4 + r;
        float g = BNINV * bn[o], bt = bn[96 + o];
        float v = fmaxf(acc[m][n][r] * g + bt, 0.f);
        y1bf[pairIdx * 2432u + (unsigned)(o * 25 + uv)] = f2bf(v);
      }
    }
  }
}

// ------- K3: conv1 MFMA GEMM, both branches. grid (128 = 2br x 64 slots, 7 n) -------
__global__ __launch_bounds__(256) void k_conv1g(
    const unsigned* __restrict__ y1b0, const unsigned* __restrict__ y1b1,
    const unsigned* __restrict__ kmtu,
    const float* __restrict__ bn1,
    unsigned short* __restrict__ y2b0, unsigned short* __restrict__ y2b1) {
  const int slot = blockIdx.x & 63;
  if (slot >= 49) return;
  const int br = blockIdx.x >> 6;
  const unsigned* y1u = br ? y1b1 : y1b0;
  unsigned short* y2bf = br ? y2b1 : y2b0;
  const int t = threadIdx.x;
  const int wave = t >> 6, lane = t & 63, quad = lane >> 4, lr = lane & 15;
  const int mh = wave >> 1, nh = wave & 1;
  const int pairBase = slot * 64, nBase = blockIdx.y * 128;
  __shared__ __align__(16) short Ash[64 * 72];
  __shared__ __align__(16) short Bsh[128 * 72];
  __shared__ float bnl[192];
  unsigned* Au = (unsigned*)Ash;
  unsigned* Bu = (unsigned*)Bsh;
  if (t < 192) bnl[t] = bn1[t];
  f32x4 acc[2][4];
#pragma unroll
  for (int m = 0; m < 2; ++m)
#pragma unroll
    for (int n = 0; n < 4; ++n) acc[m][n] = (f32x4){0.f, 0.f, 0.f, 0.f};
  const int prA = t >> 2, qA = t & 3;
  const int nB = t >> 1, qB = t & 1;
  for (int c = 0; c < 38; ++c) {
    int ku0 = c * 32;
    __syncthreads();
    {
      const unsigned* src = y1u + (unsigned)(pairBase + prA) * 1216u + ku0 + qA * 8;
      unsigned* dst = Au + prA * 36 + qA * 8;
      *(uint4*)dst = *(const uint4*)src;
      *(uint4*)(dst + 4) = *(const uint4*)(src + 4);
    }
    {
      const unsigned* src = kmtu + (unsigned)(nBase + nB) * 1216u + ku0 + qB * 16;
      unsigned* dst = Bu + nB * 36 + qB * 16;
#pragma unroll
      for (int q = 0; q < 4; ++q)
        *(uint4*)(dst + q * 4) = *(const uint4*)(src + q * 4);
    }
    __syncthreads();
#pragma unroll
    for (int s = 0; s < 2; ++s) {
      int ko = s * 32 + quad * 8;
      bf16x8 af[2], bf[4];
#pragma unroll
      for (int m = 0; m < 2; ++m)
        af[m] = *(const bf16x8*)&Ash[((mh * 2 + m) * 16 + lr) * 72 + ko];
#pragma unroll
      for (int n = 0; n < 4; ++n)
        bf[n] = *(const bf16x8*)&Bsh[((nh * 4 + n) * 16 + lr) * 72 + ko];
#pragma unroll
      for (int m = 0; m < 2; ++m)
#pragma unroll
        for (int n = 0; n < 4; ++n)
          acc[m][n] = __builtin_amdgcn_mfma_f32_16x16x32_bf16(
              af[m], bf[n], acc[m][n], 0, 0, 0);
    }
  }
#pragma unroll
  for (int m = 0; m < 2; ++m) {
#pragma unroll
    for (int r = 0; r < 4; ++r) {
      unsigned pair = (unsigned)(pairBase + (mh * 2 + m) * 16 + quad * 4 + r);
#pragma unroll
      for (int n = 0; n < 4; ++n) {
        int nn = nBase + (nh * 4 + n) * 16 + lr;
        unsigned short outv = 0;
        if (nn < 864) {
          int o = nn / 9;
          float v = fmaxf(acc[m][n][r] * (BNINV * bnl[o]) + bnl[96 + o], 0.f);
          outv = f2bf(v);
        }
        y2bf[pair * 896u + nn] = outv;
      }
    }
  }
}

// ------- K4: conv2 MFMA GEMM, both branches. grid (98, 2 br) -------
__global__ __launch_bounds__(256) void k_conv2g(
    const unsigned* __restrict__ y2b0, const unsigned* __restrict__ y2b1,
    const unsigned* __restrict__ w2u,
    const float* __restrict__ bn2,
    float* __restrict__ t0, float* __restrict__ t1) {
  const int br = blockIdx.y;
  const unsigned* y2u = br ? y2b1 : y2b0;
  float* tout = br ? t1 : t0;
  const int t = threadIdx.x;
  const int wave = t >> 6, lane = t & 63, quad = lane >> 4, lr = lane & 15;
  const int mh = wave >> 1, nh = wave & 1;
  const int pairBase = blockIdx.x * 32;
  __shared__ __align__(16) short Ash[32 * 72];
  __shared__ __align__(16) short Bsh[96 * 72];
  __shared__ float bnl[192];
  unsigned* Au = (unsigned*)Ash;
  unsigned* Bu = (unsigned*)Bsh;
  if (t < 192) bnl[t] = bn2[t];
  f32x4 acc[3];
#pragma unroll
  for (int n = 0; n < 3; ++n) acc[n] = (f32x4){0.f, 0.f, 0.f, 0.f};
  const int prA = t >> 3, qA = (t & 7) * 4;
  const int nB = t >> 1, qB = (t & 1) * 16;
  for (int c = 0; c < 14; ++c) {
    int ku0 = c * 32;
    __syncthreads();
    {
      const unsigned* src = y2u + (unsigned)(pairBase + prA) * 448u + ku0 + qA;
      *(uint4*)(Au + prA * 36 + qA) = *(const uint4*)src;
    }
    if (t < 192) {
      const unsigned* src = w2u + (unsigned)nB * 448u + ku0 + qB;
      unsigned* dst = Bu + nB * 36 + qB;
#pragma unroll
      for (int q = 0; q < 4; ++q)
        *(uint4*)(dst + q * 4) = *(const uint4*)(src + q * 4);
    }
    __syncthreads();
#pragma unroll
    for (int s = 0; s < 2; ++s) {
      int ko = s * 32 + quad * 8;
      bf16x8 af;
      af = *(const bf16x8*)&Ash[(mh * 16 + lr) * 72 + ko];
#pragma unroll
      for (int n = 0; n < 3; ++n) {
        bf16x8 bf = *(const bf16x8*)&Bsh[((nh * 3 + n) * 16 + lr) * 72 + ko];
        acc[n] = __builtin_amdgcn_mfma_f32_16x16x32_bf16(af, bf, acc[n], 0, 0, 0);
      }
    }
  }
#pragma unroll
  for (int r = 0; r < 4; ++r) {
    unsigned pair = (unsigned)(pairBase + mh * 16 + quad * 4 + r);
#pragma unroll
    for (int n = 0; n < 3; ++n) {
      int o = (nh * 3 + n) * 16 + lr;
      float v = fmaxf(acc[n][r] * (BNINV * bnl[o]) + bnl[96 + o], 0.f);
      tout[pair * 96u + o] = v;
    }
  }
}

// ------- K5: fused w_out GEMM + BN + residual relu + mean-sub + cca1 + l2norm -------
// grid (128 = 2br x 64 b, 7 pr), 512 threads.
__global__ __launch_bounds__(512) void k_out_cca(
    const float* __restrict__ t0, const float* __restrict__ t1,
    const float* __restrict__ wouT, const float* __restrict__ bno,
    const float* __restrict__ x_p, const float* __restrict__ x_i,
    const float* __restrict__ ccaT, const float* __restrict__ bnc,
    float* __restrict__ xpn, float* __restrict__ sq) {
  int bb = blockIdx.x, pr = blockIdx.y, t = threadIdx.x;
  int br = bb >> 6, b = bb & 63;
  const float* tin = br ? t1 : t0;
  const float* x = br ? x_i : x_p;
  float* xpnb = xpn + br * 3010560;
  float* sqb = sq + br * 301056;
  __shared__ __align__(16) float tl2[96 * 8];     // [ic][pl]
  __shared__ __align__(16) float xrT[960 * 8];    // [o][pl] : x then y
  __shared__ float red[8 * 520];
  __shared__ float mean[7];
  __shared__ float sv[7 * 97];
  __shared__ float inv7[7];
  for (int i = t; i < 672; i += 512) {
    int pl = i / 96, ic = i - pl * 96;
    tl2[ic * 8 + pl] = tin[(b * 49 + pr * 7 + pl) * 96 + ic];
  }
  for (int i = t; i < 6720; i += 512) {
    int o = i / 7, pl = i - o * 7;
    xrT[o * 8 + pl] = x[(b * 960 + o) * 49 + pr * 7 + pl];
  }
  __syncthreads();
  float acc0[7] = {0.f, 0.f, 0.f, 0.f, 0.f, 0.f, 0.f};
  float acc1[7] = {0.f, 0.f, 0.f, 0.f, 0.f, 0.f, 0.f};
  const bool has1 = (t < 448);
  const int o1 = has1 ? t + 512 : t;
#pragma unroll 8
  for (int ic = 0; ic < 96; ++ic) {
    float tv[8];
    *(float4*)&tv[0] = *(const float4*)&tl2[ic * 8];
    *(float4*)&tv[4] = *(const float4*)&tl2[ic * 8 + 4];
    float w0 = wouT[ic * 960 + t];
    float w1 = wouT[ic * 960 + o1];
#pragma unroll
    for (int pl = 0; pl < 7; ++pl) {
      acc0[pl] += w0 * tv[pl];
      acc1[pl] += w1 * tv[pl];
    }
  }
  float part[7] = {0.f, 0.f, 0.f, 0.f, 0.f, 0.f, 0.f};
  {
    float xv[8];
    *(float4*)&xv[0] = *(const float4*)&xrT[t * 8];
    *(float4*)&xv[4] = *(const float4*)&xrT[t * 8 + 4];
    float g = BNINV * bno[t], bt = bno[960 + t];
#pragma unroll
    for (int pl = 0; pl < 7; ++pl) {
      float v = fmaxf(xv[pl] + acc0[pl] * g + bt, 0.f);
      acc0[pl] = v; part[pl] += v;
      xrT[t * 8 + pl] = v;
    }
  }
  if (has1) {
    float xv[8];
    *(float4*)&xv[0] = *(const float4*)&xrT[o1 * 8];
    *(float4*)&xv[4] = *(const float4*)&xrT[o1 * 8 + 4];
    float g = BNINV * bno[o1], bt = bno[960 + o1];
#pragma unroll
    for (int pl = 0; pl < 7; ++pl) {
      float v = fmaxf(xv[pl] + acc1[pl] * g + bt, 0.f);
      acc1[pl] = v; part[pl] += v;
      xrT[o1 * 8 + pl] = v;
    }
  }
#pragma unroll
  for (int pl = 0; pl < 7; ++pl) red[pl * 520 + t] = part[pl];
  __syncthreads();
  if (t < 64) {
#pragma unroll
    for (int pl = 0; pl < 7; ++pl) {
      float s = 0.f;
#pragma unroll
      for (int j = 0; j < 8; ++j) s += red[pl * 520 + t + j * 64];
      red[pl * 520 + t] = s;
    }
  }
  __syncthreads();
  if (t < 7) {
    float s = 0.f;
    for (int i = 0; i < 64; ++i) s += red[t * 520 + i];
    mean[t] = s * (1.f / 960.f);
  }
  __syncthreads();
#pragma unroll
  for (int pl = 0; pl < 7; ++pl)
    xpnb[(b * 49 + pr * 7 + pl) * 960 + t] = acc0[pl] - mean[pl];
  if (has1) {
#pragma unroll
    for (int pl = 0; pl < 7; ++pl)
      xpnb[(b * 49 + pr * 7 + pl) * 960 + o1] = acc1[pl] - mean[pl];
  }
  float acc2[7] = {0.f, 0.f, 0.f, 0.f, 0.f, 0.f, 0.f};
  float sw = 0.f;
  int o2 = t % 96, csl = t / 96;
  if (t < 480) {
    int c0 = csl * 192;
#pragma unroll 8
    for (int c = c0; c < c0 + 192; ++c) {
      float w = ccaT[c * 96 + o2];
      sw += w;
      float tv[8];
      *(float4*)&tv[0] = *(const float4*)&xrT[c * 8];
      *(float4*)&tv[4] = *(const float4*)&xrT[c * 8 + 4];
#pragma unroll
      for (int pl = 0; pl < 7; ++pl) acc2[pl] += w * tv[pl];
    }
#pragma unroll
    for (int pl = 0; pl < 7; ++pl) red[pl * 520 + t] = acc2[pl];
    red[7 * 520 + t] = sw;
  }
  __syncthreads();
  if (t < 96) {
    float g = BNINV * bnc[t], bt = bnc[96 + t];
    float swt = 0.f;
#pragma unroll
    for (int s5 = 0; s5 < 5; ++s5) swt += red[7 * 520 + s5 * 96 + t];
#pragma unroll
    for (int pl = 0; pl < 7; ++pl) {
      float a = 0.f;
#pragma unroll
      for (int s5 = 0; s5 < 5; ++s5) a += red[pl * 520 + s5 * 96 + t];
      a -= mean[pl] * swt;
      sv[pl * 97 + t] = fmaxf(a * g + bt, 0.f);
    }
  }
  __syncthreads();
  if (t < 112) {
    int pl = t >> 4, ln = t & 15;
    float s = 0.f;
    for (int o = ln; o < 96; o += 16) { float v = sv[pl * 97 + o]; s += v * v; }
    red[pl * 16 + ln] = s;
  }
  __syncthreads();
  if (t < 7) {
    float s = 0.f;
    for (int i = 0; i < 16; ++i) s += red[t * 16 + i];
    inv7[t] = 1.f / fmaxf(sqrtf(s), 1e-8f);
  }
  __syncthreads();
  for (int i = t; i < 672; i += 512) {
    int pl = i / 96, o = i - pl * 96;
    sqb[(b * 49 + pr * 7 + pl) * 96 + o] = sv[pl * 97 + o] * inv7[pl];
  }
}

// ------- K7: fused corr + sep4d#0 (512 threads) -------
__global__ __launch_bounds__(512) void k_mid(
    const float* __restrict__ sq0, const float* __restrict__ sq1,
    const float* __restrict__ wuv, const float* __restrict__ bnuv,
    const float* __restrict__ wkl, const float* __restrict__ bnkl,
    const float* __restrict__ pw16, const float* __restrict__ pbn16,
    float* __restrict__ s0p) {
  int b = blockIdx.x, t = threadIdx.x;
  __shared__ float smem[12496];
  float* sL = smem;
  float* qL = smem + 5047;
  float* A = smem + 10094;
  for (int i = t; i < 4704; i += 512) {
    int p = i / 96, c = i % 96;
    sL[p * 103 + c] = sq0[b * 4704 + i];
    qL[p * 103 + c] = sq1[b * 4704 + i];
  }
  __syncthreads();
  for (int i = t; i < 2401; i += 512) {
    int ij = i / 49, kl = i % 49;
    float a = 0.f;
#pragma unroll 4
    for (int c = 0; c < 96; ++c) a += sL[ij * 103 + c] * qL[kl * 103 + c];
    A[i] = a;
  }
  __syncthreads();
  float* B = smem;
  {
    float w0[9];
#pragma unroll
    for (int d = 0; d < 9; ++d) w0[d] = wuv[d];
    float g = BNINV * bnuv[0], bt = bnuv[1];
    for (int i = t; i < 2401; i += 512) {
      int ij = i / 49, kl = i % 49;
      int u = ij / 7, v = ij % 7;
      float a = 0.f;
#pragma unroll
      for (int du = 0; du < 3; ++du) {
        int uu = u + du - 1;
        if ((unsigned)uu >= 7u) continue;
#pragma unroll
        for (int dv = 0; dv < 3; ++dv) {
          int vv = v + dv - 1;
          if ((unsigned)vv >= 7u) continue;
          a += w0[du * 3 + dv] * A[(uu * 7 + vv) * 49 + kl];
        }
      }
      B[i] = fmaxf(a * g + bt, 0.f);
    }
  }
  __syncthreads();
  float* Cc = smem + 4900;
  {
    float w1[9];
#pragma unroll
    for (int d = 0; d < 9; ++d) w1[d] = wkl[d];
    float g = BNINV * bnkl[0], bt = bnkl[1];
    for (int i = t; i < 2401; i += 512) {
      int ij = i / 49, kl = i % 49;
      int kk = kl / 7, ll = kl % 7;
      float a = 0.f;
#pragma unroll
      for (int dh = 0; dh < 3; ++dh) {
        int k2 = kk + dh - 1;
        if ((unsigned)k2 >= 7u) continue;
#pragma unroll
        for (int dw = 0; dw < 3; ++dw) {
          int l2 = ll + dw - 1;
          if ((unsigned)l2 >= 7u) continue;
          a += w1[dh * 3 + dw] * B[ij * 49 + k2 * 7 + l2];
        }
      }
      Cc[i] = a * g + bt;
    }
  }
  __syncthreads();
  for (int o = 0; o < 16; ++o) {
    float sc = pw16[o] * BNINV * pbn16[o], bt2 = pbn16[16 + o];
    for (int i = t; i < 2401; i += 512)
      s0p[(b * 16 + o) * 2401 + i] = fmaxf(Cc[i] * sc + bt2, 0.f);
  }
}

// ---------------- sep4d #1 conv a. grid (64 b, 7 kc), 512 thr ----------------
__global__ __launch_bounds__(512) void k_sep1a(
    const float* __restrict__ in, const float* __restrict__ w,
    const float* __restrict__ bnp, float* __restrict__ out) {
  int b = blockIdx.x, kc = blockIdx.y, t = threadIdx.x;
  __shared__ float inS[16 * 345];
  __shared__ __align__(16) float wP[3072];
  for (int i = t; i < 3072; i += 512) {
    int oc = i / 12, d = i % 12;
    wP[i] = (d < 9) ? w[oc * 9 + d] : 0.f;
  }
  for (int i = t; i < 5488; i += 512) {
    int ic = i / 343, r = i - ic * 343;
    int ij = r / 7, s = r - ij * 7;
    inS[ic * 345 + s * 49 + ij] = in[(b * 16 + ic) * 2401 + ij * 49 + kc * 7 + s];
  }
  __syncthreads();
  for (int rho = t; rho < 784; rho += 512) {
    int o = rho / 49, rem = rho - o * 49, u = rem / 7, s = rem - u * 7;
    float acc[7] = {0.f, 0.f, 0.f, 0.f, 0.f, 0.f, 0.f};
    for (int ic = 0; ic < 16; ++ic) {
      float wv[12];
      const float* wb = &wP[(o * 16 + ic) * 12];
      *(float4*)&wv[0] = *(const float4*)&wb[0];
      *(float4*)&wv[4] = *(const float4*)&wb[4];
      *(float4*)&wv[8] = *(const float4*)&wb[8];
      const float* rowb = &inS[ic * 345 + s * 49];
#pragma unroll
      for (int du = 0; du < 3; ++du) {
        int uu = u + du - 1;
        if ((unsigned)uu >= 7u) continue;
        const float* rr = rowb + uu * 7;
        float r7[7];
#pragma unroll
        for (int q = 0; q < 7; ++q) r7[q] = rr[q];
#pragma unroll
        for (int v = 0; v < 7; ++v) {
          float a = acc[v];
          if (v > 0) a += wv[du * 3 + 0] * r7[v - 1];
          a += wv[du * 3 + 1] * r7[v];
          if (v < 6) a += wv[du * 3 + 2] * r7[v + 1];
          acc[v] = a;
        }
      }
    }
    float g = BNINV * bnp[o], bt = bnp[16 + o];
    long ob = (long)(b * 16 + o) * 2401 + kc * 7 + s;
#pragma unroll
    for (int v = 0; v < 7; ++v)
      out[ob + (u * 7 + v) * 49] = fmaxf(acc[v] * g + bt, 0.f);
  }
}

// ---------------- sep4d #1 conv b. grid (64 b, 7 ir), 512 thr ----------------
__global__ __launch_bounds__(512) void k_sep1b(
    const float* __restrict__ in, const float* __restrict__ w,
    const float* __restrict__ bnp, float* __restrict__ out) {
  int b = blockIdx.x, ir = blockIdx.y, t = threadIdx.x;
  __shared__ float inS[16 * 345];
  __shared__ __align__(16) float wP[3072];
  for (int i = t; i < 3072; i += 512) {
    int oc = i / 12, d = i % 12;
    wP[i] = (d < 9) ? w[oc * 9 + d] : 0.f;
  }
  for (int i = t; i < 5488; i += 512) {
    int ic = i / 343, r = i - ic * 343;
    inS[ic * 345 + r] = in[(b * 16 + ic) * 2401 + ir * 343 + r];
  }
  __syncthreads();
  for (int rho = t; rho < 784; rho += 512) {
    int o = rho / 49, rem = rho - o * 49, jj = rem / 7, k = rem - jj * 7;
    float acc[7] = {0.f, 0.f, 0.f, 0.f, 0.f, 0.f, 0.f};
    for (int ic = 0; ic < 16; ++ic) {
      float wv[12];
      const float* wb = &wP[(o * 16 + ic) * 12];
      *(float4*)&wv[0] = *(const float4*)&wb[0];
      *(float4*)&wv[4] = *(const float4*)&wb[4];
      *(float4*)&wv[8] = *(const float4*)&wb[8];
      const float* rowb = &inS[ic * 345 + jj * 49];
#pragma unroll
      for (int dh = 0; dh < 3; ++dh) {
        int k2 = k + dh - 1;
        if ((unsigned)k2 >= 7u) continue;
        const float* rr = rowb + k2 * 7;
        float r7[7];
#pragma unroll
        for (int q = 0; q < 7; ++q) r7[q] = rr[q];
#pragma unroll
        for (int l = 0; l < 7; ++l) {
          float a = acc[l];
          if (l > 0) a += wv[dh * 3 + 0] * r7[l - 1];
          a += wv[dh * 3 + 1] * r7[l];
          if (l < 6) a += wv[dh * 3 + 2] * r7[l + 1];
          acc[l] = a;
        }
      }
    }
    float g = BNINV * bnp[o], bt = bnp[16 + o];
    long ob = (long)(b * 16 + o) * 2401 + ir * 343 + jj * 49 + k * 7;
#pragma unroll
    for (int l = 0; l < 7; ++l)
      out[ob + l] = acc[l] * g + bt;
  }
}

// ------- K10: fused sep1p + gauss-softmax attention (dual-phase concurrent) -------
__global__ __launch_bounds__(256) void k_c4attn(
    const float* __restrict__ in, const float* __restrict__ pw,
    const float* __restrict__ pbn, float* __restrict__ attn_s,
    float* __restrict__ attn_q) {
  int b = blockIdx.x, t = threadIdx.x;
  __shared__ float c[2401];
  __shared__ float nA[2401];
  __shared__ float nB[2401];
  __shared__ float plw[16];
  if (t < 16) plw[t] = pw[t];
  __syncthreads();
  float g0 = BNINV * pbn[0], bt0 = pbn[1];
  for (int i = t; i < 2401; i += 256) {
    float a = 0.f;
#pragma unroll
    for (int ic = 0; ic < 16; ++ic) a += plw[ic] * in[(b * 16 + ic) * 2401 + i];
    c[i] = a * g0 + bt0;
  }
  __syncthreads();
  if (t < 49) {
    float m = 0.f;
    for (int ij = 0; ij < 49; ++ij) m += c[ij * 49 + t];
    m *= (1.f / 49.f);
    float v = 0.f;
    for (int ij = 0; ij < 49; ++ij) { float d = c[ij * 49 + t] - m; v += d * d; }
    v *= (1.f / 48.f);
    float inv = 1.f / sqrtf(v + 1e-5f);
    float mx = -1e30f;
    for (int ij = 0; ij < 49; ++ij) mx = fmaxf(mx, (c[ij * 49 + t] - m) * inv);
    float s = 0.f;
    for (int ij = 0; ij < 49; ++ij) {
      float e = expf((c[ij * 49 + t] - m) * inv - mx);
      nA[ij * 49 + t] = e; s += e;
    }
    float r = 1.f / s;
    for (int ij = 0; ij < 49; ++ij) nA[ij * 49 + t] *= r;
  } else if (t >= 64 && t < 113) {
    int t2 = t - 64;
    float m = 0.f;
    for (int kl = 0; kl < 49; ++kl) m += c[t2 * 49 + kl];
    m *= (1.f / 49.f);
    float v = 0.f;
    for (int kl = 0; kl < 49; ++kl) { float d = c[t2 * 49 + kl] - m; v += d * d; }
    v *= (1.f / 48.f);
    float inv = 1.f / sqrtf(v + 1e-5f);
    float mx = -1e30f;
    for (int kl = 0; kl < 49; ++kl) mx = fmaxf(mx, (c[t2 * 49 + kl] - m) * inv);
    float s = 0.f;
    for (int kl = 0; kl < 49; ++kl) {
      float e = expf((c[t2 * 49 + kl] - m) * inv - mx);
      nB[t2 * 49 + kl] = e; s += e;
    }
    float r = 1.f / s;
    for (int kl = 0; kl < 49; ++kl) nB[t2 * 49 + kl] *= r;
  }
  __syncthreads();
  if (t < 49) {
    float s = 0.f;
    for (int kl = 0; kl < 49; ++kl) s += nA[t * 49 + kl];
    attn_s[b * 49 + t] = s;
  } else if (t >= 64 && t < 113) {
    int t2 = t - 64;
    float s = 0.f;
    for (int ij = 0; ij < 49; ++ij) s += nB[ij * 49 + t2];
    attn_q[b * 49 + t2] = s;
  }
}

// ------- K11: attention-weighted mean/max pooling -------
__global__ __launch_bounds__(256) void k_pool(const float* __restrict__ xpn,
                                              const float* __restrict__ attn,
                                              float* __restrict__ ep) {
  int b = blockIdx.x, br = blockIdx.y, t = threadIdx.x;
  const float* xb = xpn + br * 3010560 + b * 47040;
  const float* a = attn + br * 3136 + b * 49;
  __shared__ float al[49];
  if (t < 49) al[t] = a[t];
  __syncthreads();
  float* eb = ep + br * 122880 + b * 1920;
  for (int c = t; c < 960; c += 256) {
    float s = 0.f, mx = -1e30f;
#pragma unroll 7
    for (int hw = 0; hw < 49; ++hw) {
      float v = al[hw] * xb[hw * 960 + c];
      s += v; mx = fmaxf(mx, v);
    }
    eb[c] = s * (1.f / 49.f);
    eb[960 + c] = mx;
  }
}

// ------- M=64 GEMM, split-K with atomicAdd; z selects meta/ene -------
// v2: register prefetch + double-buffered LDS, one barrier per 48-k chunk.
__global__ __launch_bounds__(256) void k_gemm64(
    const float* __restrict__ A0, const float* __restrict__ A1, int asplit,
    int reluA, const float* __restrict__ Wm, const float* __restrict__ We,
    int K, int Kslice, float* __restrict__ Cm, float* __restrict__ Ce,
    int N, int zAoff) {
  int otile = blockIdx.x, ks = blockIdx.y, z = blockIdx.z;
  const float* W = z ? We : Wm;
  float* C = z ? Ce : Cm;
  int zo = z * zAoff;
  int t = threadIdx.x, bt = t >> 4, ot = t & 15;
  __shared__ __align__(16) float eT[2][48 * 68];
  __shared__ __align__(16) float wT[2][48 * 68];
  float acc[4][4];
#pragma unroll
  for (int i = 0; i < 4; ++i)
#pragma unroll
    for (int j = 0; j < 4; ++j) acc[i][j] = 0.f;
  const int kbeg = ks * Kslice;
  const int nch = Kslice / 48;
  int sb[3], skg[3];
#pragma unroll
  for (int it = 0; it < 3; ++it) {
    int i = t + it * 256;
    sb[it] = i / 12;
    skg[it] = i % 12;
  }
  float4 ra[3], rw[3];
#pragma unroll
  for (int it = 0; it < 3; ++it) {
    int k = kbeg + skg[it] * 4;
    float4 v;
    if (asplit) {
      v = (k < asplit) ? *(const float4*)&A0[sb[it] * 1920 + zo + k]
                       : *(const float4*)&A1[sb[it] * 1920 + zo + k - asplit];
    } else {
      v = *(const float4*)&A0[zo + sb[it] * K + k];
    }
    if (reluA) {
      v.x = fmaxf(v.x, 0.f); v.y = fmaxf(v.y, 0.f);
      v.z = fmaxf(v.z, 0.f); v.w = fmaxf(v.w, 0.f);
    }
    ra[it] = v;
    rw[it] = *(const float4*)&W[(otile * 64 + sb[it]) * K + kbeg + skg[it] * 4];
  }
  int p = 0;
  for (int c = 0; c < nch; ++c, p ^= 1) {
#pragma unroll
    for (int it = 0; it < 3; ++it) {
      int row4 = skg[it] * 4, col = sb[it];
      float4 v = ra[it];
      eT[p][(row4 + 0) * 68 + col] = v.x; eT[p][(row4 + 1) * 68 + col] = v.y;
      eT[p][(row4 + 2) * 68 + col] = v.z; eT[p][(row4 + 3) * 68 + col] = v.w;
      float4 w = rw[it];
      wT[p][(row4 + 0) * 68 + col] = w.x; wT[p][(row4 + 1) * 68 + col] = w.y;
      wT[p][(row4 + 2) * 68 + col] = w.z; wT[p][(row4 + 3) * 68 + col] = w.w;
    }
    __syncthreads();
    if (c + 1 < nch) {
      int k0 = kbeg + (c + 1) * 48;
#pragma unroll
      for (int it = 0; it < 3; ++it) {
        int k = k0 + skg[it] * 4;
        float4 v;
        if (asplit) {
          v = (k < asplit) ? *(const float4*)&A0[sb[it] * 1920 + zo + k]
                           : *(const float4*)&A1[sb[it] * 1920 + zo + k - asplit];
        } else {
          v = *(const float4*)&A0[zo + sb[it] * K + k];
        }
        if (reluA) {
          v.x = fmaxf(v.x, 0.f); v.y = fmaxf(v.y, 0.f);
          v.z = fmaxf(v.z, 0.f); v.w = fmaxf(v.w, 0.f);
        }
        ra[it] = v;
        rw[it] = *(const float4*)&W[(otile * 64 + sb[it]) * K + k0 + skg[it] * 4];
      }
    }
#pragma unroll 4
    for (int kk = 0; kk < 48; ++kk) {
      float av[4], wv[4];
      *(float4*)av = *(const float4*)&eT[p][kk * 68 + bt * 4];
      *(float4*)wv = *(const float4*)&wT[p][kk * 68 + ot * 4];
#pragma unroll
      for (int i = 0; i < 4; ++i)
#pragma unroll
        for (int j = 0; j < 4; ++j) acc[i][j] += av[i] * wv[j];
    }
  }
#pragma unroll
  for (int i = 0; i < 4; ++i)
#pragma unroll
    for (int j = 0; j < 4; ++j)
      atomicAdd(&C[(bt * 4 + i) * N + otile * 64 + ot * 4 + j], acc[i][j]);
}

// ------- classifier layer 1 v2: grid (30 otile, 8 g, 2 which), N=64/K-split-4 -------
__global__ __launch_bounds__(256) void k_cls1(
    const float* __restrict__ em3, const float* __restrict__ b2m,
    const float* __restrict__ b2e, const float* __restrict__ w1mT,
    const float* __restrict__ b1m, const float* __restrict__ w1eT,
    const float* __restrict__ b1e, float* __restrict__ h2) {
  int which = blockIdx.z, g = blockIdx.y, otile = blockIdx.x, t = threadIdx.x;
  const float* em = em3 + which * 61440 + g * 7680;
  const float* b2 = which ? b2e : b2m;
  const float* WT = which ? w1eT : w1mT;
  const float* b1 = which ? b1e : b1m;
  __shared__ float pl[960];
  __shared__ float red[256];
  for (int d = t; d < 960; d += 256) {
    float s = 0.f;
#pragma unroll
    for (int r = 0; r < 8; ++r) s += em[r * 960 + d];
    pl[d] = s * 0.125f + b2[d];
  }
  __syncthreads();
  int ot = t & 63, ks = t >> 6;
  int o = otile * 64 + ot;
  float acc = 0.f;
  const int k0 = ks * 240;
#pragma unroll 8
  for (int k = k0; k < k0 + 240; ++k) acc += WT[k * 1920 + o] * pl[k];
  red[t] = acc;
  __syncthreads();
  if (t < 64) {
    float s = red[t] + red[t + 64] + red[t + 128] + red[t + 192];
    float z = s + b1[o];
    h2[which * 15360 + g * 1920 + o] =
        z * fminf(fmaxf(z + 3.f, 0.f), 6.f) * (1.f / 6.f);
  }
}

// ------- classifier layer 2 + final concat -------
__global__ __launch_bounds__(128) void k_cls2(
    const float* __restrict__ h2, const float* __restrict__ w2m,
    const float* __restrict__ b2m, const float* __restrict__ w2e,
    const float* __restrict__ b2e, float* __restrict__ out) {
  int g = blockIdx.x, which = blockIdx.y;
  int t = threadIdx.x, j = t >> 6, lane = t & 63;
  const float* h = h2 + which * 15360 + g * 1920;
  const float* W = (which ? w2e : w2m) + j * 1920;
  const float* bb = which ? b2e : b2m;
  float s = 0.f;
  for (int k = lane; k < 1920; k += 64) s += h[k] * W[k];
  for (int off = 32; off >= 1; off >>= 1) s += __shfl_down(s, off);
  if (lane == 0) out[g * 4 + which * 2 + j] = s + bb[j];
}

// =======================================================================
extern "C" void kernel_launch(void* const* d_in, const int* in_sizes, int n_in,
                              void* d_out, int out_size, void* d_ws, size_t ws_size,
                              hipStream_t stream) {
  const float* x_p = (const float*)d_in[0];
  const float* x_i = (const float*)d_in[1];
  const float* scr_w_in = (const float*)d_in[2];
  const float* scr_bn_in = (const float*)d_in[3];
  const float* scr_w1 = (const float*)d_in[4];
  const float* scr_bn1 = (const float*)d_in[5];
  const float* scr_w2 = (const float*)d_in[6];
  const float* scr_bn2 = (const float*)d_in[7];
  const float* scr_w_out = (const float*)d_in[8];
  const float* scr_bn_out = (const float*)d_in[9];
  const float* cca1x1_w = (const float*)d_in[10];
  const float* cca1x1_bn = (const float*)d_in[11];
  const float* cca0_c2_w = (const float*)d_in[12];
  const float* cca0_c2_bn = (const float*)d_in[13];
  const float* cca0_c1_w = (const float*)d_in[14];
  const float* cca0_c1_bn = (const float*)d_in[15];
  const float* cca0_p_w = (const float*)d_in[16];
  const float* cca0_p_bn = (const float*)d_in[17];
  const float* cca1_c2_w = (const float*)d_in[18];
  const float* cca1_c2_bn = (const float*)d_in[19];
  const float* cca1_c1_w = (const float*)d_in[20];
  const float* cca1_c1_bn = (const float*)d_in[21];
  const float* cca1_p_w = (const float*)d_in[22];
  const float* cca1_p_bn = (const float*)d_in[23];
  const float* meta_w1 = (const float*)d_in[24];
  const float* meta_w2 = (const float*)d_in[25];
  const float* meta_b2 = (const float*)d_in[26];
  const float* ene_w1 = (const float*)d_in[27];
  const float* ene_w2 = (const float*)d_in[28];
  const float* ene_b2 = (const float*)d_in[29];
  const float* mcls_w1 = (const float*)d_in[30];
  const float* mcls_b1 = (const float*)d_in[31];
  const float* mcls_w2 = (const float*)d_in[32];
  const float* mcls_b2 = (const float*)d_in[33];
  const float* ecls_w1 = (const float*)d_in[34];
  const float* ecls_b1 = (const float*)d_in[35];
  const float* ecls_w2 = (const float*)d_in[36];
  const float* ecls_b2 = (const float*)d_in[37];

  float* ws = (float*)d_ws;
  float* PART = ws + OFF_XN;   // 2 x 64x8x49 partial sums
  unsigned short* Y1BF0 = (unsigned short*)(ws + OFF_Y1BF);
  unsigned short* Y1BF1 = (unsigned short*)(ws + OFF_Y1BF1);
  unsigned* KMTU = (unsigned*)(ws + OFF_KMT);
  unsigned short* W2BF = (unsigned short*)(ws + OFF_W2BF);
  unsigned short* Y2BF0 = (unsigned short*)(ws + OFF_Y2BF);
  unsigned short* Y2BF1 = (unsigned short*)(ws + OFF_Y2BF1);
  float* T0 = ws + OFF_T;
  float* T1 = ws + OFF_T1;
  float* XPN = ws + OFF_XPN;
  float* SQ = ws + OFF_SQ;
  float* S0P = ws + OFF_S0P;
  float* S1Y1 = ws + OFF_S1Y1;
  float* S1Y2 = ws + OFF_S1Y2;
  float* ATT = ws + OFF_ATT;
  float* EPI = ws + OFF_EPI;
  float* H1 = ws + OFF_H1;
  float* EM3 = ws + OFF_EM3;
  float* H2 = ws + OFF_H2;
  float* WOUTT = ws + OFF_WOUTT;
  float* CCAT = ws + OFF_CCAT;
  float* MCLST = ws + OFF_MCLST;
  float* ECLST = ws + OFF_ECLST;
  unsigned* WBF = (unsigned*)(ws + OFF_WBF);

  // weight preps
  k_transpose_t<<<dim3(3, 30), 256, 0, stream>>>(scr_w_out, WOUTT, 960, 96);
  k_transpose_t<<<dim3(30, 3), 256, 0, stream>>>(cca1x1_w, CCAT, 96, 960);
  k_transpose_t<<<dim3(30, 60), 256, 0, stream>>>(mcls_w1, MCLST, 1920, 960);
  k_transpose_t<<<dim3(30, 60), 256, 0, stream>>>(ecls_w1, ECLST, 1920, 960);
  k_prepwbf<<<180, 256, 0, stream>>>(scr_w_in, WBF);
  k_kmat<<<4256, 256, 0, stream>>>(scr_w1, KMTU);
  k_w2bf<<<336, 256, 0, stream>>>(scr_w2, W2BF);

  // merged dual-branch SCR chain
  k_l2npart<<<dim3(128, 8), 256, 0, stream>>>(x_p, x_i, PART);
  k_scr_in<<<dim3(128, 7), 512, 0, stream>>>(x_p, x_i, PART, WBF, scr_bn_in,
                                             Y1BF0, Y1BF1);
  k_conv1g<<<dim3(128, 7), 256, 0, stream>>>((const unsigned*)Y1BF0,
                                             (const unsigned*)Y1BF1, KMTU,
                                             scr_bn1, Y2BF0, Y2BF1);
  k_conv2g<<<dim3(98, 2), 256, 0, stream>>>((const unsigned*)Y2BF0,
                                            (const unsigned*)Y2BF1,
                                            (const unsigned*)W2BF, scr_bn2,
                                            T0, T1);
  k_out_cca<<<dim3(128, 7), 512, 0, stream>>>(T0, T1, WOUTT, scr_bn_out,
                                              x_p, x_i, CCAT, cca1x1_bn,
                                              XPN, SQ);

  k_mid<<<64, 512, 0, stream>>>(SQ, SQ + 301056, cca0_c2_w, cca0_c2_bn,
                                cca0_c1_w, cca0_c1_bn, cca0_p_w, cca0_p_bn, S0P);
  k_sep1a<<<dim3(64, 7), 512, 0, stream>>>(S0P, cca1_c2_w, cca1_c2_bn, S1Y1);
  k_sep1b<<<dim3(64, 7), 512, 0, stream>>>(S1Y1, cca1_c1_w, cca1_c1_bn, S1Y2);
  k_c4attn<<<64, 256, 0, stream>>>(S1Y2, cca1_p_w, cca1_p_bn, ATT, ATT + 3136);
  k_pool<<<dim3(64, 2), 256, 0, stream>>>(XPN, ATT, EPI);

  hipMemsetAsync(H1, 0, (245760u + 122880u) * sizeof(float), stream);
  k_gemm64<<<dim3(30, 8, 2), 256, 0, stream>>>(EPI, EPI + 122880, 960, 0,
                                               meta_w1, ene_w1, 1920, 240,
                                               H1, H1 + 122880, 1920, 960);
  k_gemm64<<<dim3(15, 8, 2), 256, 0, stream>>>(H1, nullptr, 0, 1,
                                               meta_w2, ene_w2, 1920, 240,
                                               EM3, EM3 + 61440, 960, 122880);
  k_cls1<<<dim3(30, 8, 2), 256, 0, stream>>>(EM3, meta_b2, ene_b2, MCLST, mcls_b1,
                                             ECLST, ecls_b1, H2);
  k_cls2<<<dim3(8, 2), 128, 0, stream>>>(H2, mcls_w2, mcls_b2, ecls_w2, ecls_b2,
                                         (float*)d_out);
}